// Round 1
// baseline (2126.312 us; speedup 1.0000x reference)
//
#include <hip/hip_runtime.h>
#include <math.h>

// ---------------------------------------------------------------------------
// TAPIR forward, all f32.
// Shapes: fg[64,64,256] hg[128,128,128] qf[1024,256] hq[1024,128]
// out[1024,4] = (pos_x, pos_y, occ, expd)
// ---------------------------------------------------------------------------

#define NQ 1024
#define TEMPF 20.0f
#define DIMV 388
#define INDIM 535
#define INPITCH 544
#define HID 512

// workspace layout (float offsets)
#define WS_CV      0                          // 1024*4096
#define WS_FGAVG   (WS_CV + NQ*4096)          // 32*32*256
#define WS_POS     (WS_FGAVG + 262144)        // 1024*2
#define WS_OCC     (WS_POS + NQ*2)            // 1024
#define WS_EXPD    (WS_OCC + NQ)              // 1024
#define WS_FEATS   (WS_EXPD + NQ)             // 1024*384
#define WS_MLPIN   (WS_FEATS + NQ*384)        // 1024*544 (pitch-padded 535)
#define WS_HIDDEN  (WS_MLPIN + NQ*INPITCH)    // 1024*512
#define WS_W3T     (WS_HIDDEN + NQ*HID)       // 4608 transposed hid3_w [ic][tap][oc]

// ---------------------------------------------------------------------------
// prep: fg 2x2 avg pyramid level, feats = concat(hq, qf), w3 transpose
// ---------------------------------------------------------------------------
__global__ __launch_bounds__(256) void k_prep(
    const float* __restrict__ fg, const float* __restrict__ qf,
    const float* __restrict__ hq, const float* __restrict__ w3,
    float* __restrict__ ws) {
  int i = blockIdx.x * 256 + threadIdx.x;
  if (i < 262144) {
    int c = i & 255, ox = (i >> 8) & 31, oy = i >> 13;
    const float* b = fg + (((oy * 2) * 64 + ox * 2) << 8) + c;
    ws[WS_FGAVG + i] = 0.25f * (b[0] + b[256] + b[16384] + b[16384 + 256]);
  } else if (i < 262144 + 393216) {
    int j = i - 262144;
    int n = j / 384, c = j - n * 384;
    ws[WS_FEATS + j] = (c < 128) ? hq[n * 128 + c] : qf[n * 256 + c - 128];
  } else if (i < 262144 + 393216 + 4608) {
    int j = i - (262144 + 393216);
    int oc = j & 31, rest = j >> 5;
    int tap = rest % 9, ic = rest / 9;
    ws[WS_W3T + j] = w3[(oc * 16 + ic) * 9 + tap];
  }
}

// ---------------------------------------------------------------------------
// cost volume: cv[n][p] = sum_c qf[n][c] * fg[p][c]   (A·B^T, K=256)
// tile 32(m) x 64(p), 256 threads, 2x4 per thread
// ---------------------------------------------------------------------------
__global__ __launch_bounds__(256) void k_cv(
    const float* __restrict__ qf, const float* __restrict__ fg,
    float* __restrict__ ws) {
  __shared__ float As[16][33];   // [k][m]
  __shared__ float Bs[64][17];   // [p][k]
  int t = threadIdx.x;
  int tx = t & 15, ty = t >> 4;
  int p0 = blockIdx.x * 64, m0 = blockIdx.y * 32;
  float acc[2][4] = {{0.f, 0.f, 0.f, 0.f}, {0.f, 0.f, 0.f, 0.f}};
  int kk = t & 15, r = t >> 4;
  for (int k0 = 0; k0 < 256; k0 += 16) {
    As[kk][r]      = qf[(m0 + r) * 256 + k0 + kk];
    As[kk][r + 16] = qf[(m0 + r + 16) * 256 + k0 + kk];
#pragma unroll
    for (int j = 0; j < 4; j++)
      Bs[r + 16 * j][kk] = fg[(p0 + r + 16 * j) * 256 + k0 + kk];
    __syncthreads();
#pragma unroll
    for (int k = 0; k < 16; k++) {
      float a0 = As[k][ty * 2], a1 = As[k][ty * 2 + 1];
#pragma unroll
      for (int j = 0; j < 4; j++) {
        float b = Bs[tx * 4 + j][k];
        acc[0][j] += a0 * b;
        acc[1][j] += a1 * b;
      }
    }
    __syncthreads();
  }
#pragma unroll
  for (int i = 0; i < 2; i++) {
    float4 v = make_float4(acc[i][0], acc[i][1], acc[i][2], acc[i][3]);
    *(float4*)&ws[WS_CV + (m0 + ty * 2 + i) * 4096 + p0 + tx * 4] = v;
  }
}

// ---------------------------------------------------------------------------
// per-query head: hid1 conv -> (hid2 conv -> softmax argmax-expectation) and
// (hid3 stride-2 conv -> relu -> mean -> mlp -> occ/expd)
// occ_map is row-streamed through a 4-row LDS ring.
// 1 block = 1 query, 256 threads (4 waves).
// ---------------------------------------------------------------------------
__global__ __launch_bounds__(256) void k_head(
    const float* __restrict__ w1, const float* __restrict__ b1,
    const float* __restrict__ w2, const float* __restrict__ b2,
    const float* __restrict__ b3,
    const float* __restrict__ w4, const float* __restrict__ b4,
    const float* __restrict__ w5, const float* __restrict__ b5,
    float* __restrict__ ws) {
  __shared__ float cvs[66 * 66];        // zero-padded cv (rows/cols -1..64)
  __shared__ float ring[4][16][66];     // occ rows ring, x index xi = x+1
  __shared__ float pbuf[2][256];        // pmap partials, double buffered
  __shared__ float msum_s[32];
  __shared__ float o4s[16];

  const int n = blockIdx.x;
  const int t = threadIdx.x;
  const int wv = t >> 6;
  const int x1 = t & 63;                // P1/P2 pixel x
  const int ox = t & 31;                // P3 output x
  const int oc0 = (t >> 5) * 4;         // P3 output-channel base
  const float* cv = ws + WS_CV + n * 4096;
  const float* w3t = ws + WS_W3T;

  // ---- init LDS ----
  for (int i = t; i < 66 * 66; i += 256) cvs[i] = 0.f;
  for (int i = t; i < 4 * 16 * 66; i += 256) ((float*)ring)[i] = 0.f;
  __syncthreads();
  for (int rr = 0; rr < 16; rr++) {
    int p = t + 256 * rr;
    cvs[((p >> 6) + 1) * 66 + (p & 63) + 1] = cv[p];
  }

  // ---- weights to registers ----
  float w1r[4][9], w2r[4][9], b1r[4], b3r[4];
#pragma unroll
  for (int k = 0; k < 4; k++) {
    int ch = wv * 4 + k;
    b1r[k] = b1[ch];
#pragma unroll
    for (int j = 0; j < 9; j++) {
      w1r[k][j] = w1[ch * 9 + j];
      w2r[k][j] = w2[ch * 9 + j];
    }
    b3r[k] = b3[oc0 + k];
  }
  float b2v = b2[0];

  float msum[4] = {0.f, 0.f, 0.f, 0.f};
  float sm_m = -1e30f, sm_s = 0.f, sm_sy = 0.f;   // wave0 online softmax state
  __syncthreads();

  for (int y = 0; y <= 64; y++) {
    int slot = y & 3;
    // ---- P1: produce occ row y (or zero pad row 64) ----
    if (y < 64) {
      float p[9];
#pragma unroll
      for (int ky = 0; ky < 3; ky++) {
        const float* cp = &cvs[(y + ky) * 66 + x1];
        p[3 * ky + 0] = cp[0]; p[3 * ky + 1] = cp[1]; p[3 * ky + 2] = cp[2];
      }
#pragma unroll
      for (int k = 0; k < 4; k++) {
        float a = b1r[k];
#pragma unroll
        for (int j = 0; j < 9; j++) a += w1r[k][j] * p[j];
        ring[slot][wv * 4 + k][x1 + 1] = fmaxf(a, 0.f);
      }
    } else {
#pragma unroll
      for (int k = 0; k < 4; k++) ring[slot][wv * 4 + k][x1 + 1] = 0.f;
    }
    __syncthreads();
    // ---- P2: pmap partials for row yp = y-1 ----
    if (y >= 1) {
      int yp = y - 1;
      float s = 0.f;
#pragma unroll
      for (int cc = 0; cc < 4; cc++) {
        int ch = wv * 4 + cc;
#pragma unroll
        for (int ky = 0; ky < 3; ky++) {
          const float* rp = &ring[(yp - 1 + ky + 4) & 3][ch][x1];
          s += w2r[cc][3 * ky + 0] * rp[0] + w2r[cc][3 * ky + 1] * rp[1] +
               w2r[cc][3 * ky + 2] * rp[2];
        }
      }
      pbuf[y & 1][t] = s;
    }
    // ---- P3: hid3 stride-2 conv output row oy=(y-2)/2 on even y ----
    if ((y & 1) == 0 && y >= 2) {
      float a0 = 0.f, a1 = 0.f, a2 = 0.f, a3 = 0.f;
#pragma unroll
      for (int ic = 0; ic < 16; ic++) {
        float p[9];
#pragma unroll
        for (int ky = 0; ky < 3; ky++) {
          const float* rp = &ring[(y - 2 + ky) & 3][ic][2 * ox + 1];
          p[3 * ky + 0] = rp[0]; p[3 * ky + 1] = rp[1]; p[3 * ky + 2] = rp[2];
        }
#pragma unroll
        for (int tap = 0; tap < 9; tap++) {
          float4 w4v = *(const float4*)(w3t + (ic * 9 + tap) * 32 + oc0);
          a0 += w4v.x * p[tap]; a1 += w4v.y * p[tap];
          a2 += w4v.z * p[tap]; a3 += w4v.w * p[tap];
        }
      }
      msum[0] += fmaxf(a0 + b3r[0], 0.f);
      msum[1] += fmaxf(a1 + b3r[1], 0.f);
      msum[2] += fmaxf(a2 + b3r[2], 0.f);
      msum[3] += fmaxf(a3 + b3r[3], 0.f);
    }
    // ---- wave0: lagged softmax accumulation of row y-2 ----
    if (y >= 2 && t < 64) {
      const float* pb = pbuf[(y - 1) & 1];
      float v = ((pb[t] + pb[t + 64] + pb[t + 128] + pb[t + 192]) + b2v) * TEMPF;
      float m2 = fmaxf(sm_m, v);
      float sc = __expf(sm_m - m2), e = __expf(v - m2);
      sm_s = sm_s * sc + e;
      sm_sy = sm_sy * sc + e * (float)(y - 2);
      sm_m = m2;
    }
    __syncthreads();
  }

  // ---- final softmax row (y=63) + cross-lane merge -> expected coords ----
  if (t < 64) {
    const float* pb = pbuf[0];
    float v = ((pb[t] + pb[t + 64] + pb[t + 128] + pb[t + 192]) + b2v) * TEMPF;
    float m2 = fmaxf(sm_m, v);
    float sc = __expf(sm_m - m2), e = __expf(v - m2);
    sm_s = sm_s * sc + e;
    sm_sy = sm_sy * sc + e * 63.f;
    sm_m = m2;
    float m = sm_m, s = sm_s, sy = sm_sy, sx = sm_s * (float)t;
#pragma unroll
    for (int off = 32; off >= 1; off >>= 1) {
      float mo = __shfl_xor(m, off);
      float so = __shfl_xor(s, off);
      float syo = __shfl_xor(sy, off);
      float sxo = __shfl_xor(sx, off);
      float M = fmaxf(m, mo);
      float c1 = __expf(m - M), c2 = __expf(mo - M);
      s = s * c1 + so * c2;
      sy = sy * c1 + syo * c2;
      sx = sx * c1 + sxo * c2;
      m = M;
    }
    if (t == 0) {
      ws[WS_POS + n * 2 + 0] = (sx / s) * 8.0f;   // ex * (512/64)
      ws[WS_POS + n * 2 + 1] = (sy / s) * 8.0f;   // ey * (512/64)
    }
  }

  // ---- mean-reduce hid3 outputs ----
#pragma unroll
  for (int k = 0; k < 4; k++) {
    float v = msum[k];
    v += __shfl_down(v, 16, 32);
    v += __shfl_down(v, 8, 32);
    v += __shfl_down(v, 4, 32);
    v += __shfl_down(v, 2, 32);
    v += __shfl_down(v, 1, 32);
    if ((t & 31) == 0) msum_s[oc0 + k] = v;
  }
  __syncthreads();
  // ---- tiny MLP head ----
  if (t < 16) {
    float a = b4[t];
#pragma unroll
    for (int i = 0; i < 32; i++)
      a += (msum_s[i] * (1.f / 1024.f)) * w4[i * 16 + t];
    o4s[t] = fmaxf(a, 0.f);
  }
  __syncthreads();
  if (t < 2) {
    float r = b5[t];
#pragma unroll
    for (int j = 0; j < 16; j++) r += o4s[j] * w5[j * 2 + t];
    if (t == 0) ws[WS_OCC + n] = r;
    else        ws[WS_EXPD + n] = r;
  }
}

// ---------------------------------------------------------------------------
// correlation + mlp_in assembly. 1 wave = 1 query, 4 queries/block.
// 49 context points share an 8x8 integer corner window: compute 64 dots,
// then bilinear-combine with the query's single (wy,wx).
// ---------------------------------------------------------------------------
__global__ __launch_bounds__(256) void k_corr(
    const float* __restrict__ fg, const float* __restrict__ hg,
    float* __restrict__ ws) {
  __shared__ float dbuf[4][64];
  int t = threadIdx.x;
  int wv = t >> 6, lane = t & 63;
  int n = blockIdx.x * 4 + wv;
  const float* feats = ws + WS_FEATS + n * 384;
  float posx = ws[WS_POS + n * 2 + 0];
  float posy = ws[WS_POS + n * 2 + 1];
  float* mi = ws + WS_MLPIN + n * INPITCH;

  // first 388 cols: [0,0,occ,expd,feats(384)]
  for (int col = lane; col < 388; col += 64) {
    float v;
    if (col < 2) v = 0.f;
    else if (col == 2) v = ws[WS_OCC + n];
    else if (col == 3) v = ws[WS_EXPD + n];
    else v = feats[col - 4];
    mi[col] = v;
  }

  int a = lane >> 3, b = lane & 7;
#pragma unroll
  for (int L = 0; L < 3; L++) {
    const float* grid;
    int Hg, Wg, C, qoff;
    float scl;
    if (L == 0)      { grid = hg;             Hg = 128; Wg = 128; C = 128; qoff = 0;   scl = 0.25f; }
    else if (L == 1) { grid = fg;             Hg = 64;  Wg = 64;  C = 256; qoff = 128; scl = 0.125f; }
    else             { grid = ws + WS_FGAVG;  Hg = 32;  Wg = 32;  C = 256; qoff = 128; scl = 0.0625f; }
    float cy = posy * scl, cx = posx * scl;
    float fy = floorf(cy), fx = floorf(cx);
    int iy = (int)fy, ix = (int)fx;
    float wy = cy - fy, wx = cx - fx;
    int row = iy + a - 3; row = row < 0 ? 0 : (row > Hg - 1 ? Hg - 1 : row);
    int col = ix + b - 3; col = col < 0 ? 0 : (col > Wg - 1 ? Wg - 1 : col);
    const float* gp = grid + (row * Wg + col) * C;
    const float* qp = feats + qoff;
    float acc = 0.f;
    for (int c = 0; c < C; c += 4) {
      float4 g = *(const float4*)(gp + c);
      float4 q = *(const float4*)(qp + c);
      acc += g.x * q.x + g.y * q.y + g.z * q.z + g.w * q.w;
    }
    __syncthreads();
    dbuf[wv][lane] = acc;
    __syncthreads();
    if (lane < 49) {
      int sa = lane / 7, sb = lane % 7;
      float d00 = dbuf[wv][sa * 8 + sb],     d01 = dbuf[wv][sa * 8 + sb + 1];
      float d10 = dbuf[wv][sa * 8 + sb + 8], d11 = dbuf[wv][sa * 8 + sb + 9];
      float corr = (1.f - wy) * (1.f - wx) * d00 + (1.f - wy) * wx * d01 +
                   wy * (1.f - wx) * d10 + wy * wx * d11;
      mi[388 + L * 49 + lane] = corr;
    }
  }
}

// ---------------------------------------------------------------------------
// mixer GEMM 1: hidden = gelu(mlp_in @ mix_in_w + b)   [1024,535]x[535,512]
// ---------------------------------------------------------------------------
__device__ __forceinline__ float gelu_tanh(float x) {
  float z = 0.7978845608028654f * (x + 0.044715f * x * x * x);
  z = fminf(fmaxf(z, -15.f), 15.f);
  float e = __expf(2.f * z);
  float th = (e - 1.f) / (e + 1.f);
  return 0.5f * x * (1.f + th);
}

__global__ __launch_bounds__(256) void k_mix1(
    const float* __restrict__ w, const float* __restrict__ bias,
    float* __restrict__ ws) {
  __shared__ float As[16][33];
  __shared__ float Bs[16][65];
  int t = threadIdx.x;
  int tx = t & 15, ty = t >> 4;
  int n0 = blockIdx.x * 64, m0 = blockIdx.y * 32;
  const float* A = ws + WS_MLPIN;
  float acc[2][4] = {{0.f, 0.f, 0.f, 0.f}, {0.f, 0.f, 0.f, 0.f}};
  int kk = t & 15, r = t >> 4;
  for (int k0 = 0; k0 < INDIM; k0 += 16) {
    int k = k0 + kk;
    As[kk][r]      = (k < INDIM) ? A[(m0 + r) * INPITCH + k] : 0.f;
    As[kk][r + 16] = (k < INDIM) ? A[(m0 + r + 16) * INPITCH + k] : 0.f;
#pragma unroll
    for (int j = 0; j < 4; j++) {
      int idx = t + 256 * j;
      int bk = idx >> 6, nn = idx & 63;
      Bs[bk][nn] = (k0 + bk < INDIM) ? w[(k0 + bk) * HID + n0 + nn] : 0.f;
    }
    __syncthreads();
#pragma unroll
    for (int q = 0; q < 16; q++) {
      float a0 = As[q][ty * 2], a1 = As[q][ty * 2 + 1];
#pragma unroll
      for (int j = 0; j < 4; j++) {
        float b = Bs[q][tx * 4 + j];
        acc[0][j] += a0 * b;
        acc[1][j] += a1 * b;
      }
    }
    __syncthreads();
  }
  float* Hd = ws + WS_HIDDEN;
#pragma unroll
  for (int i = 0; i < 2; i++) {
    int m = m0 + ty * 2 + i;
#pragma unroll
    for (int j = 0; j < 4; j++) {
      int nn = n0 + tx * 4 + j;
      Hd[m * HID + nn] = gelu_tanh(acc[i][j] + bias[nn]);
    }
  }
}

// ---------------------------------------------------------------------------
// mixer GEMM 2 + state update + out write.  [1024,512]x[512,388]
// ---------------------------------------------------------------------------
__global__ __launch_bounds__(256) void k_mix2(
    const float* __restrict__ w, const float* __restrict__ bias,
    float* __restrict__ ws, float* __restrict__ out) {
  __shared__ float As[16][33];
  __shared__ float Bs[16][65];
  int t = threadIdx.x;
  int tx = t & 15, ty = t >> 4;
  int n0 = blockIdx.x * 64, m0 = blockIdx.y * 32;
  const float* A = ws + WS_HIDDEN;
  float acc[2][4] = {{0.f, 0.f, 0.f, 0.f}, {0.f, 0.f, 0.f, 0.f}};
  int kk = t & 15, r = t >> 4;
  for (int k0 = 0; k0 < HID; k0 += 16) {
    As[kk][r]      = A[(m0 + r) * HID + k0 + kk];
    As[kk][r + 16] = A[(m0 + r + 16) * HID + k0 + kk];
#pragma unroll
    for (int j = 0; j < 4; j++) {
      int idx = t + 256 * j;
      int bk = idx >> 6, nn = idx & 63;
      int col = n0 + nn;
      Bs[bk][nn] = (col < DIMV) ? w[(k0 + bk) * DIMV + col] : 0.f;
    }
    __syncthreads();
#pragma unroll
    for (int q = 0; q < 16; q++) {
      float a0 = As[q][ty * 2], a1 = As[q][ty * 2 + 1];
#pragma unroll
      for (int j = 0; j < 4; j++) {
        float b = Bs[q][tx * 4 + j];
        acc[0][j] += a0 * b;
        acc[1][j] += a1 * b;
      }
    }
    __syncthreads();
  }
#pragma unroll
  for (int i = 0; i < 2; i++) {
    int m = m0 + ty * 2 + i;
#pragma unroll
    for (int j = 0; j < 4; j++) {
      int col = n0 + tx * 4 + j;
      if (col >= DIMV) continue;
      float rr = acc[i][j] + bias[col];
      if (col < 2) {
        float v = ws[WS_POS + m * 2 + col] + rr;
        ws[WS_POS + m * 2 + col] = v;
        out[m * 4 + col] = v;
      } else if (col == 2) {
        float v = ws[WS_OCC + m] + rr;
        ws[WS_OCC + m] = v;
        out[m * 4 + 2] = v;
      } else if (col == 3) {
        float v = ws[WS_EXPD + m] + rr;
        ws[WS_EXPD + m] = v;
        out[m * 4 + 3] = v;
      } else {
        ws[WS_FEATS + m * 384 + (col - 4)] += rr;
      }
    }
  }
}

// ---------------------------------------------------------------------------
extern "C" void kernel_launch(void* const* d_in, const int* in_sizes, int n_in,
                              void* d_out, int out_size, void* d_ws, size_t ws_size,
                              hipStream_t stream) {
  const float* fg = (const float*)d_in[0];
  const float* hg = (const float*)d_in[1];
  const float* qf = (const float*)d_in[2];
  const float* hq = (const float*)d_in[3];
  const float* w1 = (const float*)d_in[4];
  const float* b1 = (const float*)d_in[5];
  const float* w2 = (const float*)d_in[6];
  const float* b2 = (const float*)d_in[7];
  const float* w3 = (const float*)d_in[8];
  const float* b3 = (const float*)d_in[9];
  const float* w4 = (const float*)d_in[10];
  const float* b4 = (const float*)d_in[11];
  const float* w5 = (const float*)d_in[12];
  const float* b5 = (const float*)d_in[13];
  const float* wi = (const float*)d_in[14];
  const float* bi = (const float*)d_in[15];
  const float* wo = (const float*)d_in[16];
  const float* bo = (const float*)d_in[17];
  float* ws = (float*)d_ws;
  float* out = (float*)d_out;

  k_prep<<<2578, 256, 0, stream>>>(fg, qf, hq, w3, ws);
  k_cv<<<dim3(64, 32), 256, 0, stream>>>(qf, fg, ws);
  k_head<<<NQ, 256, 0, stream>>>(w1, b1, w2, b2, b3, w4, b4, w5, b5, ws);
  for (int it = 0; it < 4; it++) {
    k_corr<<<256, 256, 0, stream>>>(fg, hg, ws);
    k_mix1<<<dim3(8, 32), 256, 0, stream>>>(wi, bi, ws);
    k_mix2<<<dim3(7, 32), 256, 0, stream>>>(wo, bo, ws, out);
  }
}

// Round 2
// 948.487 us; speedup vs baseline: 2.2418x; 2.2418x over previous
//
#include <hip/hip_runtime.h>
#include <math.h>

// ---------------------------------------------------------------------------
// TAPIR forward, all f32.
// fg[64,64,256] hg[128,128,128] qf[1024,256] hq[1024,128] -> out[1024,4]
// ---------------------------------------------------------------------------

#define NQ 1024
#define TEMPF 20.0f
#define DIMV 388
#define INDIM 535
#define INPITCH 544
#define HID 512

// workspace layout (float offsets)
#define WS_CV      0                          // 1024*4096
#define WS_FGAVG   (WS_CV + NQ*4096)          // 32*32*256
#define WS_POS     (WS_FGAVG + 262144)        // 1024*2
#define WS_OCC     (WS_POS + NQ*2)            // 1024
#define WS_EXPD    (WS_OCC + NQ)              // 1024
#define WS_FEATS   (WS_EXPD + NQ)             // 1024*384
#define WS_MLPIN   (WS_FEATS + NQ*384)        // 1024*544 (pitch-padded 535)
#define WS_HIDDEN  (WS_MLPIN + NQ*INPITCH)    // 1024*512
#define WS_W3T     (WS_HIDDEN + NQ*HID)       // 4608 transposed hid3_w [ic][tap][oc]
// overlays (dead regions at time of use):
#define WS_PART    WS_MLPIN                   // 1024*16*4 softmax partials (m,s,sx,sy)
#define WS_SUM3    WS_HIDDEN                  // 1024*16*32 hid3 relu-sums

// ---------------------------------------------------------------------------
// prep: fg 2x2 avg pyramid level, feats = concat(hq, qf), w3 transpose
// ---------------------------------------------------------------------------
__global__ __launch_bounds__(256) void k_prep(
    const float* __restrict__ fg, const float* __restrict__ qf,
    const float* __restrict__ hq, const float* __restrict__ w3,
    float* __restrict__ ws) {
  int i = blockIdx.x * 256 + threadIdx.x;
  if (i < 262144) {
    int c = i & 255, ox = (i >> 8) & 31, oy = i >> 13;
    const float* b = fg + (((oy * 2) * 64 + ox * 2) << 8) + c;
    ws[WS_FGAVG + i] = 0.25f * (b[0] + b[256] + b[16384] + b[16384 + 256]);
  } else if (i < 262144 + 393216) {
    int j = i - 262144;
    int n = j / 384, c = j - n * 384;
    ws[WS_FEATS + j] = (c < 128) ? hq[n * 128 + c] : qf[n * 256 + c - 128];
  } else if (i < 262144 + 393216 + 4608) {
    int j = i - (262144 + 393216);
    int oc = j & 31, rest = j >> 5;
    int tap = rest % 9, ic = rest / 9;
    ws[WS_W3T + j] = w3[(oc * 16 + ic) * 9 + tap];
  }
}

// ---------------------------------------------------------------------------
// cost volume: cv[n][p] = sum_c qf[n][c] * fg[p][c]
// ---------------------------------------------------------------------------
__global__ __launch_bounds__(256) void k_cv(
    const float* __restrict__ qf, const float* __restrict__ fg,
    float* __restrict__ ws) {
  __shared__ float As[16][33];
  __shared__ float Bs[64][17];
  int t = threadIdx.x;
  int tx = t & 15, ty = t >> 4;
  int p0 = blockIdx.x * 64, m0 = blockIdx.y * 32;
  float acc[2][4] = {{0.f, 0.f, 0.f, 0.f}, {0.f, 0.f, 0.f, 0.f}};
  int kk = t & 15, r = t >> 4;
  for (int k0 = 0; k0 < 256; k0 += 16) {
    As[kk][r]      = qf[(m0 + r) * 256 + k0 + kk];
    As[kk][r + 16] = qf[(m0 + r + 16) * 256 + k0 + kk];
#pragma unroll
    for (int j = 0; j < 4; j++)
      Bs[r + 16 * j][kk] = fg[(p0 + r + 16 * j) * 256 + k0 + kk];
    __syncthreads();
#pragma unroll
    for (int k = 0; k < 16; k++) {
      float a0 = As[k][ty * 2], a1 = As[k][ty * 2 + 1];
#pragma unroll
      for (int j = 0; j < 4; j++) {
        float b = Bs[tx * 4 + j][k];
        acc[0][j] += a0 * b;
        acc[1][j] += a1 * b;
      }
    }
    __syncthreads();
  }
#pragma unroll
  for (int i = 0; i < 2; i++) {
    float4 v = make_float4(acc[i][0], acc[i][1], acc[i][2], acc[i][3]);
    *(float4*)&ws[WS_CV + (m0 + ty * 2 + i) * 4096 + p0 + tx * 4] = v;
  }
}

// ---------------------------------------------------------------------------
// head stripe kernel: 1 block = (query, 4-row stripe). 16384 blocks.
// phase1 (all 4 waves): hid1 -> occ stripe (6 rows x 16 ch) in LDS
// then wave r2: hid2 + online-softmax partials (shuffle-only)
//      wave r3: hid3 stride-2 conv + relu-sum partials
// ---------------------------------------------------------------------------
__global__ __launch_bounds__(256, 4) void k_head_stripe(
    const float* __restrict__ h1w, const float* __restrict__ h1b,
    const float* __restrict__ h2w, const float* __restrict__ h2b,
    const float* __restrict__ h3b, float* __restrict__ ws) {
  __shared__ float cvs[8 * 66];          // cv rows y0-2..y0+5, x -1..64
  __shared__ float occ[6 * 16 * 72];     // occ rows y0-1..y0+4, x at idx x+4

  const int bx = blockIdx.x;
  const int q = bx >> 4, st = bx & 15;
  const int y0 = st * 4;
  const int t = threadIdx.x;
  const int wv = t >> 6, lane = t & 63;
  const int r3 = bx & 3, r2 = (bx + 1) & 3;
  const float* cv = ws + WS_CV + q * 4096;

  // init: zero occ (covers halos + out-of-range rows), load cv stripe
  {
    float4 z = make_float4(0.f, 0.f, 0.f, 0.f);
    float4* o4 = (float4*)occ;
    for (int i = t; i < 6 * 16 * 72 / 4; i += 256) o4[i] = z;
  }
#pragma unroll
  for (int j = 0; j < 2; j++) {
    int i = t + 256 * j;
    int lr = i >> 6, x = i & 63;
    int g = y0 - 2 + lr;
    cvs[lr * 66 + x + 1] = (g >= 0 && g < 64) ? cv[g * 64 + x] : 0.f;
  }
  if (t < 16) cvs[(t >> 1) * 66 + (t & 1) * 65] = 0.f;
  __syncthreads();

  // ---- phase1: hid1 conv, occ rows r=0..5 (yo = y0-1+r) ----
  {
    const int x = lane;
    const int chg = wv * 4;
    float w1r[4][9], b1r[4];
#pragma unroll
    for (int k = 0; k < 4; k++) {
      b1r[k] = h1b[chg + k];
#pragma unroll
      for (int j = 0; j < 9; j++) w1r[k][j] = h1w[(chg + k) * 9 + j];
    }
    for (int r = 0; r < 6; r++) {
      int yo = y0 - 1 + r;
      if (yo >= 0 && yo <= 63) {
        float p[9];
#pragma unroll
        for (int ky = 0; ky < 3; ky++) {
          const float* cp = &cvs[(r + ky) * 66 + x];
          p[3 * ky] = cp[0]; p[3 * ky + 1] = cp[1]; p[3 * ky + 2] = cp[2];
        }
#pragma unroll
        for (int k = 0; k < 4; k++) {
          float a = b1r[k];
#pragma unroll
          for (int j = 0; j < 9; j++) a += w1r[k][j] * p[j];
          occ[((r * 16) + (chg + k)) * 72 + x + 4] = fmaxf(a, 0.f);
        }
      }
    }
  }
  __syncthreads();
  if (wv != r2 && wv != r3) return;

  if (wv == r2) {
    // ---- phase2: hid2 conv (4 px/thread) + softmax partials ----
    const int row = lane & 3;      // pmap local row (y = y0+row)
    const int xg = lane >> 2;      // 0..15
    const int x0 = xg * 4;
    float pm0 = 0.f, pm1 = 0.f, pm2 = 0.f, pm3 = 0.f;
    for (int ch = 0; ch < 16; ch++) {
#pragma unroll
      for (int ky = 0; ky < 3; ky++) {
        const float* bp = &occ[(((row + ky) * 16) + ch) * 72 + x0];
        float fl = bp[3];
        float4 fm = *(const float4*)(bp + 4);
        float fr = bp[8];
        float wa = h2w[ch * 9 + 3 * ky], wb = h2w[ch * 9 + 3 * ky + 1],
              wc = h2w[ch * 9 + 3 * ky + 2];
        pm0 += wa * fl   + wb * fm.x + wc * fm.y;
        pm1 += wa * fm.x + wb * fm.y + wc * fm.z;
        pm2 += wa * fm.y + wb * fm.z + wc * fm.w;
        pm3 += wa * fm.z + wb * fm.w + wc * fr;
      }
    }
    float bb = h2b[0];
    float v0 = (pm0 + bb) * TEMPF, v1 = (pm1 + bb) * TEMPF;
    float v2 = (pm2 + bb) * TEMPF, v3 = (pm3 + bb) * TEMPF;
    float mg = fmaxf(fmaxf(v0, v1), fmaxf(v2, v3));
#pragma unroll
    for (int off = 4; off < 64; off <<= 1) mg = fmaxf(mg, __shfl_xor(mg, off));
    float e0 = __expf(v0 - mg), e1 = __expf(v1 - mg);
    float e2 = __expf(v2 - mg), e3 = __expf(v3 - mg);
    float s = e0 + e1 + e2 + e3;
    float sx = e0 * (float)x0 + e1 * (float)(x0 + 1) + e2 * (float)(x0 + 2) +
               e3 * (float)(x0 + 3);
#pragma unroll
    for (int off = 4; off < 64; off <<= 1) {
      s += __shfl_xor(s, off);
      sx += __shfl_xor(sx, off);
    }
    float M = mg, S = s, SX = sx, SY = s * (float)(y0 + row);
#pragma unroll
    for (int off = 1; off < 4; off <<= 1) {
      float Mo = __shfl_xor(M, off), So = __shfl_xor(S, off);
      float SXo = __shfl_xor(SX, off), SYo = __shfl_xor(SY, off);
      float Mn = fmaxf(M, Mo);
      float c1 = __expf(M - Mn), c2 = __expf(Mo - Mn);
      S = S * c1 + So * c2; SX = SX * c1 + SXo * c2; SY = SY * c1 + SYo * c2;
      M = Mn;
    }
    if (lane == 0)
      *(float4*)&ws[WS_PART + (q * 16 + st) * 4] = make_float4(M, S, SX, SY);
  } else {
    // ---- phase3: hid3 stride-2 conv, relu-sum. 64 lanes cover 32oc x 32ox x 2oy
    const float* w3t = ws + WS_W3T;
    const int oc0 = (lane & 7) * 4;
    const int oxq = lane >> 3;           // ox = 4*oxq + j
    float acc[8][4];
#pragma unroll
    for (int i = 0; i < 8; i++) {
      acc[i][0] = 0.f; acc[i][1] = 0.f; acc[i][2] = 0.f; acc[i][3] = 0.f;
    }
    for (int ic = 0; ic < 16; ic++) {
      float4 wr[9];
#pragma unroll
      for (int tap = 0; tap < 9; tap++)
        wr[tap] = *(const float4*)(w3t + (ic * 9 + tap) * 32 + oc0);
#pragma unroll
      for (int oy = 0; oy < 2; oy++) {
        float rb[3][9];
#pragma unroll
        for (int ky = 0; ky < 3; ky++) {
          const float* rp = &occ[(((2 * oy + ky + 1) * 16) + ic) * 72 + 4 + 8 * oxq];
          float4 a4 = *(const float4*)rp;
          float4 c4 = *(const float4*)(rp + 4);
          rb[ky][0] = a4.x; rb[ky][1] = a4.y; rb[ky][2] = a4.z; rb[ky][3] = a4.w;
          rb[ky][4] = c4.x; rb[ky][5] = c4.y; rb[ky][6] = c4.z; rb[ky][7] = c4.w;
          rb[ky][8] = rp[8];
        }
#pragma unroll
        for (int j = 0; j < 4; j++) {
          float* A = acc[oy * 4 + j];
#pragma unroll
          for (int ky = 0; ky < 3; ky++) {
#pragma unroll
            for (int kx = 0; kx < 3; kx++) {
              float pv = rb[ky][2 * j + kx];
              float4 w = wr[3 * ky + kx];
              A[0] += w.x * pv; A[1] += w.y * pv;
              A[2] += w.z * pv; A[3] += w.w * pv;
            }
          }
        }
      }
    }
    float bb0 = h3b[oc0], bb1 = h3b[oc0 + 1], bb2 = h3b[oc0 + 2], bb3 = h3b[oc0 + 3];
    float s0 = 0.f, s1 = 0.f, s2 = 0.f, s3 = 0.f;
#pragma unroll
    for (int i = 0; i < 8; i++) {
      s0 += fmaxf(acc[i][0] + bb0, 0.f);
      s1 += fmaxf(acc[i][1] + bb1, 0.f);
      s2 += fmaxf(acc[i][2] + bb2, 0.f);
      s3 += fmaxf(acc[i][3] + bb3, 0.f);
    }
#pragma unroll
    for (int off = 8; off < 64; off <<= 1) {
      s0 += __shfl_xor(s0, off); s1 += __shfl_xor(s1, off);
      s2 += __shfl_xor(s2, off); s3 += __shfl_xor(s3, off);
    }
    if (lane < 8)
      *(float4*)&ws[WS_SUM3 + (q * 16 + st) * 32 + oc0] =
          make_float4(s0, s1, s2, s3);
  }
}

// ---------------------------------------------------------------------------
// head merge: combine 16 stripe partials per query -> pos, occ, expd
// 1 wave per query, 4 queries/block.
// ---------------------------------------------------------------------------
__global__ __launch_bounds__(256) void k_head_merge(
    const float* __restrict__ w4, const float* __restrict__ b4,
    const float* __restrict__ w5, const float* __restrict__ b5,
    float* __restrict__ ws) {
  __shared__ float sums_s[4][32];
  __shared__ float o4s[4][16];
  int t = threadIdx.x, wv = t >> 6, lane = t & 63;
  int q = blockIdx.x * 4 + wv;

  // softmax merge over 16 stripes
  float M = -1e30f, S = 0.f, SX = 0.f, SY = 0.f;
  if (lane < 16) {
    float4 pv = *(const float4*)&ws[WS_PART + (q * 16 + lane) * 4];
    M = pv.x; S = pv.y; SX = pv.z; SY = pv.w;
  }
#pragma unroll
  for (int off = 1; off < 16; off <<= 1) {
    float Mo = __shfl_xor(M, off), So = __shfl_xor(S, off);
    float SXo = __shfl_xor(SX, off), SYo = __shfl_xor(SY, off);
    float Mn = fmaxf(M, Mo);
    float c1 = __expf(M - Mn), c2 = __expf(Mo - Mn);
    S = S * c1 + So * c2; SX = SX * c1 + SXo * c2; SY = SY * c1 + SYo * c2;
    M = Mn;
  }
  if (lane == 0) {
    ws[WS_POS + q * 2 + 0] = (SX / S) * 8.0f;
    ws[WS_POS + q * 2 + 1] = (SY / S) * 8.0f;
  }

  // hid3 sums over 16 stripes
  int ch = lane & 31, half = lane >> 5;
  float sm = 0.f;
#pragma unroll
  for (int s8 = 0; s8 < 8; s8++)
    sm += ws[WS_SUM3 + (q * 16 + half * 8 + s8) * 32 + ch];
  sm += __shfl_xor(sm, 32);
  if (lane < 32) sums_s[wv][lane] = sm * (1.f / 1024.f);
  __syncthreads();
  if (lane < 16) {
    float a = b4[lane];
#pragma unroll
    for (int i = 0; i < 32; i++) a += sums_s[wv][i] * w4[i * 16 + lane];
    o4s[wv][lane] = fmaxf(a, 0.f);
  }
  __syncthreads();
  if (lane < 2) {
    float r = b5[lane];
#pragma unroll
    for (int j = 0; j < 16; j++) r += o4s[wv][j] * w5[j * 2 + lane];
    if (lane == 0) ws[WS_OCC + q] = r;
    else           ws[WS_EXPD + q] = r;
  }
}

// ---------------------------------------------------------------------------
// correlation + mlp_in assembly. 1 wave = 1 query, 4 queries/block.
// ---------------------------------------------------------------------------
__global__ __launch_bounds__(256) void k_corr(
    const float* __restrict__ fg, const float* __restrict__ hg,
    float* __restrict__ ws) {
  __shared__ float dbuf[4][64];
  int t = threadIdx.x;
  int wv = t >> 6, lane = t & 63;
  int n = blockIdx.x * 4 + wv;
  const float* feats = ws + WS_FEATS + n * 384;
  float posx = ws[WS_POS + n * 2 + 0];
  float posy = ws[WS_POS + n * 2 + 1];
  float* mi = ws + WS_MLPIN + n * INPITCH;

  for (int col = lane; col < 388; col += 64) {
    float v;
    if (col < 2) v = 0.f;
    else if (col == 2) v = ws[WS_OCC + n];
    else if (col == 3) v = ws[WS_EXPD + n];
    else v = feats[col - 4];
    mi[col] = v;
  }

  int a = lane >> 3, b = lane & 7;
#pragma unroll
  for (int L = 0; L < 3; L++) {
    const float* grid;
    int Hg, Wg, C, qoff;
    float scl;
    if (L == 0)      { grid = hg;             Hg = 128; Wg = 128; C = 128; qoff = 0;   scl = 0.25f; }
    else if (L == 1) { grid = fg;             Hg = 64;  Wg = 64;  C = 256; qoff = 128; scl = 0.125f; }
    else             { grid = ws + WS_FGAVG;  Hg = 32;  Wg = 32;  C = 256; qoff = 128; scl = 0.0625f; }
    float cy = posy * scl, cx = posx * scl;
    float fy = floorf(cy), fx = floorf(cx);
    int iy = (int)fy, ix = (int)fx;
    float wy = cy - fy, wx = cx - fx;
    int row = iy + a - 3; row = row < 0 ? 0 : (row > Hg - 1 ? Hg - 1 : row);
    int col = ix + b - 3; col = col < 0 ? 0 : (col > Wg - 1 ? Wg - 1 : col);
    const float* gp = grid + (row * Wg + col) * C;
    const float* qp = feats + qoff;
    float acc = 0.f;
    for (int c = 0; c < C; c += 4) {
      float4 g = *(const float4*)(gp + c);
      float4 qv = *(const float4*)(qp + c);
      acc += g.x * qv.x + g.y * qv.y + g.z * qv.z + g.w * qv.w;
    }
    __syncthreads();
    dbuf[wv][lane] = acc;
    __syncthreads();
    if (lane < 49) {
      int sa = lane / 7, sb = lane % 7;
      float d00 = dbuf[wv][sa * 8 + sb],     d01 = dbuf[wv][sa * 8 + sb + 1];
      float d10 = dbuf[wv][sa * 8 + sb + 8], d11 = dbuf[wv][sa * 8 + sb + 9];
      float corr = (1.f - wy) * (1.f - wx) * d00 + (1.f - wy) * wx * d01 +
                   wy * (1.f - wx) * d10 + wy * wx * d11;
      mi[388 + L * 49 + lane] = corr;
    }
  }
}

// ---------------------------------------------------------------------------
__device__ __forceinline__ float gelu_tanh(float x) {
  float z = 0.7978845608028654f * (x + 0.044715f * x * x * x);
  z = fminf(fmaxf(z, -15.f), 15.f);
  float e = __expf(2.f * z);
  float th = (e - 1.f) / (e + 1.f);
  return 0.5f * x * (1.f + th);
}

__global__ __launch_bounds__(256) void k_mix1(
    const float* __restrict__ w, const float* __restrict__ bias,
    float* __restrict__ ws) {
  __shared__ float As[16][33];
  __shared__ float Bs[16][65];
  int t = threadIdx.x;
  int tx = t & 15, ty = t >> 4;
  int n0 = blockIdx.x * 64, m0 = blockIdx.y * 32;
  const float* A = ws + WS_MLPIN;
  float acc[2][4] = {{0.f, 0.f, 0.f, 0.f}, {0.f, 0.f, 0.f, 0.f}};
  int kk = t & 15, r = t >> 4;
  for (int k0 = 0; k0 < INDIM; k0 += 16) {
    int k = k0 + kk;
    As[kk][r]      = (k < INDIM) ? A[(m0 + r) * INPITCH + k] : 0.f;
    As[kk][r + 16] = (k < INDIM) ? A[(m0 + r + 16) * INPITCH + k] : 0.f;
#pragma unroll
    for (int j = 0; j < 4; j++) {
      int idx = t + 256 * j;
      int bk = idx >> 6, nn = idx & 63;
      Bs[bk][nn] = (k0 + bk < INDIM) ? w[(k0 + bk) * HID + n0 + nn] : 0.f;
    }
    __syncthreads();
#pragma unroll
    for (int qq = 0; qq < 16; qq++) {
      float a0 = As[qq][ty * 2], a1 = As[qq][ty * 2 + 1];
#pragma unroll
      for (int j = 0; j < 4; j++) {
        float b = Bs[qq][tx * 4 + j];
        acc[0][j] += a0 * b;
        acc[1][j] += a1 * b;
      }
    }
    __syncthreads();
  }
  float* Hd = ws + WS_HIDDEN;
#pragma unroll
  for (int i = 0; i < 2; i++) {
    int m = m0 + ty * 2 + i;
#pragma unroll
    for (int j = 0; j < 4; j++) {
      int nn = n0 + tx * 4 + j;
      Hd[m * HID + nn] = gelu_tanh(acc[i][j] + bias[nn]);
    }
  }
}

__global__ __launch_bounds__(256) void k_mix2(
    const float* __restrict__ w, const float* __restrict__ bias,
    float* __restrict__ ws, float* __restrict__ out) {
  __shared__ float As[16][33];
  __shared__ float Bs[16][65];
  int t = threadIdx.x;
  int tx = t & 15, ty = t >> 4;
  int n0 = blockIdx.x * 64, m0 = blockIdx.y * 32;
  const float* A = ws + WS_HIDDEN;
  float acc[2][4] = {{0.f, 0.f, 0.f, 0.f}, {0.f, 0.f, 0.f, 0.f}};
  int kk = t & 15, r = t >> 4;
  for (int k0 = 0; k0 < HID; k0 += 16) {
    As[kk][r]      = A[(m0 + r) * HID + k0 + kk];
    As[kk][r + 16] = A[(m0 + r + 16) * HID + k0 + kk];
#pragma unroll
    for (int j = 0; j < 4; j++) {
      int idx = t + 256 * j;
      int bk = idx >> 6, nn = idx & 63;
      int col = n0 + nn;
      Bs[bk][nn] = (col < DIMV) ? w[(k0 + bk) * DIMV + col] : 0.f;
    }
    __syncthreads();
#pragma unroll
    for (int qq = 0; qq < 16; qq++) {
      float a0 = As[qq][ty * 2], a1 = As[qq][ty * 2 + 1];
#pragma unroll
      for (int j = 0; j < 4; j++) {
        float b = Bs[qq][tx * 4 + j];
        acc[0][j] += a0 * b;
        acc[1][j] += a1 * b;
      }
    }
    __syncthreads();
  }
#pragma unroll
  for (int i = 0; i < 2; i++) {
    int m = m0 + ty * 2 + i;
#pragma unroll
    for (int j = 0; j < 4; j++) {
      int col = n0 + tx * 4 + j;
      if (col >= DIMV) continue;
      float rr = acc[i][j] + bias[col];
      if (col < 2) {
        float v = ws[WS_POS + m * 2 + col] + rr;
        ws[WS_POS + m * 2 + col] = v;
        out[m * 4 + col] = v;
      } else if (col == 2) {
        float v = ws[WS_OCC + m] + rr;
        ws[WS_OCC + m] = v;
        out[m * 4 + 2] = v;
      } else if (col == 3) {
        float v = ws[WS_EXPD + m] + rr;
        ws[WS_EXPD + m] = v;
        out[m * 4 + 3] = v;
      } else {
        ws[WS_FEATS + m * 384 + (col - 4)] += rr;
      }
    }
  }
}

// ---------------------------------------------------------------------------
extern "C" void kernel_launch(void* const* d_in, const int* in_sizes, int n_in,
                              void* d_out, int out_size, void* d_ws, size_t ws_size,
                              hipStream_t stream) {
  const float* fg = (const float*)d_in[0];
  const float* hg = (const float*)d_in[1];
  const float* qf = (const float*)d_in[2];
  const float* hq = (const float*)d_in[3];
  const float* w1 = (const float*)d_in[4];
  const float* b1 = (const float*)d_in[5];
  const float* w2 = (const float*)d_in[6];
  const float* b2 = (const float*)d_in[7];
  const float* w3 = (const float*)d_in[8];
  const float* b3 = (const float*)d_in[9];
  const float* w4 = (const float*)d_in[10];
  const float* b4 = (const float*)d_in[11];
  const float* w5 = (const float*)d_in[12];
  const float* b5 = (const float*)d_in[13];
  const float* wi = (const float*)d_in[14];
  const float* bi = (const float*)d_in[15];
  const float* wo = (const float*)d_in[16];
  const float* bo = (const float*)d_in[17];
  float* ws = (float*)d_ws;
  float* out = (float*)d_out;

  k_prep<<<2578, 256, 0, stream>>>(fg, qf, hq, w3, ws);
  k_cv<<<dim3(64, 32), 256, 0, stream>>>(qf, fg, ws);
  k_head_stripe<<<16384, 256, 0, stream>>>(w1, b1, w2, b2, b3, ws);
  k_head_merge<<<256, 256, 0, stream>>>(w4, b4, w5, b5, ws);
  for (int it = 0; it < 4; it++) {
    k_corr<<<256, 256, 0, stream>>>(fg, hg, ws);
    k_mix1<<<dim3(8, 32), 256, 0, stream>>>(wi, bi, ws);
    k_mix2<<<dim3(7, 32), 256, 0, stream>>>(wo, bo, ws, out);
  }
}

// Round 3
// 946.696 us; speedup vs baseline: 2.2460x; 1.0019x over previous
//
#include <hip/hip_runtime.h>
#include <math.h>

// ---------------------------------------------------------------------------
// TAPIR forward, all f32.
// fg[64,64,256] hg[128,128,128] qf[1024,256] hq[1024,128] -> out[1024,4]
// ---------------------------------------------------------------------------

#define NQ 1024
#define TEMPF 20.0f
#define DIMV 388
#define INDIM 535
#define INPITCH 544
#define HID 512

// workspace layout (float offsets)
#define WS_CV      0                          // 1024*4096
#define WS_FGAVG   (WS_CV + NQ*4096)          // 32*32*256
#define WS_POS     (WS_FGAVG + 262144)        // 1024*2
#define WS_OCC     (WS_POS + NQ*2)            // 1024
#define WS_EXPD    (WS_OCC + NQ)              // 1024
#define WS_FEATS   (WS_EXPD + NQ)             // 1024*384
#define WS_MLPIN   (WS_FEATS + NQ*384)        // 1024*544 (pitch-padded 535)
#define WS_HIDDEN  (WS_MLPIN + NQ*INPITCH)    // 1024*512
#define WS_W3T     (WS_HIDDEN + NQ*HID)       // 4608 transposed hid3_w [ic][tap][oc]
// overlays (dead regions at time of use):
#define WS_PART    WS_MLPIN                   // 1024*16*4 softmax partials (m,s,sx,sy)
#define WS_SUM3    WS_HIDDEN                  // 1024*16*32 hid3 relu-sums

#define OPITCH 76                             // occ LDS x-pitch (banks decorrelated)

// ---------------------------------------------------------------------------
// prep: fg 2x2 avg pyramid level, feats = concat(hq, qf), w3 transpose
// ---------------------------------------------------------------------------
__global__ __launch_bounds__(256) void k_prep(
    const float* __restrict__ fg, const float* __restrict__ qf,
    const float* __restrict__ hq, const float* __restrict__ w3,
    float* __restrict__ ws) {
  int i = blockIdx.x * 256 + threadIdx.x;
  if (i < 262144) {
    int c = i & 255, ox = (i >> 8) & 31, oy = i >> 13;
    const float* b = fg + (((oy * 2) * 64 + ox * 2) << 8) + c;
    ws[WS_FGAVG + i] = 0.25f * (b[0] + b[256] + b[16384] + b[16384 + 256]);
  } else if (i < 262144 + 393216) {
    int j = i - 262144;
    int n = j / 384, c = j - n * 384;
    ws[WS_FEATS + j] = (c < 128) ? hq[n * 128 + c] : qf[n * 256 + c - 128];
  } else if (i < 262144 + 393216 + 4608) {
    int j = i - (262144 + 393216);
    int oc = j & 31, rest = j >> 5;
    int tap = rest % 9, ic = rest / 9;
    ws[WS_W3T + j] = w3[(oc * 16 + ic) * 9 + tap];
  }
}

// ---------------------------------------------------------------------------
// cost volume: cv[n][p] = sum_c qf[n][c] * fg[p][c]
// ---------------------------------------------------------------------------
__global__ __launch_bounds__(256) void k_cv(
    const float* __restrict__ qf, const float* __restrict__ fg,
    float* __restrict__ ws) {
  __shared__ float As[16][33];
  __shared__ float Bs[64][17];
  int t = threadIdx.x;
  int tx = t & 15, ty = t >> 4;
  int p0 = blockIdx.x * 64, m0 = blockIdx.y * 32;
  float acc[2][4] = {{0.f, 0.f, 0.f, 0.f}, {0.f, 0.f, 0.f, 0.f}};
  int kk = t & 15, r = t >> 4;
  for (int k0 = 0; k0 < 256; k0 += 16) {
    As[kk][r]      = qf[(m0 + r) * 256 + k0 + kk];
    As[kk][r + 16] = qf[(m0 + r + 16) * 256 + k0 + kk];
#pragma unroll
    for (int j = 0; j < 4; j++)
      Bs[r + 16 * j][kk] = fg[(p0 + r + 16 * j) * 256 + k0 + kk];
    __syncthreads();
#pragma unroll
    for (int k = 0; k < 16; k++) {
      float a0 = As[k][ty * 2], a1 = As[k][ty * 2 + 1];
#pragma unroll
      for (int j = 0; j < 4; j++) {
        float b = Bs[tx * 4 + j][k];
        acc[0][j] += a0 * b;
        acc[1][j] += a1 * b;
      }
    }
    __syncthreads();
  }
#pragma unroll
  for (int i = 0; i < 2; i++) {
    float4 v = make_float4(acc[i][0], acc[i][1], acc[i][2], acc[i][3]);
    *(float4*)&ws[WS_CV + (m0 + ty * 2 + i) * 4096 + p0 + tx * 4] = v;
  }
}

// ---------------------------------------------------------------------------
// head stripe kernel: 1 block = (query, 4-row stripe). 16384 blocks.
// All 4 waves work every phase:
//  P1: hid1 -> occ stripe (16ch x 6 rows) in LDS, wave = 4 channels
//  P3: hid3 s2-conv, wave = (oy, ox-half) quadrant, relu-sum -> part3
//  P2: hid2, wave = channel quarter -> pm4 partials
//  merge: wave0 softmax -> WS_PART, wave1 oc-sums -> WS_SUM3
// ---------------------------------------------------------------------------
__global__ __launch_bounds__(256, 4) void k_head_stripe(
    const float* __restrict__ h1w, const float* __restrict__ h1b,
    const float* __restrict__ h2w, const float* __restrict__ h2b,
    const float* __restrict__ h3b, float* __restrict__ ws) {
  __shared__ float cvs[8 * 66];            // cv rows y0-2..y0+5, x -1..64
  __shared__ float occ[16 * 6 * OPITCH];   // [ch][r][x+4]
  __shared__ float pm4[4][64][4];          // hid2 partials [chq][(row,xg)][px]
  __shared__ float part3[4][32];           // hid3 quadrant sums [wave][oc]

  const int bx = blockIdx.x;
  const int q = bx >> 4, st = bx & 15;
  const int y0 = st * 4;
  const int t = threadIdx.x;
  const int wv = t >> 6, lane = t & 63;
  const float* cv = ws + WS_CV + q * 4096;

  // init: zero occ (covers halos + out-of-range rows), load cv stripe
  {
    float4 z = make_float4(0.f, 0.f, 0.f, 0.f);
    float4* o4 = (float4*)occ;
    for (int i = t; i < 16 * 6 * OPITCH / 4; i += 256) o4[i] = z;
  }
#pragma unroll
  for (int j = 0; j < 2; j++) {
    int i = t + 256 * j;
    int lr = i >> 6, x = i & 63;
    int g = y0 - 2 + lr;
    cvs[lr * 66 + x + 1] = (g >= 0 && g < 64) ? cv[g * 64 + x] : 0.f;
  }
  if (t < 16) cvs[(t >> 1) * 66 + (t & 1) * 65] = 0.f;
  __syncthreads();

  // ---- P1: hid1 conv, occ rows r=0..5 (yo = y0-1+r), wave = 4 channels ----
  {
    const int x = lane;
    const int chg = wv * 4;
    float w1r[4][9], b1r[4];
#pragma unroll
    for (int k = 0; k < 4; k++) {
      b1r[k] = h1b[chg + k];
#pragma unroll
      for (int j = 0; j < 9; j++) w1r[k][j] = h1w[(chg + k) * 9 + j];
    }
    for (int r = 0; r < 6; r++) {
      int yo = y0 - 1 + r;
      if (yo >= 0 && yo <= 63) {
        float p[9];
#pragma unroll
        for (int ky = 0; ky < 3; ky++) {
          const float* cp = &cvs[(r + ky) * 66 + x];
          p[3 * ky] = cp[0]; p[3 * ky + 1] = cp[1]; p[3 * ky + 2] = cp[2];
        }
#pragma unroll
        for (int k = 0; k < 4; k++) {
          float a = b1r[k];
#pragma unroll
          for (int j = 0; j < 9; j++) a += w1r[k][j] * p[j];
          occ[((chg + k) * 6 + r) * OPITCH + x + 4] = fmaxf(a, 0.f);
        }
      }
    }
  }
  __syncthreads();

  // ---- P3: hid3 stride-2 conv quadrant (oy = wv&1, ox-half = wv>>1) ----
  {
    const float* w3t = ws + WS_W3T;
    const int oc0 = (lane & 7) * 4;
    const int oxb = 16 * (wv >> 1) + 2 * (lane >> 3);   // this lane: ox = oxb, oxb+1
    const int oy = wv & 1;
    float acc[2][4] = {{0.f, 0.f, 0.f, 0.f}, {0.f, 0.f, 0.f, 0.f}};
    for (int ic = 0; ic < 16; ic++) {
      float4 wr[9];
#pragma unroll
      for (int tap = 0; tap < 9; tap++)
        wr[tap] = *(const float4*)(w3t + (ic * 9 + tap) * 32 + oc0);
      float rb[3][5];
#pragma unroll
      for (int ky = 0; ky < 3; ky++) {
        const float* rp = &occ[(ic * 6 + (2 * oy + 1 + ky)) * OPITCH + 4 + 2 * oxb];
        float4 a4 = *(const float4*)rp;
        rb[ky][0] = a4.x; rb[ky][1] = a4.y; rb[ky][2] = a4.z; rb[ky][3] = a4.w;
        rb[ky][4] = rp[4];
      }
#pragma unroll
      for (int j = 0; j < 2; j++) {
#pragma unroll
        for (int ky = 0; ky < 3; ky++) {
#pragma unroll
          for (int kx = 0; kx < 3; kx++) {
            float pv = rb[ky][2 * j + kx];
            float4 w = wr[3 * ky + kx];
            acc[j][0] += w.x * pv; acc[j][1] += w.y * pv;
            acc[j][2] += w.z * pv; acc[j][3] += w.w * pv;
          }
        }
      }
    }
    float bb0 = h3b[oc0], bb1 = h3b[oc0 + 1], bb2 = h3b[oc0 + 2], bb3 = h3b[oc0 + 3];
    float s0 = fmaxf(acc[0][0] + bb0, 0.f) + fmaxf(acc[1][0] + bb0, 0.f);
    float s1 = fmaxf(acc[0][1] + bb1, 0.f) + fmaxf(acc[1][1] + bb1, 0.f);
    float s2 = fmaxf(acc[0][2] + bb2, 0.f) + fmaxf(acc[1][2] + bb2, 0.f);
    float s3 = fmaxf(acc[0][3] + bb3, 0.f) + fmaxf(acc[1][3] + bb3, 0.f);
#pragma unroll
    for (int off = 8; off < 64; off <<= 1) {
      s0 += __shfl_xor(s0, off); s1 += __shfl_xor(s1, off);
      s2 += __shfl_xor(s2, off); s3 += __shfl_xor(s3, off);
    }
    if (lane < 8)
      *(float4*)&part3[wv][lane * 4] = make_float4(s0, s1, s2, s3);
  }

  // ---- P2: hid2 conv, wave = channel quarter, 4 px/lane ----
  {
    const int row = lane & 3;      // pmap local row (y = y0+row)
    const int x0 = (lane >> 2) * 4;
    float pm0 = 0.f, pm1 = 0.f, pm2 = 0.f, pm3 = 0.f;
#pragma unroll
    for (int cc = 0; cc < 4; cc++) {
      int ch = wv * 4 + cc;
#pragma unroll
      for (int ky = 0; ky < 3; ky++) {
        const float* bp = &occ[(ch * 6 + row + ky) * OPITCH + x0];
        float fl = bp[3];
        float4 fm = *(const float4*)(bp + 4);
        float fr = bp[8];
        float wa = h2w[ch * 9 + 3 * ky], wb = h2w[ch * 9 + 3 * ky + 1],
              wc = h2w[ch * 9 + 3 * ky + 2];
        pm0 += wa * fl   + wb * fm.x + wc * fm.y;
        pm1 += wa * fm.x + wb * fm.y + wc * fm.z;
        pm2 += wa * fm.y + wb * fm.z + wc * fm.w;
        pm3 += wa * fm.z + wb * fm.w + wc * fr;
      }
    }
    *(float4*)pm4[wv][lane] = make_float4(pm0, pm1, pm2, pm3);
  }
  __syncthreads();

  if (wv == 0) {
    // ---- softmax partials over the 4-row stripe ----
    const int row = lane & 3;
    const int x0 = (lane >> 2) * 4;
    float4 p0 = *(const float4*)pm4[0][lane];
    float4 p1 = *(const float4*)pm4[1][lane];
    float4 p2 = *(const float4*)pm4[2][lane];
    float4 p3 = *(const float4*)pm4[3][lane];
    float bb = h2b[0];
    float v0 = ((p0.x + p1.x + p2.x + p3.x) + bb) * TEMPF;
    float v1 = ((p0.y + p1.y + p2.y + p3.y) + bb) * TEMPF;
    float v2 = ((p0.z + p1.z + p2.z + p3.z) + bb) * TEMPF;
    float v3 = ((p0.w + p1.w + p2.w + p3.w) + bb) * TEMPF;
    float mg = fmaxf(fmaxf(v0, v1), fmaxf(v2, v3));
#pragma unroll
    for (int off = 4; off < 64; off <<= 1) mg = fmaxf(mg, __shfl_xor(mg, off));
    float e0 = __expf(v0 - mg), e1 = __expf(v1 - mg);
    float e2 = __expf(v2 - mg), e3 = __expf(v3 - mg);
    float s = e0 + e1 + e2 + e3;
    float sx = e0 * (float)x0 + e1 * (float)(x0 + 1) + e2 * (float)(x0 + 2) +
               e3 * (float)(x0 + 3);
#pragma unroll
    for (int off = 4; off < 64; off <<= 1) {
      s += __shfl_xor(s, off);
      sx += __shfl_xor(sx, off);
    }
    float M = mg, S = s, SX = sx, SY = s * (float)(y0 + row);
#pragma unroll
    for (int off = 1; off < 4; off <<= 1) {
      float Mo = __shfl_xor(M, off), So = __shfl_xor(S, off);
      float SXo = __shfl_xor(SX, off), SYo = __shfl_xor(SY, off);
      float Mn = fmaxf(M, Mo);
      float c1 = __expf(M - Mn), c2 = __expf(Mo - Mn);
      S = S * c1 + So * c2; SX = SX * c1 + SXo * c2; SY = SY * c1 + SYo * c2;
      M = Mn;
    }
    if (lane == 0)
      *(float4*)&ws[WS_PART + (q * 16 + st) * 4] = make_float4(M, S, SX, SY);
  } else if (wv == 1 && lane < 32) {
    float sm = part3[0][lane] + part3[1][lane] + part3[2][lane] + part3[3][lane];
    ws[WS_SUM3 + (q * 16 + st) * 32 + lane] = sm;
  }
}

// ---------------------------------------------------------------------------
// head merge: combine 16 stripe partials per query -> pos, occ, expd
// ---------------------------------------------------------------------------
__global__ __launch_bounds__(256) void k_head_merge(
    const float* __restrict__ w4, const float* __restrict__ b4,
    const float* __restrict__ w5, const float* __restrict__ b5,
    float* __restrict__ ws) {
  __shared__ float sums_s[4][32];
  __shared__ float o4s[4][16];
  int t = threadIdx.x, wv = t >> 6, lane = t & 63;
  int q = blockIdx.x * 4 + wv;

  float M = -1e30f, S = 0.f, SX = 0.f, SY = 0.f;
  if (lane < 16) {
    float4 pv = *(const float4*)&ws[WS_PART + (q * 16 + lane) * 4];
    M = pv.x; S = pv.y; SX = pv.z; SY = pv.w;
  }
#pragma unroll
  for (int off = 1; off < 16; off <<= 1) {
    float Mo = __shfl_xor(M, off), So = __shfl_xor(S, off);
    float SXo = __shfl_xor(SX, off), SYo = __shfl_xor(SY, off);
    float Mn = fmaxf(M, Mo);
    float c1 = __expf(M - Mn), c2 = __expf(Mo - Mn);
    S = S * c1 + So * c2; SX = SX * c1 + SXo * c2; SY = SY * c1 + SYo * c2;
    M = Mn;
  }
  if (lane == 0) {
    ws[WS_POS + q * 2 + 0] = (SX / S) * 8.0f;
    ws[WS_POS + q * 2 + 1] = (SY / S) * 8.0f;
  }

  int ch = lane & 31, half = lane >> 5;
  float sm = 0.f;
#pragma unroll
  for (int s8 = 0; s8 < 8; s8++)
    sm += ws[WS_SUM3 + (q * 16 + half * 8 + s8) * 32 + ch];
  sm += __shfl_xor(sm, 32);
  if (lane < 32) sums_s[wv][lane] = sm * (1.f / 1024.f);
  __syncthreads();
  if (lane < 16) {
    float a = b4[lane];
#pragma unroll
    for (int i = 0; i < 32; i++) a += sums_s[wv][i] * w4[i * 16 + lane];
    o4s[wv][lane] = fmaxf(a, 0.f);
  }
  __syncthreads();
  if (lane < 2) {
    float r = b5[lane];
#pragma unroll
    for (int j = 0; j < 16; j++) r += o4s[wv][j] * w5[j * 2 + lane];
    if (lane == 0) ws[WS_OCC + q] = r;
    else           ws[WS_EXPD + q] = r;
  }
}

// ---------------------------------------------------------------------------
// correlation + mlp_in assembly. 1 block = 1 query; 4 waves split channels.
// ---------------------------------------------------------------------------
__global__ __launch_bounds__(256) void k_corr(
    const float* __restrict__ fg, const float* __restrict__ hg,
    float* __restrict__ ws) {
  __shared__ float dbuf[3][64][4];
  int t = threadIdx.x;
  int wv = t >> 6, lane = t & 63;
  int n = blockIdx.x;
  const float* feats = ws + WS_FEATS + n * 384;
  float posx = ws[WS_POS + n * 2 + 0];
  float posy = ws[WS_POS + n * 2 + 1];
  float* mi = ws + WS_MLPIN + n * INPITCH;

  for (int col = t; col < 388; col += 256) {
    float v;
    if (col < 2) v = 0.f;
    else if (col == 2) v = ws[WS_OCC + n];
    else if (col == 3) v = ws[WS_EXPD + n];
    else v = feats[col - 4];
    mi[col] = v;
  }

  int a = lane >> 3, b = lane & 7;
#pragma unroll
  for (int L = 0; L < 3; L++) {
    const float* grid;
    int Hg, Wg, C, qoff;
    float scl;
    if (L == 0)      { grid = hg;             Hg = 128; Wg = 128; C = 128; qoff = 0;   scl = 0.25f; }
    else if (L == 1) { grid = fg;             Hg = 64;  Wg = 64;  C = 256; qoff = 128; scl = 0.125f; }
    else             { grid = ws + WS_FGAVG;  Hg = 32;  Wg = 32;  C = 256; qoff = 128; scl = 0.0625f; }
    float cy = posy * scl, cx = posx * scl;
    int iy = (int)floorf(cy), ix = (int)floorf(cx);
    int row = iy + a - 3; row = row < 0 ? 0 : (row > Hg - 1 ? Hg - 1 : row);
    int col = ix + b - 3; col = col < 0 ? 0 : (col > Wg - 1 ? Wg - 1 : col);
    int cq = C >> 2;
    const float* gp = grid + (row * Wg + col) * C + wv * cq;
    const float* qp = feats + qoff + wv * cq;
    float acc0 = 0.f, acc1 = 0.f;
    for (int c = 0; c < cq; c += 8) {
      float4 g0 = *(const float4*)(gp + c);
      float4 g1 = *(const float4*)(gp + c + 4);
      float4 q0 = *(const float4*)(qp + c);
      float4 q1 = *(const float4*)(qp + c + 4);
      acc0 += g0.x * q0.x + g0.y * q0.y + g0.z * q0.z + g0.w * q0.w;
      acc1 += g1.x * q1.x + g1.y * q1.y + g1.z * q1.z + g1.w * q1.w;
    }
    dbuf[L][lane][wv] = acc0 + acc1;
  }
  __syncthreads();
  if (t < 147) {
    int L = t / 49, s = t - L * 49;
    int sa = s / 7, sb = s - sa * 7;
    float scl = (L == 0) ? 0.25f : ((L == 1) ? 0.125f : 0.0625f);
    float cy = posy * scl, cx = posx * scl;
    float wy = cy - floorf(cy), wx = cx - floorf(cx);
    int i00 = sa * 8 + sb;
    float4 q00 = *(const float4*)dbuf[L][i00];
    float4 q01 = *(const float4*)dbuf[L][i00 + 1];
    float4 q10 = *(const float4*)dbuf[L][i00 + 8];
    float4 q11 = *(const float4*)dbuf[L][i00 + 9];
    float d00 = q00.x + q00.y + q00.z + q00.w;
    float d01 = q01.x + q01.y + q01.z + q01.w;
    float d10 = q10.x + q10.y + q10.z + q10.w;
    float d11 = q11.x + q11.y + q11.z + q11.w;
    float corr = (1.f - wy) * (1.f - wx) * d00 + (1.f - wy) * wx * d01 +
                 wy * (1.f - wx) * d10 + wy * wx * d11;
    mi[388 + t] = corr;
  }
}

// ---------------------------------------------------------------------------
__device__ __forceinline__ float gelu_tanh(float x) {
  float z = 0.7978845608028654f * (x + 0.044715f * x * x * x);
  z = fminf(fmaxf(z, -15.f), 15.f);
  float e = __expf(2.f * z);
  float th = (e - 1.f) / (e + 1.f);
  return 0.5f * x * (1.f + th);
}

// mixer GEMM 1: hidden = gelu(mlp_in @ mix_in_w + b). 32x32 tile, BK=32.
__global__ __launch_bounds__(256) void k_mix1(
    const float* __restrict__ w, const float* __restrict__ bias,
    float* __restrict__ ws) {
  __shared__ float As[32][33];
  __shared__ float Bs[32][33];
  int t = threadIdx.x;
  int tx = t & 15, ty = t >> 4;
  int n0 = blockIdx.x * 32, m0 = blockIdx.y * 32;
  const float* A = ws + WS_MLPIN;
  float acc[2][2] = {{0.f, 0.f}, {0.f, 0.f}};
  for (int k0 = 0; k0 < INDIM; k0 += 32) {
#pragma unroll
    for (int j = 0; j < 4; j++) {
      int idx = t + 256 * j;
      int m = idx >> 5, kk = idx & 31;
      int k = k0 + kk;
      As[kk][m] = (k < INDIM) ? A[(m0 + m) * INPITCH + k] : 0.f;
      Bs[kk][m] = (k < INDIM) ? w[k * HID + n0 + m] : 0.f;
    }
    __syncthreads();
#pragma unroll
    for (int qi = 0; qi < 32; qi++) {
      float a0 = As[qi][ty * 2], a1 = As[qi][ty * 2 + 1];
      float b0 = Bs[qi][tx * 2], b1 = Bs[qi][tx * 2 + 1];
      acc[0][0] += a0 * b0; acc[0][1] += a0 * b1;
      acc[1][0] += a1 * b0; acc[1][1] += a1 * b1;
    }
    __syncthreads();
  }
  float* Hd = ws + WS_HIDDEN;
#pragma unroll
  for (int i = 0; i < 2; i++) {
    int m = m0 + ty * 2 + i;
#pragma unroll
    for (int j = 0; j < 2; j++) {
      int nn = n0 + tx * 2 + j;
      Hd[m * HID + nn] = gelu_tanh(acc[i][j] + bias[nn]);
    }
  }
}

// mixer GEMM 2 + state update + out write. 32x32 tile, BK=32.
__global__ __launch_bounds__(256) void k_mix2(
    const float* __restrict__ w, const float* __restrict__ bias,
    float* __restrict__ ws, float* __restrict__ out) {
  __shared__ float As[32][33];
  __shared__ float Bs[32][33];
  int t = threadIdx.x;
  int tx = t & 15, ty = t >> 4;
  int n0 = blockIdx.x * 32, m0 = blockIdx.y * 32;
  const float* A = ws + WS_HIDDEN;
  float acc[2][2] = {{0.f, 0.f}, {0.f, 0.f}};
  for (int k0 = 0; k0 < HID; k0 += 32) {
#pragma unroll
    for (int j = 0; j < 4; j++) {
      int idx = t + 256 * j;
      int m = idx >> 5, kk = idx & 31;
      int col = n0 + m;
      As[kk][m] = A[(m0 + m) * HID + k0 + kk];
      Bs[kk][m] = (col < DIMV) ? w[(k0 + kk) * DIMV + col] : 0.f;
    }
    __syncthreads();
#pragma unroll
    for (int qi = 0; qi < 32; qi++) {
      float a0 = As[qi][ty * 2], a1 = As[qi][ty * 2 + 1];
      float b0 = Bs[qi][tx * 2], b1 = Bs[qi][tx * 2 + 1];
      acc[0][0] += a0 * b0; acc[0][1] += a0 * b1;
      acc[1][0] += a1 * b0; acc[1][1] += a1 * b1;
    }
    __syncthreads();
  }
#pragma unroll
  for (int i = 0; i < 2; i++) {
    int m = m0 + ty * 2 + i;
#pragma unroll
    for (int j = 0; j < 2; j++) {
      int col = n0 + tx * 2 + j;
      if (col >= DIMV) continue;
      float rr = acc[i][j] + bias[col];
      if (col < 2) {
        float v = ws[WS_POS + m * 2 + col] + rr;
        ws[WS_POS + m * 2 + col] = v;
        out[m * 4 + col] = v;
      } else if (col == 2) {
        float v = ws[WS_OCC + m] + rr;
        ws[WS_OCC + m] = v;
        out[m * 4 + 2] = v;
      } else if (col == 3) {
        float v = ws[WS_EXPD + m] + rr;
        ws[WS_EXPD + m] = v;
        out[m * 4 + 3] = v;
      } else {
        ws[WS_FEATS + m * 384 + (col - 4)] += rr;
      }
    }
  }
}

// ---------------------------------------------------------------------------
extern "C" void kernel_launch(void* const* d_in, const int* in_sizes, int n_in,
                              void* d_out, int out_size, void* d_ws, size_t ws_size,
                              hipStream_t stream) {
  const float* fg = (const float*)d_in[0];
  const float* hg = (const float*)d_in[1];
  const float* qf = (const float*)d_in[2];
  const float* hq = (const float*)d_in[3];
  const float* w1 = (const float*)d_in[4];
  const float* b1 = (const float*)d_in[5];
  const float* w2 = (const float*)d_in[6];
  const float* b2 = (const float*)d_in[7];
  const float* w3 = (const float*)d_in[8];
  const float* b3 = (const float*)d_in[9];
  const float* w4 = (const float*)d_in[10];
  const float* b4 = (const float*)d_in[11];
  const float* w5 = (const float*)d_in[12];
  const float* b5 = (const float*)d_in[13];
  const float* wi = (const float*)d_in[14];
  const float* bi = (const float*)d_in[15];
  const float* wo = (const float*)d_in[16];
  const float* bo = (const float*)d_in[17];
  float* ws = (float*)d_ws;
  float* out = (float*)d_out;

  k_prep<<<2578, 256, 0, stream>>>(fg, qf, hq, w3, ws);
  k_cv<<<dim3(64, 32), 256, 0, stream>>>(qf, fg, ws);
  k_head_stripe<<<16384, 256, 0, stream>>>(w1, b1, w2, b2, b3, ws);
  k_head_merge<<<256, 256, 0, stream>>>(w4, b4, w5, b5, ws);
  for (int it = 0; it < 4; it++) {
    k_corr<<<1024, 256, 0, stream>>>(fg, hg, ws);
    k_mix1<<<dim3(16, 32), 256, 0, stream>>>(wi, bi, ws);
    k_mix2<<<dim3(13, 32), 256, 0, stream>>>(wo, bo, ws, out);
  }
}

// Round 4
// 768.686 us; speedup vs baseline: 2.7662x; 1.2316x over previous
//
#include <hip/hip_runtime.h>
#include <math.h>

// ---------------------------------------------------------------------------
// TAPIR forward, all f32.
// fg[64,64,256] hg[128,128,128] qf[1024,256] hq[1024,128] -> out[1024,4]
// ---------------------------------------------------------------------------

#define NQ 1024
#define TEMPF 20.0f
#define DIMV 388
#define INDIM 535
#define INPITCH 544
#define HID 512

// workspace layout (float offsets)
#define WS_CV      0                          // 1024*4096
#define WS_FGAVG   (WS_CV + NQ*4096)          // 32*32*256
#define WS_POS     (WS_FGAVG + 262144)        // 1024*2
#define WS_OCC     (WS_POS + NQ*2)            // 1024
#define WS_EXPD    (WS_OCC + NQ)              // 1024
#define WS_FEATS   (WS_EXPD + NQ)             // 1024*384
#define WS_MLPIN   (WS_FEATS + NQ*384)        // 1024*544 (pitch-padded 535)
#define WS_HIDDEN  (WS_MLPIN + NQ*INPITCH)    // 1024*512
#define WS_W3T     (WS_HIDDEN + NQ*HID)       // 4608 transposed hid3_w [ic][tap][oc]
// overlays (dead regions at time of use):
#define WS_PART    WS_MLPIN                   // 1024*32*4 softmax partials (m,s,sx,sy)
#define WS_SUM3    WS_HIDDEN                  // 1024*16*32 hid3 relu-sums (atomicAdd)

#define OP 72                                 // occ LDS x-pitch

// ---------------------------------------------------------------------------
// prep: fg 2x2 avg pyramid, feats=concat(hq,qf), w3 transpose, zero SUM3
// ---------------------------------------------------------------------------
__global__ __launch_bounds__(256) void k_prep(
    const float* __restrict__ fg, const float* __restrict__ qf,
    const float* __restrict__ hq, const float* __restrict__ w3,
    float* __restrict__ ws) {
  int i = blockIdx.x * 256 + threadIdx.x;
  if (i < 262144) {
    int c = i & 255, ox = (i >> 8) & 31, oy = i >> 13;
    const float* b = fg + (((oy * 2) * 64 + ox * 2) << 8) + c;
    ws[WS_FGAVG + i] = 0.25f * (b[0] + b[256] + b[16384] + b[16384 + 256]);
  } else if (i < 262144 + 393216) {
    int j = i - 262144;
    int n = j / 384, c = j - n * 384;
    ws[WS_FEATS + j] = (c < 128) ? hq[n * 128 + c] : qf[n * 256 + c - 128];
  } else if (i < 262144 + 393216 + 4608) {
    int j = i - (262144 + 393216);
    int oc = j & 31, rest = j >> 5;
    int tap = rest % 9, ic = rest / 9;
    ws[WS_W3T + j] = w3[(oc * 16 + ic) * 9 + tap];
  } else if (i < 262144 + 393216 + 4608 + 524288) {
    int j = i - (262144 + 393216 + 4608);
    ws[WS_SUM3 + j] = 0.f;
  }
}

// ---------------------------------------------------------------------------
// cost volume: cv[n][p] = sum_c qf[n][c] * fg[p][c]. 64x64 tile, BK=32.
// ---------------------------------------------------------------------------
__global__ __launch_bounds__(256) void k_cv(
    const float* __restrict__ qf, const float* __restrict__ fg,
    float* __restrict__ ws) {
  __shared__ float As[32][68];
  __shared__ float Bs[32][68];
  int t = threadIdx.x;
  int tx = t & 15, ty = t >> 4;
  int p0 = blockIdx.x * 64, m0 = blockIdx.y * 64;
  float acc[4][4] = {{0.f,0.f,0.f,0.f},{0.f,0.f,0.f,0.f},
                     {0.f,0.f,0.f,0.f},{0.f,0.f,0.f,0.f}};
  for (int k0 = 0; k0 < 256; k0 += 32) {
#pragma unroll
    for (int j = 0; j < 8; j++) {
      int idx = t + 256 * j;
      int kk = idx & 31, mm = idx >> 5;
      As[kk][mm] = qf[(m0 + mm) * 256 + k0 + kk];
      Bs[kk][mm] = fg[(p0 + mm) * 256 + k0 + kk];
    }
    __syncthreads();
#pragma unroll
    for (int k = 0; k < 32; k++) {
      float4 a = *(const float4*)&As[k][ty * 4];
      float4 b = *(const float4*)&Bs[k][tx * 4];
      float av[4] = {a.x, a.y, a.z, a.w};
      float bv[4] = {b.x, b.y, b.z, b.w};
#pragma unroll
      for (int i = 0; i < 4; i++)
#pragma unroll
        for (int jj = 0; jj < 4; jj++) acc[i][jj] += av[i] * bv[jj];
    }
    __syncthreads();
  }
#pragma unroll
  for (int i = 0; i < 4; i++) {
    float4 v = make_float4(acc[i][0], acc[i][1], acc[i][2], acc[i][3]);
    *(float4*)&ws[WS_CV + (m0 + ty * 4 + i) * 4096 + p0 + tx * 4] = v;
  }
}

// ---------------------------------------------------------------------------
// head stripe kernel: 1 block = (query, 4-row stripe). 16384 blocks.
// P1 (all waves): hid1 -> occ stripe (6 rows x 16 ch) in LDS.
// Then 4 independent roles (rotated by blockIdx, no further barriers):
//  role 0: hid2+softmax rows y0+0..1   role 3: rows y0+2..3  -> WS_PART
//  role 1: hid3 s2-conv oy local 0     role 2: oy local 1    -> atomicAdd SUM3
// ---------------------------------------------------------------------------
__global__ __launch_bounds__(256, 4) void k_head_stripe(
    const float* __restrict__ h1w, const float* __restrict__ h1b,
    const float* __restrict__ h2w, const float* __restrict__ h2b,
    const float* __restrict__ h3b, float* __restrict__ ws) {
  __shared__ float cvs[8 * 66];          // cv rows y0-2..y0+5, x -1..64
  __shared__ float occ[6 * 16 * OP];     // [r][ch][x+4]

  const int bx = blockIdx.x;
  const int q = bx >> 4, st = bx & 15;
  const int y0 = st * 4;
  const int t = threadIdx.x;
  const int wv = t >> 6, lane = t & 63;
  const int role = (wv + bx) & 3;
  const float* cv = ws + WS_CV + q * 4096;

  // zero occ (covers halos + out-of-range rows), load cv stripe
  {
    float4 z = make_float4(0.f, 0.f, 0.f, 0.f);
    float4* o4 = (float4*)occ;
    for (int i = t; i < 6 * 16 * OP / 4; i += 256) o4[i] = z;
  }
#pragma unroll
  for (int j = 0; j < 2; j++) {
    int i = t + 256 * j;
    int lr = i >> 6, x = i & 63;
    int g = y0 - 2 + lr;
    cvs[lr * 66 + x + 1] = (g >= 0 && g < 64) ? cv[g * 64 + x] : 0.f;
  }
  if (t < 16) cvs[(t >> 1) * 66 + (t & 1) * 65] = 0.f;
  __syncthreads();

  // ---- P1: hid1 conv, occ rows r=0..5 (yo=y0-1+r), wave = 4 channels ----
  {
    const int x = lane;
    const int chg = wv * 4;
    float w1r[4][9], b1r[4];
#pragma unroll
    for (int k = 0; k < 4; k++) {
      b1r[k] = h1b[chg + k];
#pragma unroll
      for (int j = 0; j < 9; j++) w1r[k][j] = h1w[(chg + k) * 9 + j];
    }
    for (int r = 0; r < 6; r++) {
      int yo = y0 - 1 + r;
      if (yo >= 0 && yo <= 63) {
        float p[9];
#pragma unroll
        for (int ky = 0; ky < 3; ky++) {
          const float* cp = &cvs[(r + ky) * 66 + x];
          p[3 * ky] = cp[0]; p[3 * ky + 1] = cp[1]; p[3 * ky + 2] = cp[2];
        }
#pragma unroll
        for (int k = 0; k < 4; k++) {
          float a = b1r[k];
#pragma unroll
          for (int j = 0; j < 9; j++) a += w1r[k][j] * p[j];
          occ[(r * 16 + chg + k) * OP + x + 4] = fmaxf(a, 0.f);
        }
      }
    }
  }
  __syncthreads();

  if (role == 1 || role == 2) {
    // ---- hid3 stride-2 conv, one output row (oyl = role-1) ----
    const float* w3t = ws + WS_W3T;
    const int oyl = role - 1;
    const int oc0 = (lane & 7) * 4;
    const int oxq = lane >> 3;           // ox = 4*oxq + j
    float acc[4][4];
#pragma unroll
    for (int i = 0; i < 4; i++) {
      acc[i][0] = 0.f; acc[i][1] = 0.f; acc[i][2] = 0.f; acc[i][3] = 0.f;
    }
    for (int ic = 0; ic < 16; ic++) {
      float4 wr[9];
#pragma unroll
      for (int tap = 0; tap < 9; tap++)
        wr[tap] = *(const float4*)(w3t + (ic * 9 + tap) * 32 + oc0);
      float rb[3][9];
#pragma unroll
      for (int ky = 0; ky < 3; ky++) {
        const float* rp = &occ[((2 * oyl + ky + 1) * 16 + ic) * OP + 4 + 8 * oxq];
        float4 a4 = *(const float4*)rp;
        float4 c4 = *(const float4*)(rp + 4);
        rb[ky][0] = a4.x; rb[ky][1] = a4.y; rb[ky][2] = a4.z; rb[ky][3] = a4.w;
        rb[ky][4] = c4.x; rb[ky][5] = c4.y; rb[ky][6] = c4.z; rb[ky][7] = c4.w;
        rb[ky][8] = rp[8];
      }
#pragma unroll
      for (int j = 0; j < 4; j++) {
#pragma unroll
        for (int ky = 0; ky < 3; ky++) {
#pragma unroll
          for (int kx = 0; kx < 3; kx++) {
            float pv = rb[ky][2 * j + kx];
            float4 w = wr[3 * ky + kx];
            acc[j][0] += w.x * pv; acc[j][1] += w.y * pv;
            acc[j][2] += w.z * pv; acc[j][3] += w.w * pv;
          }
        }
      }
    }
    float bb0 = h3b[oc0], bb1 = h3b[oc0+1], bb2 = h3b[oc0+2], bb3 = h3b[oc0+3];
    float s0 = 0.f, s1 = 0.f, s2 = 0.f, s3 = 0.f;
#pragma unroll
    for (int j = 0; j < 4; j++) {
      s0 += fmaxf(acc[j][0] + bb0, 0.f);
      s1 += fmaxf(acc[j][1] + bb1, 0.f);
      s2 += fmaxf(acc[j][2] + bb2, 0.f);
      s3 += fmaxf(acc[j][3] + bb3, 0.f);
    }
#pragma unroll
    for (int off = 8; off < 64; off <<= 1) {
      s0 += __shfl_xor(s0, off); s1 += __shfl_xor(s1, off);
      s2 += __shfl_xor(s2, off); s3 += __shfl_xor(s3, off);
    }
    if (lane < 8) {
      float* dst = &ws[WS_SUM3 + (q * 16 + st) * 32 + lane * 4];
      atomicAdd(dst + 0, s0); atomicAdd(dst + 1, s1);
      atomicAdd(dst + 2, s2); atomicAdd(dst + 3, s3);
    }
  } else {
    // ---- hid2 + softmax partial on 2 rows (role 0: rows 0-1, role 3: 2-3) --
    const int rl = ((role == 3) ? 2 : 0) + (lane >> 5);  // local pmap row
    const int yg = y0 + rl;
    const int x0 = (lane & 31) * 2;
    float pa = 0.f, pb = 0.f;
    for (int ch = 0; ch < 16; ch++) {
#pragma unroll
      for (int ky = 0; ky < 3; ky++) {
        const float* bp = &occ[((rl + ky) * 16 + ch) * OP + x0 + 3];
        float f0 = bp[0], f1 = bp[1], f2 = bp[2], f3 = bp[3];
        float wa = h2w[ch * 9 + 3 * ky], wb = h2w[ch * 9 + 3 * ky + 1],
              wc = h2w[ch * 9 + 3 * ky + 2];
        pa += wa * f0 + wb * f1 + wc * f2;
        pb += wa * f1 + wb * f2 + wc * f3;
      }
    }
    float bb = h2b[0];
    float v0 = (pa + bb) * TEMPF, v1 = (pb + bb) * TEMPF;
    float mg = fmaxf(v0, v1);
#pragma unroll
    for (int off = 1; off < 64; off <<= 1) mg = fmaxf(mg, __shfl_xor(mg, off));
    float e0 = __expf(v0 - mg), e1 = __expf(v1 - mg);
    float s = e0 + e1;
    float sx = e0 * (float)x0 + e1 * (float)(x0 + 1);
    float sy = s * (float)yg;
#pragma unroll
    for (int off = 1; off < 64; off <<= 1) {
      s += __shfl_xor(s, off);
      sx += __shfl_xor(sx, off);
      sy += __shfl_xor(sy, off);
    }
    if (lane == 0) {
      int slot = q * 32 + st * 2 + ((role == 3) ? 1 : 0);
      *(float4*)&ws[WS_PART + slot * 4] = make_float4(mg, s, sx, sy);
    }
  }
}

// ---------------------------------------------------------------------------
// head merge: 32 softmax partials + 16 hid3 sum slots per query
// ---------------------------------------------------------------------------
__global__ __launch_bounds__(256) void k_head_merge(
    const float* __restrict__ w4, const float* __restrict__ b4,
    const float* __restrict__ w5, const float* __restrict__ b5,
    float* __restrict__ ws) {
  __shared__ float sums_s[4][32];
  __shared__ float o4s[4][16];
  int t = threadIdx.x, wv = t >> 6, lane = t & 63;
  int q = blockIdx.x * 4 + wv;

  float M = -1e30f, S = 0.f, SX = 0.f, SY = 0.f;
  if (lane < 32) {
    float4 pv = *(const float4*)&ws[WS_PART + (q * 32 + lane) * 4];
    M = pv.x; S = pv.y; SX = pv.z; SY = pv.w;
  }
#pragma unroll
  for (int off = 1; off < 64; off <<= 1) {
    float Mo = __shfl_xor(M, off), So = __shfl_xor(S, off);
    float SXo = __shfl_xor(SX, off), SYo = __shfl_xor(SY, off);
    float Mn = fmaxf(M, Mo);
    float c1 = __expf(M - Mn), c2 = __expf(Mo - Mn);
    S = S * c1 + So * c2; SX = SX * c1 + SXo * c2; SY = SY * c1 + SYo * c2;
    M = Mn;
  }
  if (lane == 0) {
    ws[WS_POS + q * 2 + 0] = (SX / S) * 8.0f;
    ws[WS_POS + q * 2 + 1] = (SY / S) * 8.0f;
  }

  int ch = lane & 31, half = lane >> 5;
  float sm = 0.f;
#pragma unroll
  for (int s8 = 0; s8 < 8; s8++)
    sm += ws[WS_SUM3 + (q * 16 + half * 8 + s8) * 32 + ch];
  sm += __shfl_xor(sm, 32);
  if (lane < 32) sums_s[wv][lane] = sm * (1.f / 1024.f);
  __syncthreads();
  if (lane < 16) {
    float a = b4[lane];
#pragma unroll
    for (int i = 0; i < 32; i++) a += sums_s[wv][i] * w4[i * 16 + lane];
    o4s[wv][lane] = fmaxf(a, 0.f);
  }
  __syncthreads();
  if (lane < 2) {
    float r = b5[lane];
#pragma unroll
    for (int j = 0; j < 16; j++) r += o4s[wv][j] * w5[j * 2 + lane];
    if (lane == 0) ws[WS_OCC + q] = r;
    else           ws[WS_EXPD + q] = r;
  }
}

// ---------------------------------------------------------------------------
// correlation + mlp_in assembly. 1 block = 1 query; 4 waves split channels.
// ---------------------------------------------------------------------------
__global__ __launch_bounds__(256) void k_corr(
    const float* __restrict__ fg, const float* __restrict__ hg,
    float* __restrict__ ws) {
  __shared__ float dbuf[3][64][4];
  int t = threadIdx.x;
  int wv = t >> 6, lane = t & 63;
  int n = blockIdx.x;
  const float* feats = ws + WS_FEATS + n * 384;
  float posx = ws[WS_POS + n * 2 + 0];
  float posy = ws[WS_POS + n * 2 + 1];
  float* mi = ws + WS_MLPIN + n * INPITCH;

  for (int col = t; col < 388; col += 256) {
    float v;
    if (col < 2) v = 0.f;
    else if (col == 2) v = ws[WS_OCC + n];
    else if (col == 3) v = ws[WS_EXPD + n];
    else v = feats[col - 4];
    mi[col] = v;
  }

  int a = lane >> 3, b = lane & 7;
#pragma unroll
  for (int L = 0; L < 3; L++) {
    const float* grid;
    int Hg, Wg, C, qoff;
    float scl;
    if (L == 0)      { grid = hg;             Hg = 128; Wg = 128; C = 128; qoff = 0;   scl = 0.25f; }
    else if (L == 1) { grid = fg;             Hg = 64;  Wg = 64;  C = 256; qoff = 128; scl = 0.125f; }
    else             { grid = ws + WS_FGAVG;  Hg = 32;  Wg = 32;  C = 256; qoff = 128; scl = 0.0625f; }
    float cy = posy * scl, cx = posx * scl;
    int iy = (int)floorf(cy), ix = (int)floorf(cx);
    int row = iy + a - 3; row = row < 0 ? 0 : (row > Hg - 1 ? Hg - 1 : row);
    int col = ix + b - 3; col = col < 0 ? 0 : (col > Wg - 1 ? Wg - 1 : col);
    int cq = C >> 2;
    const float* gp = grid + (row * Wg + col) * C + wv * cq;
    const float* qp = feats + qoff + wv * cq;
    float acc0 = 0.f, acc1 = 0.f;
    for (int c = 0; c < cq; c += 8) {
      float4 g0 = *(const float4*)(gp + c);
      float4 g1 = *(const float4*)(gp + c + 4);
      float4 q0 = *(const float4*)(qp + c);
      float4 q1 = *(const float4*)(qp + c + 4);
      acc0 += g0.x * q0.x + g0.y * q0.y + g0.z * q0.z + g0.w * q0.w;
      acc1 += g1.x * q1.x + g1.y * q1.y + g1.z * q1.z + g1.w * q1.w;
    }
    dbuf[L][lane][wv] = acc0 + acc1;
  }
  __syncthreads();
  if (t < 147) {
    int L = t / 49, s = t - L * 49;
    int sa = s / 7, sb = s - sa * 7;
    float scl = (L == 0) ? 0.25f : ((L == 1) ? 0.125f : 0.0625f);
    float cy = posy * scl, cx = posx * scl;
    float wy = cy - floorf(cy), wx = cx - floorf(cx);
    int i00 = sa * 8 + sb;
    float4 q00 = *(const float4*)dbuf[L][i00];
    float4 q01 = *(const float4*)dbuf[L][i00 + 1];
    float4 q10 = *(const float4*)dbuf[L][i00 + 8];
    float4 q11 = *(const float4*)dbuf[L][i00 + 9];
    float d00 = q00.x + q00.y + q00.z + q00.w;
    float d01 = q01.x + q01.y + q01.z + q01.w;
    float d10 = q10.x + q10.y + q10.z + q10.w;
    float d11 = q11.x + q11.y + q11.z + q11.w;
    float corr = (1.f - wy) * (1.f - wx) * d00 + (1.f - wy) * wx * d01 +
                 wy * (1.f - wx) * d10 + wy * wx * d11;
    mi[388 + t] = corr;
  }
}

// ---------------------------------------------------------------------------
__device__ __forceinline__ float gelu_tanh(float x) {
  float z = 0.7978845608028654f * (x + 0.044715f * x * x * x);
  z = fminf(fmaxf(z, -15.f), 15.f);
  float e = __expf(2.f * z);
  float th = (e - 1.f) / (e + 1.f);
  return 0.5f * x * (1.f + th);
}

// mixer GEMM 1: hidden = gelu(mlp_in @ mix_in_w + b). 32x32 tile, BK=32.
__global__ __launch_bounds__(256) void k_mix1(
    const float* __restrict__ w, const float* __restrict__ bias,
    float* __restrict__ ws) {
  __shared__ float As[32][33];
  __shared__ float Bs[32][33];
  int t = threadIdx.x;
  int tx = t & 15, ty = t >> 4;
  int n0 = blockIdx.x * 32, m0 = blockIdx.y * 32;
  const float* A = ws + WS_MLPIN;
  float acc[2][2] = {{0.f, 0.f}, {0.f, 0.f}};
  for (int k0 = 0; k0 < INDIM; k0 += 32) {
#pragma unroll
    for (int j = 0; j < 4; j++) {
      int idx = t + 256 * j;
      int m = idx >> 5, kk = idx & 31;
      int k = k0 + kk;
      As[kk][m] = (k < INDIM) ? A[(m0 + m) * INPITCH + k] : 0.f;
      Bs[kk][m] = (k < INDIM) ? w[k * HID + n0 + m] : 0.f;
    }
    __syncthreads();
#pragma unroll
    for (int qi = 0; qi < 32; qi++) {
      float a0 = As[qi][ty * 2], a1 = As[qi][ty * 2 + 1];
      float b0 = Bs[qi][tx * 2], b1 = Bs[qi][tx * 2 + 1];
      acc[0][0] += a0 * b0; acc[0][1] += a0 * b1;
      acc[1][0] += a1 * b0; acc[1][1] += a1 * b1;
    }
    __syncthreads();
  }
  float* Hd = ws + WS_HIDDEN;
#pragma unroll
  for (int i = 0; i < 2; i++) {
    int m = m0 + ty * 2 + i;
#pragma unroll
    for (int j = 0; j < 2; j++) {
      int nn = n0 + tx * 2 + j;
      Hd[m * HID + nn] = gelu_tanh(acc[i][j] + bias[nn]);
    }
  }
}

// mixer GEMM 2 + state update + out write. 32x32 tile, BK=32.
__global__ __launch_bounds__(256) void k_mix2(
    const float* __restrict__ w, const float* __restrict__ bias,
    float* __restrict__ ws, float* __restrict__ out) {
  __shared__ float As[32][33];
  __shared__ float Bs[32][33];
  int t = threadIdx.x;
  int tx = t & 15, ty = t >> 4;
  int n0 = blockIdx.x * 32, m0 = blockIdx.y * 32;
  const float* A = ws + WS_HIDDEN;
  float acc[2][2] = {{0.f, 0.f}, {0.f, 0.f}};
  for (int k0 = 0; k0 < HID; k0 += 32) {
#pragma unroll
    for (int j = 0; j < 4; j++) {
      int idx = t + 256 * j;
      int m = idx >> 5, kk = idx & 31;
      int col = n0 + m;
      As[kk][m] = A[(m0 + m) * HID + k0 + kk];
      Bs[kk][m] = (col < DIMV) ? w[(k0 + kk) * DIMV + col] : 0.f;
    }
    __syncthreads();
#pragma unroll
    for (int qi = 0; qi < 32; qi++) {
      float a0 = As[qi][ty * 2], a1 = As[qi][ty * 2 + 1];
      float b0 = Bs[qi][tx * 2], b1 = Bs[qi][tx * 2 + 1];
      acc[0][0] += a0 * b0; acc[0][1] += a0 * b1;
      acc[1][0] += a1 * b0; acc[1][1] += a1 * b1;
    }
    __syncthreads();
  }
#pragma unroll
  for (int i = 0; i < 2; i++) {
    int m = m0 + ty * 2 + i;
#pragma unroll
    for (int j = 0; j < 2; j++) {
      int col = n0 + tx * 2 + j;
      if (col >= DIMV) continue;
      float rr = acc[i][j] + bias[col];
      if (col < 2) {
        float v = ws[WS_POS + m * 2 + col] + rr;
        ws[WS_POS + m * 2 + col] = v;
        out[m * 4 + col] = v;
      } else if (col == 2) {
        float v = ws[WS_OCC + m] + rr;
        ws[WS_OCC + m] = v;
        out[m * 4 + 2] = v;
      } else if (col == 3) {
        float v = ws[WS_EXPD + m] + rr;
        ws[WS_EXPD + m] = v;
        out[m * 4 + 3] = v;
      } else {
        ws[WS_FEATS + m * 384 + (col - 4)] += rr;
      }
    }
  }
}

// ---------------------------------------------------------------------------
extern "C" void kernel_launch(void* const* d_in, const int* in_sizes, int n_in,
                              void* d_out, int out_size, void* d_ws, size_t ws_size,
                              hipStream_t stream) {
  const float* fg = (const float*)d_in[0];
  const float* hg = (const float*)d_in[1];
  const float* qf = (const float*)d_in[2];
  const float* hq = (const float*)d_in[3];
  const float* w1 = (const float*)d_in[4];
  const float* b1 = (const float*)d_in[5];
  const float* w2 = (const float*)d_in[6];
  const float* b2 = (const float*)d_in[7];
  const float* w3 = (const float*)d_in[8];
  const float* b3 = (const float*)d_in[9];
  const float* w4 = (const float*)d_in[10];
  const float* b4 = (const float*)d_in[11];
  const float* w5 = (const float*)d_in[12];
  const float* b5 = (const float*)d_in[13];
  const float* wi = (const float*)d_in[14];
  const float* bi = (const float*)d_in[15];
  const float* wo = (const float*)d_in[16];
  const float* bo = (const float*)d_in[17];
  float* ws = (float*)d_ws;
  float* out = (float*)d_out;

  k_prep<<<4626, 256, 0, stream>>>(fg, qf, hq, w3, ws);
  k_cv<<<dim3(64, 16), 256, 0, stream>>>(qf, fg, ws);
  k_head_stripe<<<16384, 256, 0, stream>>>(w1, b1, w2, b2, b3, ws);
  k_head_merge<<<256, 256, 0, stream>>>(w4, b4, w5, b5, ws);
  for (int it = 0; it < 4; it++) {
    k_corr<<<1024, 256, 0, stream>>>(fg, hg, ws);
    k_mix1<<<dim3(16, 32), 256, 0, stream>>>(wi, bi, ws);
    k_mix2<<<dim3(13, 32), 256, 0, stream>>>(wo, bo, ws, out);
  }
}

// Round 5
// 701.739 us; speedup vs baseline: 3.0301x; 1.0954x over previous
//
#include <hip/hip_runtime.h>
#include <math.h>

// ---------------------------------------------------------------------------
// TAPIR forward, all f32.
// fg[64,64,256] hg[128,128,128] qf[1024,256] hq[1024,128] -> out[1024,4]
// ---------------------------------------------------------------------------

#define NQ 1024
#define TEMPF 20.0f
#define DIMV 388
#define INDIM 535
#define INPITCH 544
#define HID 512

// workspace layout (float offsets)
#define WS_CV      0                          // 1024*4096
#define WS_FGAVG   (WS_CV + NQ*4096)          // 32*32*256
#define WS_POS     (WS_FGAVG + 262144)        // 1024*2
#define WS_OCC     (WS_POS + NQ*2)            // 1024
#define WS_EXPD    (WS_OCC + NQ)              // 1024
#define WS_FEATS   (WS_EXPD + NQ)             // 1024*384
#define WS_MLPIN   (WS_FEATS + NQ*384)        // 1024*544 (pitch-padded 535)
#define WS_HIDDEN  (WS_MLPIN + NQ*INPITCH)    // 1024*512
#define WS_W3T     (WS_HIDDEN + NQ*HID)       // 4608 transposed hid3_w [ic][tap][oc]
// overlays (dead regions at time of use):
#define WS_PART    WS_MLPIN                   // 1024*32*4 softmax partials (m,s,sx,sy)
#define WS_SUM3    WS_HIDDEN                  // 1024*16*32 hid3 relu-sums (atomicAdd)

#define OP 72                                 // occ LDS x-pitch

// ---------------------------------------------------------------------------
// prep: fg 2x2 avg pyramid, feats=concat(hq,qf), w3 transpose, zero SUM3
// ---------------------------------------------------------------------------
__global__ __launch_bounds__(256) void k_prep(
    const float* __restrict__ fg, const float* __restrict__ qf,
    const float* __restrict__ hq, const float* __restrict__ w3,
    float* __restrict__ ws) {
  int i = blockIdx.x * 256 + threadIdx.x;
  if (i < 262144) {
    int c = i & 255, ox = (i >> 8) & 31, oy = i >> 13;
    const float* b = fg + (((oy * 2) * 64 + ox * 2) << 8) + c;
    ws[WS_FGAVG + i] = 0.25f * (b[0] + b[256] + b[16384] + b[16384 + 256]);
  } else if (i < 262144 + 393216) {
    int j = i - 262144;
    int n = j / 384, c = j - n * 384;
    ws[WS_FEATS + j] = (c < 128) ? hq[n * 128 + c] : qf[n * 256 + c - 128];
  } else if (i < 262144 + 393216 + 4608) {
    int j = i - (262144 + 393216);
    int oc = j & 31, rest = j >> 5;
    int tap = rest % 9, ic = rest / 9;
    ws[WS_W3T + j] = w3[(oc * 16 + ic) * 9 + tap];
  } else if (i < 262144 + 393216 + 4608 + 524288) {
    int j = i - (262144 + 393216 + 4608);
    ws[WS_SUM3 + j] = 0.f;
  }
}

// ---------------------------------------------------------------------------
// cost volume: cv[n][p] = sum_c qf[n][c] * fg[p][c]. 64x64 tile, BK=32.
// ---------------------------------------------------------------------------
__global__ __launch_bounds__(256) void k_cv(
    const float* __restrict__ qf, const float* __restrict__ fg,
    float* __restrict__ ws) {
  __shared__ float As[32][68];
  __shared__ float Bs[32][68];
  int t = threadIdx.x;
  int tx = t & 15, ty = t >> 4;
  int p0 = blockIdx.x * 64, m0 = blockIdx.y * 64;
  float acc[4][4] = {{0.f,0.f,0.f,0.f},{0.f,0.f,0.f,0.f},
                     {0.f,0.f,0.f,0.f},{0.f,0.f,0.f,0.f}};
  for (int k0 = 0; k0 < 256; k0 += 32) {
#pragma unroll
    for (int j = 0; j < 8; j++) {
      int idx = t + 256 * j;
      int kk = idx & 31, mm = idx >> 5;
      As[kk][mm] = qf[(m0 + mm) * 256 + k0 + kk];
      Bs[kk][mm] = fg[(p0 + mm) * 256 + k0 + kk];
    }
    __syncthreads();
#pragma unroll
    for (int k = 0; k < 32; k++) {
      float4 a = *(const float4*)&As[k][ty * 4];
      float4 b = *(const float4*)&Bs[k][tx * 4];
      float av[4] = {a.x, a.y, a.z, a.w};
      float bv[4] = {b.x, b.y, b.z, b.w};
#pragma unroll
      for (int i = 0; i < 4; i++)
#pragma unroll
        for (int jj = 0; jj < 4; jj++) acc[i][jj] += av[i] * bv[jj];
    }
    __syncthreads();
  }
#pragma unroll
  for (int i = 0; i < 4; i++) {
    float4 v = make_float4(acc[i][0], acc[i][1], acc[i][2], acc[i][3]);
    *(float4*)&ws[WS_CV + (m0 + ty * 4 + i) * 4096 + p0 + tx * 4] = v;
  }
}

// ---------------------------------------------------------------------------
// head stripe kernel: 1 block = (query, 4-row stripe). 16384 blocks.
// P1 (all waves): hid1 -> occ stripe (6 rows x 16 ch) in LDS.
// Then 4 independent roles (rotated by blockIdx, no further barriers):
//  role 0: hid2+softmax rows y0+0..1   role 3: rows y0+2..3  -> WS_PART
//  role 1: hid3 s2-conv oy local 0     role 2: oy local 1    -> atomicAdd SUM3
// ---------------------------------------------------------------------------
__global__ __launch_bounds__(256, 4) void k_head_stripe(
    const float* __restrict__ h1w, const float* __restrict__ h1b,
    const float* __restrict__ h2w, const float* __restrict__ h2b,
    const float* __restrict__ h3b, float* __restrict__ ws) {
  __shared__ float cvs[8 * 66];          // cv rows y0-2..y0+5, x -1..64
  __shared__ float occ[6 * 16 * OP];     // [r][ch][x+4]

  const int bx = blockIdx.x;
  const int q = bx >> 4, st = bx & 15;
  const int y0 = st * 4;
  const int t = threadIdx.x;
  const int wv = t >> 6, lane = t & 63;
  const int role = (wv + bx) & 3;
  const float* cv = ws + WS_CV + q * 4096;

  // zero occ (covers halos + out-of-range rows), load cv stripe
  {
    float4 z = make_float4(0.f, 0.f, 0.f, 0.f);
    float4* o4 = (float4*)occ;
    for (int i = t; i < 6 * 16 * OP / 4; i += 256) o4[i] = z;
  }
#pragma unroll
  for (int j = 0; j < 2; j++) {
    int i = t + 256 * j;
    int lr = i >> 6, x = i & 63;
    int g = y0 - 2 + lr;
    cvs[lr * 66 + x + 1] = (g >= 0 && g < 64) ? cv[g * 64 + x] : 0.f;
  }
  if (t < 16) cvs[(t >> 1) * 66 + (t & 1) * 65] = 0.f;
  __syncthreads();

  // ---- P1: hid1 conv, occ rows r=0..5 (yo=y0-1+r), wave = 4 channels ----
  {
    const int x = lane;
    const int chg = wv * 4;
    float w1r[4][9], b1r[4];
#pragma unroll
    for (int k = 0; k < 4; k++) {
      b1r[k] = h1b[chg + k];
#pragma unroll
      for (int j = 0; j < 9; j++) w1r[k][j] = h1w[(chg + k) * 9 + j];
    }
    for (int r = 0; r < 6; r++) {
      int yo = y0 - 1 + r;
      if (yo >= 0 && yo <= 63) {
        float p[9];
#pragma unroll
        for (int ky = 0; ky < 3; ky++) {
          const float* cp = &cvs[(r + ky) * 66 + x];
          p[3 * ky] = cp[0]; p[3 * ky + 1] = cp[1]; p[3 * ky + 2] = cp[2];
        }
#pragma unroll
        for (int k = 0; k < 4; k++) {
          float a = b1r[k];
#pragma unroll
          for (int j = 0; j < 9; j++) a += w1r[k][j] * p[j];
          occ[(r * 16 + chg + k) * OP + x + 4] = fmaxf(a, 0.f);
        }
      }
    }
  }
  __syncthreads();

  if (role == 1 || role == 2) {
    // ---- hid3 stride-2 conv, one output row (oyl = role-1) ----
    const float* w3t = ws + WS_W3T;
    const int oyl = role - 1;
    const int oc0 = (lane & 7) * 4;
    const int oxq = lane >> 3;           // ox = 4*oxq + j
    float acc[4][4];
#pragma unroll
    for (int i = 0; i < 4; i++) {
      acc[i][0] = 0.f; acc[i][1] = 0.f; acc[i][2] = 0.f; acc[i][3] = 0.f;
    }
    for (int ic = 0; ic < 16; ic++) {
      float4 wr[9];
#pragma unroll
      for (int tap = 0; tap < 9; tap++)
        wr[tap] = *(const float4*)(w3t + (ic * 9 + tap) * 32 + oc0);
      float rb[3][9];
#pragma unroll
      for (int ky = 0; ky < 3; ky++) {
        const float* rp = &occ[((2 * oyl + ky + 1) * 16 + ic) * OP + 4 + 8 * oxq];
        float4 a4 = *(const float4*)rp;
        float4 c4 = *(const float4*)(rp + 4);
        rb[ky][0] = a4.x; rb[ky][1] = a4.y; rb[ky][2] = a4.z; rb[ky][3] = a4.w;
        rb[ky][4] = c4.x; rb[ky][5] = c4.y; rb[ky][6] = c4.z; rb[ky][7] = c4.w;
        rb[ky][8] = rp[8];
      }
#pragma unroll
      for (int j = 0; j < 4; j++) {
#pragma unroll
        for (int ky = 0; ky < 3; ky++) {
#pragma unroll
          for (int kx = 0; kx < 3; kx++) {
            float pv = rb[ky][2 * j + kx];
            float4 w = wr[3 * ky + kx];
            acc[j][0] += w.x * pv; acc[j][1] += w.y * pv;
            acc[j][2] += w.z * pv; acc[j][3] += w.w * pv;
          }
        }
      }
    }
    float bb0 = h3b[oc0], bb1 = h3b[oc0+1], bb2 = h3b[oc0+2], bb3 = h3b[oc0+3];
    float s0 = 0.f, s1 = 0.f, s2 = 0.f, s3 = 0.f;
#pragma unroll
    for (int j = 0; j < 4; j++) {
      s0 += fmaxf(acc[j][0] + bb0, 0.f);
      s1 += fmaxf(acc[j][1] + bb1, 0.f);
      s2 += fmaxf(acc[j][2] + bb2, 0.f);
      s3 += fmaxf(acc[j][3] + bb3, 0.f);
    }
#pragma unroll
    for (int off = 8; off < 64; off <<= 1) {
      s0 += __shfl_xor(s0, off); s1 += __shfl_xor(s1, off);
      s2 += __shfl_xor(s2, off); s3 += __shfl_xor(s3, off);
    }
    if (lane < 8) {
      float* dst = &ws[WS_SUM3 + (q * 16 + st) * 32 + lane * 4];
      atomicAdd(dst + 0, s0); atomicAdd(dst + 1, s1);
      atomicAdd(dst + 2, s2); atomicAdd(dst + 3, s3);
    }
  } else {
    // ---- hid2 + softmax partial on 2 rows (role 0: rows 0-1, role 3: 2-3) --
    const int rl = ((role == 3) ? 2 : 0) + (lane >> 5);  // local pmap row
    const int yg = y0 + rl;
    const int x0 = (lane & 31) * 2;
    float pa = 0.f, pb = 0.f;
    for (int ch = 0; ch < 16; ch++) {
#pragma unroll
      for (int ky = 0; ky < 3; ky++) {
        const float* bp = &occ[((rl + ky) * 16 + ch) * OP + x0 + 3];
        float f0 = bp[0], f1 = bp[1], f2 = bp[2], f3 = bp[3];
        float wa = h2w[ch * 9 + 3 * ky], wb = h2w[ch * 9 + 3 * ky + 1],
              wc = h2w[ch * 9 + 3 * ky + 2];
        pa += wa * f0 + wb * f1 + wc * f2;
        pb += wa * f1 + wb * f2 + wc * f3;
      }
    }
    float bb = h2b[0];
    float v0 = (pa + bb) * TEMPF, v1 = (pb + bb) * TEMPF;
    float mg = fmaxf(v0, v1);
#pragma unroll
    for (int off = 1; off < 64; off <<= 1) mg = fmaxf(mg, __shfl_xor(mg, off));
    float e0 = __expf(v0 - mg), e1 = __expf(v1 - mg);
    float s = e0 + e1;
    float sx = e0 * (float)x0 + e1 * (float)(x0 + 1);
    float sy = s * (float)yg;
#pragma unroll
    for (int off = 1; off < 64; off <<= 1) {
      s += __shfl_xor(s, off);
      sx += __shfl_xor(sx, off);
      sy += __shfl_xor(sy, off);
    }
    if (lane == 0) {
      int slot = q * 32 + st * 2 + ((role == 3) ? 1 : 0);
      *(float4*)&ws[WS_PART + slot * 4] = make_float4(mg, s, sx, sy);
    }
  }
}

// ---------------------------------------------------------------------------
// head merge: 32 softmax partials + 16 hid3 sum slots per query
// ---------------------------------------------------------------------------
__global__ __launch_bounds__(256) void k_head_merge(
    const float* __restrict__ w4, const float* __restrict__ b4,
    const float* __restrict__ w5, const float* __restrict__ b5,
    float* __restrict__ ws) {
  __shared__ float sums_s[4][32];
  __shared__ float o4s[4][16];
  int t = threadIdx.x, wv = t >> 6, lane = t & 63;
  int q = blockIdx.x * 4 + wv;

  float M = -1e30f, S = 0.f, SX = 0.f, SY = 0.f;
  if (lane < 32) {
    float4 pv = *(const float4*)&ws[WS_PART + (q * 32 + lane) * 4];
    M = pv.x; S = pv.y; SX = pv.z; SY = pv.w;
  }
#pragma unroll
  for (int off = 1; off < 64; off <<= 1) {
    float Mo = __shfl_xor(M, off), So = __shfl_xor(S, off);
    float SXo = __shfl_xor(SX, off), SYo = __shfl_xor(SY, off);
    float Mn = fmaxf(M, Mo);
    float c1 = __expf(M - Mn), c2 = __expf(Mo - Mn);
    S = S * c1 + So * c2; SX = SX * c1 + SXo * c2; SY = SY * c1 + SYo * c2;
    M = Mn;
  }
  if (lane == 0) {
    ws[WS_POS + q * 2 + 0] = (SX / S) * 8.0f;
    ws[WS_POS + q * 2 + 1] = (SY / S) * 8.0f;
  }

  int ch = lane & 31, half = lane >> 5;
  float sm = 0.f;
#pragma unroll
  for (int s8 = 0; s8 < 8; s8++)
    sm += ws[WS_SUM3 + (q * 16 + half * 8 + s8) * 32 + ch];
  sm += __shfl_xor(sm, 32);
  if (lane < 32) sums_s[wv][lane] = sm * (1.f / 1024.f);
  __syncthreads();
  if (lane < 16) {
    float a = b4[lane];
#pragma unroll
    for (int i = 0; i < 32; i++) a += sums_s[wv][i] * w4[i * 16 + lane];
    o4s[wv][lane] = fmaxf(a, 0.f);
  }
  __syncthreads();
  if (lane < 2) {
    float r = b5[lane];
#pragma unroll
    for (int j = 0; j < 16; j++) r += o4s[wv][j] * w5[j * 2 + lane];
    if (lane == 0) ws[WS_OCC + q] = r;
    else           ws[WS_EXPD + q] = r;
  }
}

// ---------------------------------------------------------------------------
// correlation + mlp_in assembly. 1 block = 1 query.
// Coalesced: 16-lane groups share a window position; lane cl loads channels
// cl*4 + 64k as float4 (16B/lane), dot vs q-register fragments, 4-step
// shfl_xor reduce inside the group.
// ---------------------------------------------------------------------------
__global__ __launch_bounds__(256) void k_corr(
    const float* __restrict__ fg, const float* __restrict__ hg,
    float* __restrict__ ws) {
  __shared__ float qs[384];
  __shared__ float dbuf[3][64];
  int t = threadIdx.x;
  int wv = t >> 6, lane = t & 63;
  int cl = lane & 15, sub = lane >> 4;
  int n = blockIdx.x;
  const float* feats = ws + WS_FEATS + n * 384;
  float posx = ws[WS_POS + n * 2 + 0];
  float posy = ws[WS_POS + n * 2 + 1];
  float* mi = ws + WS_MLPIN + n * INPITCH;

  // stage feats to LDS + write mlp_in[0:388]
  for (int col = t; col < 384; col += 256) {
    float v = feats[col];
    qs[col] = v;
    mi[4 + col] = v;
  }
  if (t < 4) {
    float v = (t == 2) ? ws[WS_OCC + n] : ((t == 3) ? ws[WS_EXPD + n] : 0.f);
    mi[t] = v;
  }
  __syncthreads();

  // q fragments in registers
  float4 qh0 = *(const float4*)&qs[cl * 4];
  float4 qh1 = *(const float4*)&qs[64 + cl * 4];
  float4 qq0 = *(const float4*)&qs[128 + cl * 4];
  float4 qq1 = *(const float4*)&qs[192 + cl * 4];
  float4 qq2 = *(const float4*)&qs[256 + cl * 4];
  float4 qq3 = *(const float4*)&qs[320 + cl * 4];

#pragma unroll
  for (int L = 0; L < 3; L++) {
    const float* grid;
    int Hg, Wg;
    float scl;
    if (L == 0)      { grid = hg;             Hg = 128; Wg = 128; scl = 0.25f; }
    else if (L == 1) { grid = fg;             Hg = 64;  Wg = 64;  scl = 0.125f; }
    else             { grid = ws + WS_FGAVG;  Hg = 32;  Wg = 32;  scl = 0.0625f; }
    float cy = posy * scl, cx = posx * scl;
    int iy = (int)floorf(cy), ix = (int)floorf(cx);
#pragma unroll
    for (int g = 0; g < 4; g++) {
      int p = wv * 16 + g * 4 + sub;
      int a = p >> 3, b = p & 7;
      int row = iy + a - 3; row = row < 0 ? 0 : (row > Hg - 1 ? Hg - 1 : row);
      int col = ix + b - 3; col = col < 0 ? 0 : (col > Wg - 1 ? Wg - 1 : col);
      float acc;
      if (L == 0) {
        const float* gp = grid + (row * Wg + col) * 128 + cl * 4;
        float4 g0 = *(const float4*)gp;
        float4 g1 = *(const float4*)(gp + 64);
        acc = g0.x * qh0.x + g0.y * qh0.y + g0.z * qh0.z + g0.w * qh0.w +
              g1.x * qh1.x + g1.y * qh1.y + g1.z * qh1.z + g1.w * qh1.w;
      } else {
        const float* gp = grid + (row * Wg + col) * 256 + cl * 4;
        float4 g0 = *(const float4*)gp;
        float4 g1 = *(const float4*)(gp + 64);
        float4 g2 = *(const float4*)(gp + 128);
        float4 g3 = *(const float4*)(gp + 192);
        acc = g0.x * qq0.x + g0.y * qq0.y + g0.z * qq0.z + g0.w * qq0.w +
              g1.x * qq1.x + g1.y * qq1.y + g1.z * qq1.z + g1.w * qq1.w +
              g2.x * qq2.x + g2.y * qq2.y + g2.z * qq2.z + g2.w * qq2.w +
              g3.x * qq3.x + g3.y * qq3.y + g3.z * qq3.z + g3.w * qq3.w;
      }
      acc += __shfl_xor(acc, 1);
      acc += __shfl_xor(acc, 2);
      acc += __shfl_xor(acc, 4);
      acc += __shfl_xor(acc, 8);
      if (cl == 0) dbuf[L][p] = acc;
    }
  }
  __syncthreads();

  if (t < 147) {
    int L = t / 49, s = t - L * 49;
    int sa = s / 7, sb = s - sa * 7;
    float scl = (L == 0) ? 0.25f : ((L == 1) ? 0.125f : 0.0625f);
    float cy = posy * scl, cx = posx * scl;
    float wy = cy - floorf(cy), wx = cx - floorf(cx);
    int i00 = sa * 8 + sb;
    float d00 = dbuf[L][i00], d01 = dbuf[L][i00 + 1];
    float d10 = dbuf[L][i00 + 8], d11 = dbuf[L][i00 + 9];
    float corr = (1.f - wy) * (1.f - wx) * d00 + (1.f - wy) * wx * d01 +
                 wy * (1.f - wx) * d10 + wy * wx * d11;
    mi[388 + t] = corr;
  }
}

// ---------------------------------------------------------------------------
__device__ __forceinline__ float gelu_tanh(float x) {
  float z = 0.7978845608028654f * (x + 0.044715f * x * x * x);
  z = fminf(fmaxf(z, -15.f), 15.f);
  float e = __expf(2.f * z);
  float th = (e - 1.f) / (e + 1.f);
  return 0.5f * x * (1.f + th);
}

// mixer GEMM 1: hidden = gelu(mlp_in @ mix_in_w + b). 32x32 tile, BK=32.
__global__ __launch_bounds__(256) void k_mix1(
    const float* __restrict__ w, const float* __restrict__ bias,
    float* __restrict__ ws) {
  __shared__ float As[32][33];
  __shared__ float Bs[32][33];
  int t = threadIdx.x;
  int tx = t & 15, ty = t >> 4;
  int n0 = blockIdx.x * 32, m0 = blockIdx.y * 32;
  const float* A = ws + WS_MLPIN;
  float acc[2][2] = {{0.f, 0.f}, {0.f, 0.f}};
  for (int k0 = 0; k0 < INDIM; k0 += 32) {
#pragma unroll
    for (int j = 0; j < 4; j++) {
      int idx = t + 256 * j;
      int m = idx >> 5, kk = idx & 31;
      int k = k0 + kk;
      As[kk][m] = (k < INDIM) ? A[(m0 + m) * INPITCH + k] : 0.f;
      Bs[kk][m] = (k < INDIM) ? w[k * HID + n0 + m] : 0.f;
    }
    __syncthreads();
#pragma unroll
    for (int qi = 0; qi < 32; qi++) {
      float a0 = As[qi][ty * 2], a1 = As[qi][ty * 2 + 1];
      float b0 = Bs[qi][tx * 2], b1 = Bs[qi][tx * 2 + 1];
      acc[0][0] += a0 * b0; acc[0][1] += a0 * b1;
      acc[1][0] += a1 * b0; acc[1][1] += a1 * b1;
    }
    __syncthreads();
  }
  float* Hd = ws + WS_HIDDEN;
#pragma unroll
  for (int i = 0; i < 2; i++) {
    int m = m0 + ty * 2 + i;
#pragma unroll
    for (int j = 0; j < 2; j++) {
      int nn = n0 + tx * 2 + j;
      Hd[m * HID + nn] = gelu_tanh(acc[i][j] + bias[nn]);
    }
  }
}

// mixer GEMM 2 + state update + out write. 32x32 tile, BK=32.
__global__ __launch_bounds__(256) void k_mix2(
    const float* __restrict__ w, const float* __restrict__ bias,
    float* __restrict__ ws, float* __restrict__ out) {
  __shared__ float As[32][33];
  __shared__ float Bs[32][33];
  int t = threadIdx.x;
  int tx = t & 15, ty = t >> 4;
  int n0 = blockIdx.x * 32, m0 = blockIdx.y * 32;
  const float* A = ws + WS_HIDDEN;
  float acc[2][2] = {{0.f, 0.f}, {0.f, 0.f}};
  for (int k0 = 0; k0 < HID; k0 += 32) {
#pragma unroll
    for (int j = 0; j < 4; j++) {
      int idx = t + 256 * j;
      int m = idx >> 5, kk = idx & 31;
      int col = n0 + m;
      As[kk][m] = A[(m0 + m) * HID + k0 + kk];
      Bs[kk][m] = (col < DIMV) ? w[(k0 + kk) * DIMV + col] : 0.f;
    }
    __syncthreads();
#pragma unroll
    for (int qi = 0; qi < 32; qi++) {
      float a0 = As[qi][ty * 2], a1 = As[qi][ty * 2 + 1];
      float b0 = Bs[qi][tx * 2], b1 = Bs[qi][tx * 2 + 1];
      acc[0][0] += a0 * b0; acc[0][1] += a0 * b1;
      acc[1][0] += a1 * b0; acc[1][1] += a1 * b1;
    }
    __syncthreads();
  }
#pragma unroll
  for (int i = 0; i < 2; i++) {
    int m = m0 + ty * 2 + i;
#pragma unroll
    for (int j = 0; j < 2; j++) {
      int col = n0 + tx * 2 + j;
      if (col >= DIMV) continue;
      float rr = acc[i][j] + bias[col];
      if (col < 2) {
        float v = ws[WS_POS + m * 2 + col] + rr;
        ws[WS_POS + m * 2 + col] = v;
        out[m * 4 + col] = v;
      } else if (col == 2) {
        float v = ws[WS_OCC + m] + rr;
        ws[WS_OCC + m] = v;
        out[m * 4 + 2] = v;
      } else if (col == 3) {
        float v = ws[WS_EXPD + m] + rr;
        ws[WS_EXPD + m] = v;
        out[m * 4 + 3] = v;
      } else {
        ws[WS_FEATS + m * 384 + (col - 4)] += rr;
      }
    }
  }
}

// ---------------------------------------------------------------------------
extern "C" void kernel_launch(void* const* d_in, const int* in_sizes, int n_in,
                              void* d_out, int out_size, void* d_ws, size_t ws_size,
                              hipStream_t stream) {
  const float* fg = (const float*)d_in[0];
  const float* hg = (const float*)d_in[1];
  const float* qf = (const float*)d_in[2];
  const float* hq = (const float*)d_in[3];
  const float* w1 = (const float*)d_in[4];
  const float* b1 = (const float*)d_in[5];
  const float* w2 = (const float*)d_in[6];
  const float* b2 = (const float*)d_in[7];
  const float* w3 = (const float*)d_in[8];
  const float* b3 = (const float*)d_in[9];
  const float* w4 = (const float*)d_in[10];
  const float* b4 = (const float*)d_in[11];
  const float* w5 = (const float*)d_in[12];
  const float* b5 = (const float*)d_in[13];
  const float* wi = (const float*)d_in[14];
  const float* bi = (const float*)d_in[15];
  const float* wo = (const float*)d_in[16];
  const float* bo = (const float*)d_in[17];
  float* ws = (float*)d_ws;
  float* out = (float*)d_out;

  k_prep<<<4626, 256, 0, stream>>>(fg, qf, hq, w3, ws);
  k_cv<<<dim3(64, 16), 256, 0, stream>>>(qf, fg, ws);
  k_head_stripe<<<16384, 256, 0, stream>>>(w1, b1, w2, b2, b3, ws);
  k_head_merge<<<256, 256, 0, stream>>>(w4, b4, w5, b5, ws);
  for (int it = 0; it < 4; it++) {
    k_corr<<<1024, 256, 0, stream>>>(fg, hg, ws);
    k_mix1<<<dim3(16, 32), 256, 0, stream>>>(wi, bi, ws);
    k_mix2<<<dim3(13, 32), 256, 0, stream>>>(wo, bo, ws, out);
  }
}

// Round 6
// 465.761 us; speedup vs baseline: 4.5652x; 1.5066x over previous
//
#include <hip/hip_runtime.h>
#include <hip/hip_bf16.h>
#include <math.h>

// ---------------------------------------------------------------------------
// TAPIR forward. State f32; mixer GEMMs via bf16 MFMA (f32 accumulate).
// fg[64,64,256] hg[128,128,128] qf[1024,256] hq[1024,128] -> out[1024,4]
// ---------------------------------------------------------------------------

#define NQ 1024
#define TEMPF 20.0f
#define DIMV 388
#define INDIM 535
#define KPAD 544
#define HID 512

// workspace layout (float offsets)
#define WS_CV      0                          // 1024*4096 (dead after stripe)
#define WS_FGAVG   (WS_CV + NQ*4096)          // 32*32*256
#define WS_POS     (WS_FGAVG + 262144)        // 1024*2
#define WS_OCC     (WS_POS + NQ*2)            // 1024
#define WS_EXPD    (WS_OCC + NQ)              // 1024
#define WS_FEATS   (WS_EXPD + NQ)             // 1024*384
#define WS_MLPIN   (WS_FEATS + NQ*384)        // bf16 mlp_in [1024][544] (278528 fl)
#define WS_HIDDEN  (WS_MLPIN + NQ*KPAD)       // bf16 hidden [1024][512] / SUM3 f32
#define WS_W3T     (WS_HIDDEN + NQ*HID)       // 4608 transposed hid3_w [ic][tap][oc]
// overlays:
#define WS_PART    (WS_MLPIN + 278528)        // 1024*32*4 softmax partials
#define WS_SUM3    WS_HIDDEN                  // 1024*16*32 hid3 relu-sums (dead after merge)
#define WS_WIT     WS_CV                      // bf16 [512][544] mix_in_w^T (139264 fl)
#define WS_WOT     (WS_CV + 139264)           // bf16 [448][512] mix_out_w^T (114688 fl)

#define OP 72                                 // occ LDS x-pitch

typedef __attribute__((ext_vector_type(8))) short bf16x8;
typedef __attribute__((ext_vector_type(4))) float f32x4;

// ---------------------------------------------------------------------------
// prep: fg 2x2 avg pyramid, feats=concat(hq,qf), w3 transpose, zero SUM3
// ---------------------------------------------------------------------------
__global__ __launch_bounds__(256) void k_prep(
    const float* __restrict__ fg, const float* __restrict__ qf,
    const float* __restrict__ hq, const float* __restrict__ w3,
    float* __restrict__ ws) {
  int i = blockIdx.x * 256 + threadIdx.x;
  if (i < 262144) {
    int c = i & 255, ox = (i >> 8) & 31, oy = i >> 13;
    const float* b = fg + (((oy * 2) * 64 + ox * 2) << 8) + c;
    ws[WS_FGAVG + i] = 0.25f * (b[0] + b[256] + b[16384] + b[16384 + 256]);
  } else if (i < 262144 + 393216) {
    int j = i - 262144;
    int n = j / 384, c = j - n * 384;
    ws[WS_FEATS + j] = (c < 128) ? hq[n * 128 + c] : qf[n * 256 + c - 128];
  } else if (i < 262144 + 393216 + 4608) {
    int j = i - (262144 + 393216);
    int oc = j & 31, rest = j >> 5;
    int tap = rest % 9, ic = rest / 9;
    ws[WS_W3T + j] = w3[(oc * 16 + ic) * 9 + tap];
  } else if (i < 262144 + 393216 + 4608 + 524288) {
    int j = i - (262144 + 393216 + 4608);
    ws[WS_SUM3 + j] = 0.f;
  }
}

// ---------------------------------------------------------------------------
// weight convert (runs AFTER stripe; overlays dead WS_CV):
// WIT[n][k] = bf16(mix_in_w[k][n]), k<535 else 0   (512 x 544)
// WOT[n][k] = bf16(mix_out_w[k][n]), n<388 else 0  (448 x 512)
// ---------------------------------------------------------------------------
__global__ __launch_bounds__(256) void k_cvt(
    const float* __restrict__ wi, const float* __restrict__ wo,
    float* __restrict__ ws) {
  int i = blockIdx.x * 256 + threadIdx.x;
  __hip_bfloat16* WIT = (__hip_bfloat16*)(ws + WS_WIT);
  __hip_bfloat16* WOT = (__hip_bfloat16*)(ws + WS_WOT);
  if (i < 278528) {
    int n = i / KPAD, k = i - n * KPAD;
    float v = (k < INDIM) ? wi[k * HID + n] : 0.f;
    WIT[i] = __float2bfloat16(v);
  } else if (i < 278528 + 229376) {
    int j = i - 278528;
    int n = j >> 9, k = j & 511;
    float v = (n < DIMV) ? wo[k * DIMV + n] : 0.f;
    WOT[j] = __float2bfloat16(v);
  }
}

// ---------------------------------------------------------------------------
// cost volume: cv[n][p] = sum_c qf[n][c] * fg[p][c]. 64x64 tile, BK=32.
// ---------------------------------------------------------------------------
__global__ __launch_bounds__(256) void k_cv(
    const float* __restrict__ qf, const float* __restrict__ fg,
    float* __restrict__ ws) {
  __shared__ float As[32][68];
  __shared__ float Bs[32][68];
  int t = threadIdx.x;
  int tx = t & 15, ty = t >> 4;
  int p0 = blockIdx.x * 64, m0 = blockIdx.y * 64;
  float acc[4][4] = {{0.f,0.f,0.f,0.f},{0.f,0.f,0.f,0.f},
                     {0.f,0.f,0.f,0.f},{0.f,0.f,0.f,0.f}};
  for (int k0 = 0; k0 < 256; k0 += 32) {
#pragma unroll
    for (int j = 0; j < 8; j++) {
      int idx = t + 256 * j;
      int kk = idx & 31, mm = idx >> 5;
      As[kk][mm] = qf[(m0 + mm) * 256 + k0 + kk];
      Bs[kk][mm] = fg[(p0 + mm) * 256 + k0 + kk];
    }
    __syncthreads();
#pragma unroll
    for (int k = 0; k < 32; k++) {
      float4 a = *(const float4*)&As[k][ty * 4];
      float4 b = *(const float4*)&Bs[k][tx * 4];
      float av[4] = {a.x, a.y, a.z, a.w};
      float bv[4] = {b.x, b.y, b.z, b.w};
#pragma unroll
      for (int i = 0; i < 4; i++)
#pragma unroll
        for (int jj = 0; jj < 4; jj++) acc[i][jj] += av[i] * bv[jj];
    }
    __syncthreads();
  }
#pragma unroll
  for (int i = 0; i < 4; i++) {
    float4 v = make_float4(acc[i][0], acc[i][1], acc[i][2], acc[i][3]);
    *(float4*)&ws[WS_CV + (m0 + ty * 4 + i) * 4096 + p0 + tx * 4] = v;
  }
}

// ---------------------------------------------------------------------------
// head stripe kernel: 1 block = (query, 4-row stripe). 16384 blocks.
// ---------------------------------------------------------------------------
__global__ __launch_bounds__(256, 4) void k_head_stripe(
    const float* __restrict__ h1w, const float* __restrict__ h1b,
    const float* __restrict__ h2w, const float* __restrict__ h2b,
    const float* __restrict__ h3b, float* __restrict__ ws) {
  __shared__ float cvs[8 * 66];          // cv rows y0-2..y0+5, x -1..64
  __shared__ float occ[6 * 16 * OP];     // [r][ch][x+4]

  const int bx = blockIdx.x;
  const int q = bx >> 4, st = bx & 15;
  const int y0 = st * 4;
  const int t = threadIdx.x;
  const int wv = t >> 6, lane = t & 63;
  const int role = (wv + bx) & 3;
  const float* cv = ws + WS_CV + q * 4096;

  {
    float4 z = make_float4(0.f, 0.f, 0.f, 0.f);
    float4* o4 = (float4*)occ;
    for (int i = t; i < 6 * 16 * OP / 4; i += 256) o4[i] = z;
  }
#pragma unroll
  for (int j = 0; j < 2; j++) {
    int i = t + 256 * j;
    int lr = i >> 6, x = i & 63;
    int g = y0 - 2 + lr;
    cvs[lr * 66 + x + 1] = (g >= 0 && g < 64) ? cv[g * 64 + x] : 0.f;
  }
  if (t < 16) cvs[(t >> 1) * 66 + (t & 1) * 65] = 0.f;
  __syncthreads();

  // ---- P1: hid1 conv, occ rows r=0..5 (yo=y0-1+r), wave = 4 channels ----
  {
    const int x = lane;
    const int chg = wv * 4;
    float w1r[4][9], b1r[4];
#pragma unroll
    for (int k = 0; k < 4; k++) {
      b1r[k] = h1b[chg + k];
#pragma unroll
      for (int j = 0; j < 9; j++) w1r[k][j] = h1w[(chg + k) * 9 + j];
    }
    for (int r = 0; r < 6; r++) {
      int yo = y0 - 1 + r;
      if (yo >= 0 && yo <= 63) {
        float p[9];
#pragma unroll
        for (int ky = 0; ky < 3; ky++) {
          const float* cp = &cvs[(r + ky) * 66 + x];
          p[3 * ky] = cp[0]; p[3 * ky + 1] = cp[1]; p[3 * ky + 2] = cp[2];
        }
#pragma unroll
        for (int k = 0; k < 4; k++) {
          float a = b1r[k];
#pragma unroll
          for (int j = 0; j < 9; j++) a += w1r[k][j] * p[j];
          occ[(r * 16 + chg + k) * OP + x + 4] = fmaxf(a, 0.f);
        }
      }
    }
  }
  __syncthreads();

  if (role == 1 || role == 2) {
    // ---- hid3 stride-2 conv, one output row (oyl = role-1) ----
    const float* w3t = ws + WS_W3T;
    const int oyl = role - 1;
    const int oc0 = (lane & 7) * 4;
    const int oxq = lane >> 3;
    float acc[4][4];
#pragma unroll
    for (int i = 0; i < 4; i++) {
      acc[i][0] = 0.f; acc[i][1] = 0.f; acc[i][2] = 0.f; acc[i][3] = 0.f;
    }
    for (int ic = 0; ic < 16; ic++) {
      float4 wr[9];
#pragma unroll
      for (int tap = 0; tap < 9; tap++)
        wr[tap] = *(const float4*)(w3t + (ic * 9 + tap) * 32 + oc0);
      float rb[3][9];
#pragma unroll
      for (int ky = 0; ky < 3; ky++) {
        const float* rp = &occ[((2 * oyl + ky + 1) * 16 + ic) * OP + 4 + 8 * oxq];
        float4 a4 = *(const float4*)rp;
        float4 c4 = *(const float4*)(rp + 4);
        rb[ky][0] = a4.x; rb[ky][1] = a4.y; rb[ky][2] = a4.z; rb[ky][3] = a4.w;
        rb[ky][4] = c4.x; rb[ky][5] = c4.y; rb[ky][6] = c4.z; rb[ky][7] = c4.w;
        rb[ky][8] = rp[8];
      }
#pragma unroll
      for (int j = 0; j < 4; j++) {
#pragma unroll
        for (int ky = 0; ky < 3; ky++) {
#pragma unroll
          for (int kx = 0; kx < 3; kx++) {
            float pv = rb[ky][2 * j + kx];
            float4 w = wr[3 * ky + kx];
            acc[j][0] += w.x * pv; acc[j][1] += w.y * pv;
            acc[j][2] += w.z * pv; acc[j][3] += w.w * pv;
          }
        }
      }
    }
    float bb0 = h3b[oc0], bb1 = h3b[oc0+1], bb2 = h3b[oc0+2], bb3 = h3b[oc0+3];
    float s0 = 0.f, s1 = 0.f, s2 = 0.f, s3 = 0.f;
#pragma unroll
    for (int j = 0; j < 4; j++) {
      s0 += fmaxf(acc[j][0] + bb0, 0.f);
      s1 += fmaxf(acc[j][1] + bb1, 0.f);
      s2 += fmaxf(acc[j][2] + bb2, 0.f);
      s3 += fmaxf(acc[j][3] + bb3, 0.f);
    }
#pragma unroll
    for (int off = 8; off < 64; off <<= 1) {
      s0 += __shfl_xor(s0, off); s1 += __shfl_xor(s1, off);
      s2 += __shfl_xor(s2, off); s3 += __shfl_xor(s3, off);
    }
    if (lane < 8) {
      float* dst = &ws[WS_SUM3 + (q * 16 + st) * 32 + lane * 4];
      atomicAdd(dst + 0, s0); atomicAdd(dst + 1, s1);
      atomicAdd(dst + 2, s2); atomicAdd(dst + 3, s3);
    }
  } else {
    // ---- hid2 + softmax partial on 2 rows ----
    const int rl = ((role == 3) ? 2 : 0) + (lane >> 5);
    const int yg = y0 + rl;
    const int x0 = (lane & 31) * 2;
    float pa = 0.f, pb = 0.f;
    for (int ch = 0; ch < 16; ch++) {
#pragma unroll
      for (int ky = 0; ky < 3; ky++) {
        const float* bp = &occ[((rl + ky) * 16 + ch) * OP + x0 + 3];
        float f0 = bp[0], f1 = bp[1], f2 = bp[2], f3 = bp[3];
        float wa = h2w[ch * 9 + 3 * ky], wb = h2w[ch * 9 + 3 * ky + 1],
              wc = h2w[ch * 9 + 3 * ky + 2];
        pa += wa * f0 + wb * f1 + wc * f2;
        pb += wa * f1 + wb * f2 + wc * f3;
      }
    }
    float bb = h2b[0];
    float v0 = (pa + bb) * TEMPF, v1 = (pb + bb) * TEMPF;
    float mg = fmaxf(v0, v1);
#pragma unroll
    for (int off = 1; off < 64; off <<= 1) mg = fmaxf(mg, __shfl_xor(mg, off));
    float e0 = __expf(v0 - mg), e1 = __expf(v1 - mg);
    float s = e0 + e1;
    float sx = e0 * (float)x0 + e1 * (float)(x0 + 1);
    float sy = s * (float)yg;
#pragma unroll
    for (int off = 1; off < 64; off <<= 1) {
      s += __shfl_xor(s, off);
      sx += __shfl_xor(sx, off);
      sy += __shfl_xor(sy, off);
    }
    if (lane == 0) {
      int slot = q * 32 + st * 2 + ((role == 3) ? 1 : 0);
      *(float4*)&ws[WS_PART + slot * 4] = make_float4(mg, s, sx, sy);
    }
  }
}

// ---------------------------------------------------------------------------
// head merge: 32 softmax partials + 16 hid3 sum slots per query
// ---------------------------------------------------------------------------
__global__ __launch_bounds__(256) void k_head_merge(
    const float* __restrict__ w4, const float* __restrict__ b4,
    const float* __restrict__ w5, const float* __restrict__ b5,
    float* __restrict__ ws) {
  __shared__ float sums_s[4][32];
  __shared__ float o4s[4][16];
  int t = threadIdx.x, wv = t >> 6, lane = t & 63;
  int q = blockIdx.x * 4 + wv;

  float M = -1e30f, S = 0.f, SX = 0.f, SY = 0.f;
  if (lane < 32) {
    float4 pv = *(const float4*)&ws[WS_PART + (q * 32 + lane) * 4];
    M = pv.x; S = pv.y; SX = pv.z; SY = pv.w;
  }
#pragma unroll
  for (int off = 1; off < 64; off <<= 1) {
    float Mo = __shfl_xor(M, off), So = __shfl_xor(S, off);
    float SXo = __shfl_xor(SX, off), SYo = __shfl_xor(SY, off);
    float Mn = fmaxf(M, Mo);
    float c1 = __expf(M - Mn), c2 = __expf(Mo - Mn);
    S = S * c1 + So * c2; SX = SX * c1 + SXo * c2; SY = SY * c1 + SYo * c2;
    M = Mn;
  }
  if (lane == 0) {
    ws[WS_POS + q * 2 + 0] = (SX / S) * 8.0f;
    ws[WS_POS + q * 2 + 1] = (SY / S) * 8.0f;
  }

  int ch = lane & 31, half = lane >> 5;
  float sm = 0.f;
#pragma unroll
  for (int s8 = 0; s8 < 8; s8++)
    sm += ws[WS_SUM3 + (q * 16 + half * 8 + s8) * 32 + ch];
  sm += __shfl_xor(sm, 32);
  if (lane < 32) sums_s[wv][lane] = sm * (1.f / 1024.f);
  __syncthreads();
  if (lane < 16) {
    float a = b4[lane];
#pragma unroll
    for (int i = 0; i < 32; i++) a += sums_s[wv][i] * w4[i * 16 + lane];
    o4s[wv][lane] = fmaxf(a, 0.f);
  }
  __syncthreads();
  if (lane < 2) {
    float r = b5[lane];
#pragma unroll
    for (int j = 0; j < 16; j++) r += o4s[wv][j] * w5[j * 2 + lane];
    if (lane == 0) ws[WS_OCC + q] = r;
    else           ws[WS_EXPD + q] = r;
  }
}

// ---------------------------------------------------------------------------
// correlation + bf16 mlp_in assembly. 1 block = 1 query.
// ---------------------------------------------------------------------------
__global__ __launch_bounds__(256) void k_corr(
    const float* __restrict__ fg, const float* __restrict__ hg,
    float* __restrict__ ws) {
  __shared__ float qs[384];
  __shared__ float dbuf[3][64];
  int t = threadIdx.x;
  int wv = t >> 6, lane = t & 63;
  int cl = lane & 15, sub = lane >> 4;
  int n = blockIdx.x;
  const float* feats = ws + WS_FEATS + n * 384;
  float posx = ws[WS_POS + n * 2 + 0];
  float posy = ws[WS_POS + n * 2 + 1];
  __hip_bfloat16* mi = (__hip_bfloat16*)(ws + WS_MLPIN) + n * KPAD;

  for (int col = t; col < 384; col += 256) {
    float v = feats[col];
    qs[col] = v;
    mi[4 + col] = __float2bfloat16(v);
  }
  if (t < 4) {
    float v = (t == 2) ? ws[WS_OCC + n] : ((t == 3) ? ws[WS_EXPD + n] : 0.f);
    mi[t] = __float2bfloat16(v);
  }
  __syncthreads();

  float4 qh0 = *(const float4*)&qs[cl * 4];
  float4 qh1 = *(const float4*)&qs[64 + cl * 4];
  float4 qq0 = *(const float4*)&qs[128 + cl * 4];
  float4 qq1 = *(const float4*)&qs[192 + cl * 4];
  float4 qq2 = *(const float4*)&qs[256 + cl * 4];
  float4 qq3 = *(const float4*)&qs[320 + cl * 4];

#pragma unroll
  for (int L = 0; L < 3; L++) {
    const float* grid;
    int Hg, Wg;
    float scl;
    if (L == 0)      { grid = hg;             Hg = 128; Wg = 128; scl = 0.25f; }
    else if (L == 1) { grid = fg;             Hg = 64;  Wg = 64;  scl = 0.125f; }
    else             { grid = ws + WS_FGAVG;  Hg = 32;  Wg = 32;  scl = 0.0625f; }
    float cy = posy * scl, cx = posx * scl;
    int iy = (int)floorf(cy), ix = (int)floorf(cx);
#pragma unroll
    for (int g = 0; g < 4; g++) {
      int p = wv * 16 + g * 4 + sub;
      int a = p >> 3, b = p & 7;
      int row = iy + a - 3; row = row < 0 ? 0 : (row > Hg - 1 ? Hg - 1 : row);
      int col = ix + b - 3; col = col < 0 ? 0 : (col > Wg - 1 ? Wg - 1 : col);
      float acc;
      if (L == 0) {
        const float* gp = grid + (row * Wg + col) * 128 + cl * 4;
        float4 g0 = *(const float4*)gp;
        float4 g1 = *(const float4*)(gp + 64);
        acc = g0.x * qh0.x + g0.y * qh0.y + g0.z * qh0.z + g0.w * qh0.w +
              g1.x * qh1.x + g1.y * qh1.y + g1.z * qh1.z + g1.w * qh1.w;
      } else {
        const float* gp = grid + (row * Wg + col) * 256 + cl * 4;
        float4 g0 = *(const float4*)gp;
        float4 g1 = *(const float4*)(gp + 64);
        float4 g2 = *(const float4*)(gp + 128);
        float4 g3 = *(const float4*)(gp + 192);
        acc = g0.x * qq0.x + g0.y * qq0.y + g0.z * qq0.z + g0.w * qq0.w +
              g1.x * qq1.x + g1.y * qq1.y + g1.z * qq1.z + g1.w * qq1.w +
              g2.x * qq2.x + g2.y * qq2.y + g2.z * qq2.z + g2.w * qq2.w +
              g3.x * qq3.x + g3.y * qq3.y + g3.z * qq3.z + g3.w * qq3.w;
      }
      acc += __shfl_xor(acc, 1);
      acc += __shfl_xor(acc, 2);
      acc += __shfl_xor(acc, 4);
      acc += __shfl_xor(acc, 8);
      if (cl == 0) dbuf[L][p] = acc;
    }
  }
  __syncthreads();

  if (t < 147) {
    int L = t / 49, s = t - L * 49;
    int sa = s / 7, sb = s - sa * 7;
    float scl = (L == 0) ? 0.25f : ((L == 1) ? 0.125f : 0.0625f);
    float cy = posy * scl, cx = posx * scl;
    float wy = cy - floorf(cy), wx = cx - floorf(cx);
    int i00 = sa * 8 + sb;
    float d00 = dbuf[L][i00], d01 = dbuf[L][i00 + 1];
    float d10 = dbuf[L][i00 + 8], d11 = dbuf[L][i00 + 9];
    float corr = (1.f - wy) * (1.f - wx) * d00 + (1.f - wy) * wx * d01 +
                 wy * (1.f - wx) * d10 + wy * wx * d11;
    mi[388 + t] = __float2bfloat16(corr);
  }
}

// ---------------------------------------------------------------------------
__device__ __forceinline__ float gelu_tanh(float x) {
  float z = 0.7978845608028654f * (x + 0.044715f * x * x * x);
  z = fminf(fmaxf(z, -15.f), 15.f);
  float e = __expf(2.f * z);
  float th = (e - 1.f) / (e + 1.f);
  return 0.5f * x * (1.f + th);
}

// ---------------------------------------------------------------------------
// mixer GEMM 1 (MFMA bf16): hidden = gelu(mlp_in @ mix_in_w + b)
// block tile 32m x 64n, wave = (m-half, n-half). K = 544.
// ---------------------------------------------------------------------------
__global__ __launch_bounds__(256) void k_mix1(
    const float* __restrict__ bias, float* __restrict__ ws) {
  __shared__ __hip_bfloat16 A_s[32 * 32];
  __shared__ __hip_bfloat16 B_s[64 * 32];
  const int t = threadIdx.x;
  const int wv = t >> 6, lane = t & 63;
  const int wm = wv & 1, wn = wv >> 1;
  const int quad = lane >> 4, nl = lane & 15;
  const int n0 = blockIdx.x * 64, m0 = blockIdx.y * 32;
  const unsigned short* Abf = (const unsigned short*)(ws + WS_MLPIN);
  const unsigned short* WIT = (const unsigned short*)(ws + WS_WIT);
  f32x4 acc0 = {0.f, 0.f, 0.f, 0.f};
  f32x4 acc1 = {0.f, 0.f, 0.f, 0.f};

  for (int k0 = 0; k0 < KPAD; k0 += 32) {
    if (t < 128) {
      int r = t >> 2, c = t & 3;
      *(uint4*)&A_s[r * 32 + c * 8] =
          *(const uint4*)&Abf[(m0 + r) * KPAD + k0 + c * 8];
    }
    {
      int r = t >> 2, c = t & 3;
      *(uint4*)&B_s[r * 32 + c * 8] =
          *(const uint4*)&WIT[(n0 + r) * KPAD + k0 + c * 8];
    }
    __syncthreads();
    bf16x8 a = *(const bf16x8*)&A_s[(16 * wm + nl) * 32 + quad * 8];
    bf16x8 b0 = *(const bf16x8*)&B_s[(32 * wn + nl) * 32 + quad * 8];
    bf16x8 b1 = *(const bf16x8*)&B_s[(32 * wn + 16 + nl) * 32 + quad * 8];
    acc0 = __builtin_amdgcn_mfma_f32_16x16x32_bf16(a, b0, acc0, 0, 0, 0);
    acc1 = __builtin_amdgcn_mfma_f32_16x16x32_bf16(a, b1, acc1, 0, 0, 0);
    __syncthreads();
  }

  __hip_bfloat16* Hd = (__hip_bfloat16*)(ws + WS_HIDDEN);
#pragma unroll
  for (int nt = 0; nt < 2; nt++) {
    int nn = n0 + 32 * wn + nt * 16 + nl;
    float bv = bias[nn];
#pragma unroll
    for (int r = 0; r < 4; r++) {
      int m = m0 + 16 * wm + quad * 4 + r;
      float v = gelu_tanh((nt ? acc1[r] : acc0[r]) + bv);
      Hd[m * HID + nn] = __float2bfloat16(v);
    }
  }
}

// ---------------------------------------------------------------------------
// mixer GEMM 2 (MFMA bf16) + state update + out write. K = 512, N tiles 448.
// ---------------------------------------------------------------------------
__global__ __launch_bounds__(256) void k_mix2(
    const float* __restrict__ bias, float* __restrict__ ws,
    float* __restrict__ out) {
  __shared__ __hip_bfloat16 A_s[32 * 32];
  __shared__ __hip_bfloat16 B_s[64 * 32];
  const int t = threadIdx.x;
  const int wv = t >> 6, lane = t & 63;
  const int wm = wv & 1, wn = wv >> 1;
  const int quad = lane >> 4, nl = lane & 15;
  const int n0 = blockIdx.x * 64, m0 = blockIdx.y * 32;
  const unsigned short* Abf = (const unsigned short*)(ws + WS_HIDDEN);
  const unsigned short* WOT = (const unsigned short*)(ws + WS_WOT);
  f32x4 acc0 = {0.f, 0.f, 0.f, 0.f};
  f32x4 acc1 = {0.f, 0.f, 0.f, 0.f};

  for (int k0 = 0; k0 < HID; k0 += 32) {
    if (t < 128) {
      int r = t >> 2, c = t & 3;
      *(uint4*)&A_s[r * 32 + c * 8] =
          *(const uint4*)&Abf[(m0 + r) * HID + k0 + c * 8];
    }
    {
      int r = t >> 2, c = t & 3;
      *(uint4*)&B_s[r * 32 + c * 8] =
          *(const uint4*)&WOT[(n0 + r) * HID + k0 + c * 8];
    }
    __syncthreads();
    bf16x8 a = *(const bf16x8*)&A_s[(16 * wm + nl) * 32 + quad * 8];
    bf16x8 b0 = *(const bf16x8*)&B_s[(32 * wn + nl) * 32 + quad * 8];
    bf16x8 b1 = *(const bf16x8*)&B_s[(32 * wn + 16 + nl) * 32 + quad * 8];
    acc0 = __builtin_amdgcn_mfma_f32_16x16x32_bf16(a, b0, acc0, 0, 0, 0);
    acc1 = __builtin_amdgcn_mfma_f32_16x16x32_bf16(a, b1, acc1, 0, 0, 0);
    __syncthreads();
  }

#pragma unroll
  for (int nt = 0; nt < 2; nt++) {
    int col = n0 + 32 * wn + nt * 16 + nl;
    if (col >= DIMV) continue;
    float bv = bias[col];
#pragma unroll
    for (int r = 0; r < 4; r++) {
      int m = m0 + 16 * wm + quad * 4 + r;
      float rr = (nt ? acc1[r] : acc0[r]) + bv;
      if (col < 2) {
        float v = ws[WS_POS + m * 2 + col] + rr;
        ws[WS_POS + m * 2 + col] = v;
        out[m * 4 + col] = v;
      } else if (col == 2) {
        float v = ws[WS_OCC + m] + rr;
        ws[WS_OCC + m] = v;
        out[m * 4 + 2] = v;
      } else if (col == 3) {
        float v = ws[WS_EXPD + m] + rr;
        ws[WS_EXPD + m] = v;
        out[m * 4 + 3] = v;
      } else {
        ws[WS_FEATS + m * 384 + (col - 4)] += rr;
      }
    }
  }
}

// ---------------------------------------------------------------------------
extern "C" void kernel_launch(void* const* d_in, const int* in_sizes, int n_in,
                              void* d_out, int out_size, void* d_ws, size_t ws_size,
                              hipStream_t stream) {
  const float* fg = (const float*)d_in[0];
  const float* hg = (const float*)d_in[1];
  const float* qf = (const float*)d_in[2];
  const float* hq = (const float*)d_in[3];
  const float* w1 = (const float*)d_in[4];
  const float* b1 = (const float*)d_in[5];
  const float* w2 = (const float*)d_in[6];
  const float* b2 = (const float*)d_in[7];
  const float* w3 = (const float*)d_in[8];
  const float* b3 = (const float*)d_in[9];
  const float* w4 = (const float*)d_in[10];
  const float* b4 = (const float*)d_in[11];
  const float* w5 = (const float*)d_in[12];
  const float* b5 = (const float*)d_in[13];
  const float* wi = (const float*)d_in[14];
  const float* bi = (const float*)d_in[15];
  const float* wo = (const float*)d_in[16];
  const float* bo = (const float*)d_in[17];
  float* ws = (float*)d_ws;
  float* out = (float*)d_out;

  k_prep<<<4626, 256, 0, stream>>>(fg, qf, hq, w3, ws);
  k_cv<<<dim3(64, 16), 256, 0, stream>>>(qf, fg, ws);
  k_head_stripe<<<16384, 256, 0, stream>>>(w1, b1, w2, b2, b3, ws);
  k_head_merge<<<256, 256, 0, stream>>>(w4, b4, w5, b5, ws);
  k_cvt<<<1984, 256, 0, stream>>>(wi, wo, ws);
  for (int it = 0; it < 4; it++) {
    k_corr<<<1024, 256, 0, stream>>>(fg, hg, ws);
    k_mix1<<<dim3(8, 32), 256, 0, stream>>>(bi, ws);
    k_mix2<<<dim3(7, 32), 256, 0, stream>>>(bo, ws, out);
  }
}

// Round 7
// 361.215 us; speedup vs baseline: 5.8866x; 1.2894x over previous
//
#include <hip/hip_runtime.h>
#include <hip/hip_bf16.h>
#include <math.h>

// ---------------------------------------------------------------------------
// TAPIR forward. State f32; mixer GEMMs + hid3 conv via bf16 MFMA.
// fg[64,64,256] hg[128,128,128] qf[1024,256] hq[1024,128] -> out[1024,4]
// ---------------------------------------------------------------------------

#define NQ 1024
#define TEMPF 20.0f
#define DIMV 388
#define INDIM 535
#define KPAD 544
#define HID 512

// workspace layout (float offsets)
#define WS_CV      0                          // 1024*4096 (dead after stripe)
#define WS_FGAVG   (WS_CV + NQ*4096)          // 32*32*256
#define WS_POS     (WS_FGAVG + 262144)        // 1024*2
#define WS_OCC     (WS_POS + NQ*2)            // 1024
#define WS_EXPD    (WS_OCC + NQ)              // 1024
#define WS_FEATS   (WS_EXPD + NQ)             // 1024*384
#define WS_MLPIN   (WS_FEATS + NQ*384)        // bf16 mlp_in [1024][544] (278528 fl)
#define WS_HIDDEN  (WS_MLPIN + NQ*KPAD)       // bf16 hidden [1024][512] / SUM3 f32
#define WS_W3B     (WS_HIDDEN + NQ*HID)       // bf16 hid3 B-fragments (5120 bf16)
// overlays:
#define WS_PART    (WS_MLPIN + 278528)        // 1024*32*4 softmax partials
#define WS_SUM3    WS_HIDDEN                  // 1024*16*32 hid3 relu-sums (dead after merge)
#define WS_WIT     WS_CV                      // bf16 [512][544] mix_in_w^T
#define WS_WOT     (WS_CV + 139264)           // bf16 [448][512] mix_out_w^T

#define OP 72                                 // occ LDS x-pitch

typedef __attribute__((ext_vector_type(8))) short bf16x8;
typedef __attribute__((ext_vector_type(4))) float f32x4;

// ---------------------------------------------------------------------------
// prep: fg 2x2 avg pyramid, feats=concat(hq,qf), W3B fragment pack, zero SUM3
// W3B flat idx: (((kt*2+nt)*16 + nl)*4 + q)*8 + e ; k=kt*32+q*8+e ;
//   k-order: k = tap*16 + ic  (tap>=9 -> 0)
// ---------------------------------------------------------------------------
__global__ __launch_bounds__(256) void k_prep(
    const float* __restrict__ fg, const float* __restrict__ qf,
    const float* __restrict__ hq, const float* __restrict__ w3,
    float* __restrict__ ws) {
  int i = blockIdx.x * 256 + threadIdx.x;
  if (i < 262144) {
    int c = i & 255, ox = (i >> 8) & 31, oy = i >> 13;
    const float* b = fg + (((oy * 2) * 64 + ox * 2) << 8) + c;
    ws[WS_FGAVG + i] = 0.25f * (b[0] + b[256] + b[16384] + b[16384 + 256]);
  } else if (i < 262144 + 393216) {
    int j = i - 262144;
    int n = j / 384, c = j - n * 384;
    ws[WS_FEATS + j] = (c < 128) ? hq[n * 128 + c] : qf[n * 256 + c - 128];
  } else if (i < 262144 + 393216 + 5120) {
    int j = i - (262144 + 393216);
    int e = j & 7, qd = (j >> 3) & 3, nl = (j >> 5) & 15;
    int nt = (j >> 9) & 1, kt = j >> 10;
    int k = kt * 32 + qd * 8 + e;
    int ic = k & 15, tap = k >> 4;
    int oc = nt * 16 + nl;
    float v = (tap < 9) ? w3[(oc * 16 + ic) * 9 + tap] : 0.f;
    ((__hip_bfloat16*)(ws + WS_W3B))[j] = __float2bfloat16(v);
  } else if (i < 262144 + 393216 + 5120 + 524288) {
    int j = i - (262144 + 393216 + 5120);
    ws[WS_SUM3 + j] = 0.f;
  }
}

// ---------------------------------------------------------------------------
// weight convert (runs AFTER stripe; overlays dead WS_CV)
// ---------------------------------------------------------------------------
__global__ __launch_bounds__(256) void k_cvt(
    const float* __restrict__ wi, const float* __restrict__ wo,
    float* __restrict__ ws) {
  int i = blockIdx.x * 256 + threadIdx.x;
  __hip_bfloat16* WIT = (__hip_bfloat16*)(ws + WS_WIT);
  __hip_bfloat16* WOT = (__hip_bfloat16*)(ws + WS_WOT);
  if (i < 278528) {
    int n = i / KPAD, k = i - n * KPAD;
    float v = (k < INDIM) ? wi[k * HID + n] : 0.f;
    WIT[i] = __float2bfloat16(v);
  } else if (i < 278528 + 229376) {
    int j = i - 278528;
    int n = j >> 9, k = j & 511;
    float v = (n < DIMV) ? wo[k * DIMV + n] : 0.f;
    WOT[j] = __float2bfloat16(v);
  }
}

// ---------------------------------------------------------------------------
// cost volume: cv[n][p] = sum_c qf[n][c] * fg[p][c]. 64x64 tile, BK=32.
// ---------------------------------------------------------------------------
__global__ __launch_bounds__(256) void k_cv(
    const float* __restrict__ qf, const float* __restrict__ fg,
    float* __restrict__ ws) {
  __shared__ float As[32][68];
  __shared__ float Bs[32][68];
  int t = threadIdx.x;
  int tx = t & 15, ty = t >> 4;
  int p0 = blockIdx.x * 64, m0 = blockIdx.y * 64;
  float acc[4][4] = {{0.f,0.f,0.f,0.f},{0.f,0.f,0.f,0.f},
                     {0.f,0.f,0.f,0.f},{0.f,0.f,0.f,0.f}};
  for (int k0 = 0; k0 < 256; k0 += 32) {
#pragma unroll
    for (int j = 0; j < 8; j++) {
      int idx = t + 256 * j;
      int kk = idx & 31, mm = idx >> 5;
      As[kk][mm] = qf[(m0 + mm) * 256 + k0 + kk];
      Bs[kk][mm] = fg[(p0 + mm) * 256 + k0 + kk];
    }
    __syncthreads();
#pragma unroll
    for (int k = 0; k < 32; k++) {
      float4 a = *(const float4*)&As[k][ty * 4];
      float4 b = *(const float4*)&Bs[k][tx * 4];
      float av[4] = {a.x, a.y, a.z, a.w};
      float bv[4] = {b.x, b.y, b.z, b.w};
#pragma unroll
      for (int i = 0; i < 4; i++)
#pragma unroll
        for (int jj = 0; jj < 4; jj++) acc[i][jj] += av[i] * bv[jj];
    }
    __syncthreads();
  }
#pragma unroll
  for (int i = 0; i < 4; i++) {
    float4 v = make_float4(acc[i][0], acc[i][1], acc[i][2], acc[i][3]);
    *(float4*)&ws[WS_CV + (m0 + ty * 4 + i) * 4096 + p0 + tx * 4] = v;
  }
}

// ---------------------------------------------------------------------------
// head stripe kernel: 1 block = (query, 4-row stripe). 16384 blocks.
// P1 (all waves): hid1 -> occ stripe (6 rows x 16 ch) in LDS.
// roles: 0/3 -> hid2+softmax (2 rows each); 1/2 -> hid3 MFMA (1 out-row each)
// ---------------------------------------------------------------------------
__global__ __launch_bounds__(256, 4) void k_head_stripe(
    const float* __restrict__ h1w, const float* __restrict__ h1b,
    const float* __restrict__ h2w, const float* __restrict__ h2b,
    const float* __restrict__ h3b, float* __restrict__ ws) {
  __shared__ float cvs[8 * 66];          // cv rows y0-2..y0+5, x -1..64
  __shared__ float occ[6 * 16 * OP];     // [r][ch][x+4]

  const int bx = blockIdx.x;
  const int q = bx >> 4, st = bx & 15;
  const int y0 = st * 4;
  const int t = threadIdx.x;
  const int wv = t >> 6, lane = t & 63;
  const int role = (wv + bx) & 3;
  const float* cv = ws + WS_CV + q * 4096;

  {
    float4 z = make_float4(0.f, 0.f, 0.f, 0.f);
    float4* o4 = (float4*)occ;
    for (int i = t; i < 6 * 16 * OP / 4; i += 256) o4[i] = z;
  }
#pragma unroll
  for (int j = 0; j < 2; j++) {
    int i = t + 256 * j;
    int lr = i >> 6, x = i & 63;
    int g = y0 - 2 + lr;
    cvs[lr * 66 + x + 1] = (g >= 0 && g < 64) ? cv[g * 64 + x] : 0.f;
  }
  if (t < 16) cvs[(t >> 1) * 66 + (t & 1) * 65] = 0.f;
  __syncthreads();

  // ---- P1: hid1 conv, occ rows r=0..5 (yo=y0-1+r), wave = 4 channels ----
  {
    const int x = lane;
    const int chg = wv * 4;
    float w1r[4][9], b1r[4];
#pragma unroll
    for (int k = 0; k < 4; k++) {
      b1r[k] = h1b[chg + k];
#pragma unroll
      for (int j = 0; j < 9; j++) w1r[k][j] = h1w[(chg + k) * 9 + j];
    }
    for (int r = 0; r < 6; r++) {
      int yo = y0 - 1 + r;
      if (yo >= 0 && yo <= 63) {
        float p[9];
#pragma unroll
        for (int ky = 0; ky < 3; ky++) {
          const float* cp = &cvs[(r + ky) * 66 + x];
          p[3 * ky] = cp[0]; p[3 * ky + 1] = cp[1]; p[3 * ky + 2] = cp[2];
        }
#pragma unroll
        for (int k = 0; k < 4; k++) {
          float a = b1r[k];
#pragma unroll
          for (int j = 0; j < 9; j++) a += w1r[k][j] * p[j];
          occ[(r * 16 + chg + k) * OP + x + 4] = fmaxf(a, 0.f);
        }
      }
    }
  }
  __syncthreads();

  if (role == 1 || role == 2) {
    // ---- hid3 MFMA: one output row (oyl = role-1). M=32 ox, N=32 oc, K=160.
    // k-order: k = tap*16 + ic. a-frag: lane nl=m(ox), quad -> (tap half, ic half)
    const __hip_bfloat16* W3B = (const __hip_bfloat16*)(ws + WS_W3B);
    const int oyl = role - 1;
    const int nl = lane & 15;
    const int qd = lane >> 4, qh = qd >> 1, ql = qd & 1;
    f32x4 acc00 = {0.f,0.f,0.f,0.f}, acc01 = {0.f,0.f,0.f,0.f};
    f32x4 acc10 = {0.f,0.f,0.f,0.f}, acc11 = {0.f,0.f,0.f,0.f};
#pragma unroll
    for (int kt = 0; kt < 5; kt++) {
      int tap = kt * 2 + qh;               // 0..9 (9 => zero pad)
      int tv = (tap < 9) ? tap : 0;
      int ky = (tv >= 6) ? 2 : ((tv >= 3) ? 1 : 0);
      int kx = tv - 3 * ky;
      const float* ap =
          &occ[((2 * oyl + 1 + ky) * 16 + ql * 8) * OP + 4 + kx + 2 * nl];
      union { bf16x8 v; __hip_bfloat16 h[8]; } a0u, a1u;
      if (tap < 9) {
#pragma unroll
        for (int j = 0; j < 8; j++) {
          a0u.h[j] = __float2bfloat16(ap[j * OP]);
          a1u.h[j] = __float2bfloat16(ap[j * OP + 32]);
        }
      } else {
#pragma unroll
        for (int j = 0; j < 8; j++) {
          a0u.h[j] = __float2bfloat16(0.f);
          a1u.h[j] = __float2bfloat16(0.f);
        }
      }
      bf16x8 b0 = *(const bf16x8*)&W3B[((kt * 2 + 0) * 16 + nl) * 32 + qd * 8];
      bf16x8 b1 = *(const bf16x8*)&W3B[((kt * 2 + 1) * 16 + nl) * 32 + qd * 8];
      acc00 = __builtin_amdgcn_mfma_f32_16x16x32_bf16(a0u.v, b0, acc00, 0, 0, 0);
      acc01 = __builtin_amdgcn_mfma_f32_16x16x32_bf16(a0u.v, b1, acc01, 0, 0, 0);
      acc10 = __builtin_amdgcn_mfma_f32_16x16x32_bf16(a1u.v, b0, acc10, 0, 0, 0);
      acc11 = __builtin_amdgcn_mfma_f32_16x16x32_bf16(a1u.v, b1, acc11, 0, 0, 0);
    }
    // epilogue: relu(acc + bias) summed over all 32 ox
    float bb0 = h3b[nl], bb1 = h3b[16 + nl];
    float s0 = 0.f, s1 = 0.f;
#pragma unroll
    for (int r = 0; r < 4; r++) {
      s0 += fmaxf(acc00[r] + bb0, 0.f) + fmaxf(acc10[r] + bb0, 0.f);
      s1 += fmaxf(acc01[r] + bb1, 0.f) + fmaxf(acc11[r] + bb1, 0.f);
    }
    s0 += __shfl_xor(s0, 16); s0 += __shfl_xor(s0, 32);
    s1 += __shfl_xor(s1, 16); s1 += __shfl_xor(s1, 32);
    if (lane < 16) {
      atomicAdd(&ws[WS_SUM3 + (q * 16 + st) * 32 + nl], s0);
      atomicAdd(&ws[WS_SUM3 + (q * 16 + st) * 32 + 16 + nl], s1);
    }
  } else {
    // ---- hid2 + softmax partial on 2 rows ----
    const int rl = ((role == 3) ? 2 : 0) + (lane >> 5);
    const int yg = y0 + rl;
    const int x0 = (lane & 31) * 2;
    float pa = 0.f, pb = 0.f;
    for (int ch = 0; ch < 16; ch++) {
#pragma unroll
      for (int ky = 0; ky < 3; ky++) {
        const float* bp = &occ[((rl + ky) * 16 + ch) * OP + x0];
        float f0 = bp[3];
        float2 fm = *(const float2*)(bp + 4);
        float f3 = bp[6];
        float wa = h2w[ch * 9 + 3 * ky], wb = h2w[ch * 9 + 3 * ky + 1],
              wc = h2w[ch * 9 + 3 * ky + 2];
        pa += wa * f0 + wb * fm.x + wc * fm.y;
        pb += wa * fm.x + wb * fm.y + wc * f3;
      }
    }
    float bb = h2b[0];
    float v0 = (pa + bb) * TEMPF, v1 = (pb + bb) * TEMPF;
    float mg = fmaxf(v0, v1);
#pragma unroll
    for (int off = 1; off < 64; off <<= 1) mg = fmaxf(mg, __shfl_xor(mg, off));
    float e0 = __expf(v0 - mg), e1 = __expf(v1 - mg);
    float s = e0 + e1;
    float sx = e0 * (float)x0 + e1 * (float)(x0 + 1);
    float sy = s * (float)yg;
#pragma unroll
    for (int off = 1; off < 64; off <<= 1) {
      s += __shfl_xor(s, off);
      sx += __shfl_xor(sx, off);
      sy += __shfl_xor(sy, off);
    }
    if (lane == 0) {
      int slot = q * 32 + st * 2 + ((role == 3) ? 1 : 0);
      *(float4*)&ws[WS_PART + slot * 4] = make_float4(mg, s, sx, sy);
    }
  }
}

// ---------------------------------------------------------------------------
// head merge: 32 softmax partials + 16 hid3 sum slots per query
// ---------------------------------------------------------------------------
__global__ __launch_bounds__(256) void k_head_merge(
    const float* __restrict__ w4, const float* __restrict__ b4,
    const float* __restrict__ w5, const float* __restrict__ b5,
    float* __restrict__ ws) {
  __shared__ float sums_s[4][32];
  __shared__ float o4s[4][16];
  int t = threadIdx.x, wv = t >> 6, lane = t & 63;
  int q = blockIdx.x * 4 + wv;

  float M = -1e30f, S = 0.f, SX = 0.f, SY = 0.f;
  if (lane < 32) {
    float4 pv = *(const float4*)&ws[WS_PART + (q * 32 + lane) * 4];
    M = pv.x; S = pv.y; SX = pv.z; SY = pv.w;
  }
#pragma unroll
  for (int off = 1; off < 64; off <<= 1) {
    float Mo = __shfl_xor(M, off), So = __shfl_xor(S, off);
    float SXo = __shfl_xor(SX, off), SYo = __shfl_xor(SY, off);
    float Mn = fmaxf(M, Mo);
    float c1 = __expf(M - Mn), c2 = __expf(Mo - Mn);
    S = S * c1 + So * c2; SX = SX * c1 + SXo * c2; SY = SY * c1 + SYo * c2;
    M = Mn;
  }
  if (lane == 0) {
    ws[WS_POS + q * 2 + 0] = (SX / S) * 8.0f;
    ws[WS_POS + q * 2 + 1] = (SY / S) * 8.0f;
  }

  int ch = lane & 31, half = lane >> 5;
  float sm = 0.f;
#pragma unroll
  for (int s8 = 0; s8 < 8; s8++)
    sm += ws[WS_SUM3 + (q * 16 + half * 8 + s8) * 32 + ch];
  sm += __shfl_xor(sm, 32);
  if (lane < 32) sums_s[wv][lane] = sm * (1.f / 1024.f);
  __syncthreads();
  if (lane < 16) {
    float a = b4[lane];
#pragma unroll
    for (int i = 0; i < 32; i++) a += sums_s[wv][i] * w4[i * 16 + lane];
    o4s[wv][lane] = fmaxf(a, 0.f);
  }
  __syncthreads();
  if (lane < 2) {
    float r = b5[lane];
#pragma unroll
    for (int j = 0; j < 16; j++) r += o4s[wv][j] * w5[j * 2 + lane];
    if (lane == 0) ws[WS_OCC + q] = r;
    else           ws[WS_EXPD + q] = r;
  }
}

// ---------------------------------------------------------------------------
// correlation + bf16 mlp_in assembly. 1 block = 1 query.
// ---------------------------------------------------------------------------
__global__ __launch_bounds__(256) void k_corr(
    const float* __restrict__ fg, const float* __restrict__ hg,
    float* __restrict__ ws) {
  __shared__ float qs[384];
  __shared__ float dbuf[3][64];
  int t = threadIdx.x;
  int wv = t >> 6, lane = t & 63;
  int cl = lane & 15, sub = lane >> 4;
  int n = blockIdx.x;
  const float* feats = ws + WS_FEATS + n * 384;
  float posx = ws[WS_POS + n * 2 + 0];
  float posy = ws[WS_POS + n * 2 + 1];
  __hip_bfloat16* mi = (__hip_bfloat16*)(ws + WS_MLPIN) + n * KPAD;

  for (int col = t; col < 384; col += 256) {
    float v = feats[col];
    qs[col] = v;
    mi[4 + col] = __float2bfloat16(v);
  }
  if (t < 4) {
    float v = (t == 2) ? ws[WS_OCC + n] : ((t == 3) ? ws[WS_EXPD + n] : 0.f);
    mi[t] = __float2bfloat16(v);
  }
  __syncthreads();

  float4 qh0 = *(const float4*)&qs[cl * 4];
  float4 qh1 = *(const float4*)&qs[64 + cl * 4];
  float4 qq0 = *(const float4*)&qs[128 + cl * 4];
  float4 qq1 = *(const float4*)&qs[192 + cl * 4];
  float4 qq2 = *(const float4*)&qs[256 + cl * 4];
  float4 qq3 = *(const float4*)&qs[320 + cl * 4];

#pragma unroll
  for (int L = 0; L < 3; L++) {
    const float* grid;
    int Hg, Wg;
    float scl;
    if (L == 0)      { grid = hg;             Hg = 128; Wg = 128; scl = 0.25f; }
    else if (L == 1) { grid = fg;             Hg = 64;  Wg = 64;  scl = 0.125f; }
    else             { grid = ws + WS_FGAVG;  Hg = 32;  Wg = 32;  scl = 0.0625f; }
    float cy = posy * scl, cx = posx * scl;
    int iy = (int)floorf(cy), ix = (int)floorf(cx);
#pragma unroll
    for (int g = 0; g < 4; g++) {
      int p = wv * 16 + g * 4 + sub;
      int a = p >> 3, b = p & 7;
      int row = iy + a - 3; row = row < 0 ? 0 : (row > Hg - 1 ? Hg - 1 : row);
      int col = ix + b - 3; col = col < 0 ? 0 : (col > Wg - 1 ? Wg - 1 : col);
      float acc;
      if (L == 0) {
        const float* gp = grid + (row * Wg + col) * 128 + cl * 4;
        float4 g0 = *(const float4*)gp;
        float4 g1 = *(const float4*)(gp + 64);
        acc = g0.x * qh0.x + g0.y * qh0.y + g0.z * qh0.z + g0.w * qh0.w +
              g1.x * qh1.x + g1.y * qh1.y + g1.z * qh1.z + g1.w * qh1.w;
      } else {
        const float* gp = grid + (row * Wg + col) * 256 + cl * 4;
        float4 g0 = *(const float4*)gp;
        float4 g1 = *(const float4*)(gp + 64);
        float4 g2 = *(const float4*)(gp + 128);
        float4 g3 = *(const float4*)(gp + 192);
        acc = g0.x * qq0.x + g0.y * qq0.y + g0.z * qq0.z + g0.w * qq0.w +
              g1.x * qq1.x + g1.y * qq1.y + g1.z * qq1.z + g1.w * qq1.w +
              g2.x * qq2.x + g2.y * qq2.y + g2.z * qq2.z + g2.w * qq2.w +
              g3.x * qq3.x + g3.y * qq3.y + g3.z * qq3.z + g3.w * qq3.w;
      }
      acc += __shfl_xor(acc, 1);
      acc += __shfl_xor(acc, 2);
      acc += __shfl_xor(acc, 4);
      acc += __shfl_xor(acc, 8);
      if (cl == 0) dbuf[L][p] = acc;
    }
  }
  __syncthreads();

  if (t < 147) {
    int L = t / 49, s = t - L * 49;
    int sa = s / 7, sb = s - sa * 7;
    float scl = (L == 0) ? 0.25f : ((L == 1) ? 0.125f : 0.0625f);
    float cy = posy * scl, cx = posx * scl;
    float wy = cy - floorf(cy), wx = cx - floorf(cx);
    int i00 = sa * 8 + sb;
    float d00 = dbuf[L][i00], d01 = dbuf[L][i00 + 1];
    float d10 = dbuf[L][i00 + 8], d11 = dbuf[L][i00 + 9];
    float corr = (1.f - wy) * (1.f - wx) * d00 + (1.f - wy) * wx * d01 +
                 wy * (1.f - wx) * d10 + wy * wx * d11;
    mi[388 + t] = __float2bfloat16(corr);
  }
}

// ---------------------------------------------------------------------------
__device__ __forceinline__ float gelu_tanh(float x) {
  float z = 0.7978845608028654f * (x + 0.044715f * x * x * x);
  z = fminf(fmaxf(z, -15.f), 15.f);
  float e = __expf(2.f * z);
  float th = (e - 1.f) / (e + 1.f);
  return 0.5f * x * (1.f + th);
}

// ---------------------------------------------------------------------------
// mixer GEMM 1 (MFMA bf16): hidden = gelu(mlp_in @ mix_in_w + b)
// ---------------------------------------------------------------------------
__global__ __launch_bounds__(256) void k_mix1(
    const float* __restrict__ bias, float* __restrict__ ws) {
  __shared__ __hip_bfloat16 A_s[32 * 32];
  __shared__ __hip_bfloat16 B_s[64 * 32];
  const int t = threadIdx.x;
  const int wv = t >> 6, lane = t & 63;
  const int wm = wv & 1, wn = wv >> 1;
  const int quad = lane >> 4, nl = lane & 15;
  const int n0 = blockIdx.x * 64, m0 = blockIdx.y * 32;
  const unsigned short* Abf = (const unsigned short*)(ws + WS_MLPIN);
  const unsigned short* WIT = (const unsigned short*)(ws + WS_WIT);
  f32x4 acc0 = {0.f, 0.f, 0.f, 0.f};
  f32x4 acc1 = {0.f, 0.f, 0.f, 0.f};

  for (int k0 = 0; k0 < KPAD; k0 += 32) {
    if (t < 128) {
      int r = t >> 2, c = t & 3;
      *(uint4*)&A_s[r * 32 + c * 8] =
          *(const uint4*)&Abf[(m0 + r) * KPAD + k0 + c * 8];
    }
    {
      int r = t >> 2, c = t & 3;
      *(uint4*)&B_s[r * 32 + c * 8] =
          *(const uint4*)&WIT[(n0 + r) * KPAD + k0 + c * 8];
    }
    __syncthreads();
    bf16x8 a = *(const bf16x8*)&A_s[(16 * wm + nl) * 32 + quad * 8];
    bf16x8 b0 = *(const bf16x8*)&B_s[(32 * wn + nl) * 32 + quad * 8];
    bf16x8 b1 = *(const bf16x8*)&B_s[(32 * wn + 16 + nl) * 32 + quad * 8];
    acc0 = __builtin_amdgcn_mfma_f32_16x16x32_bf16(a, b0, acc0, 0, 0, 0);
    acc1 = __builtin_amdgcn_mfma_f32_16x16x32_bf16(a, b1, acc1, 0, 0, 0);
    __syncthreads();
  }

  __hip_bfloat16* Hd = (__hip_bfloat16*)(ws + WS_HIDDEN);
#pragma unroll
  for (int nt = 0; nt < 2; nt++) {
    int nn = n0 + 32 * wn + nt * 16 + nl;
    float bv = bias[nn];
#pragma unroll
    for (int r = 0; r < 4; r++) {
      int m = m0 + 16 * wm + quad * 4 + r;
      float v = gelu_tanh((nt ? acc1[r] : acc0[r]) + bv);
      Hd[m * HID + nn] = __float2bfloat16(v);
    }
  }
}

// ---------------------------------------------------------------------------
// mixer GEMM 2 (MFMA bf16) + state update + out write
// ---------------------------------------------------------------------------
__global__ __launch_bounds__(256) void k_mix2(
    const float* __restrict__ bias, float* __restrict__ ws,
    float* __restrict__ out) {
  __shared__ __hip_bfloat16 A_s[32 * 32];
  __shared__ __hip_bfloat16 B_s[64 * 32];
  const int t = threadIdx.x;
  const int wv = t >> 6, lane = t & 63;
  const int wm = wv & 1, wn = wv >> 1;
  const int quad = lane >> 4, nl = lane & 15;
  const int n0 = blockIdx.x * 64, m0 = blockIdx.y * 32;
  const unsigned short* Abf = (const unsigned short*)(ws + WS_HIDDEN);
  const unsigned short* WOT = (const unsigned short*)(ws + WS_WOT);
  f32x4 acc0 = {0.f, 0.f, 0.f, 0.f};
  f32x4 acc1 = {0.f, 0.f, 0.f, 0.f};

  for (int k0 = 0; k0 < HID; k0 += 32) {
    if (t < 128) {
      int r = t >> 2, c = t & 3;
      *(uint4*)&A_s[r * 32 + c * 8] =
          *(const uint4*)&Abf[(m0 + r) * HID + k0 + c * 8];
    }
    {
      int r = t >> 2, c = t & 3;
      *(uint4*)&B_s[r * 32 + c * 8] =
          *(const uint4*)&WOT[(n0 + r) * HID + k0 + c * 8];
    }
    __syncthreads();
    bf16x8 a = *(const bf16x8*)&A_s[(16 * wm + nl) * 32 + quad * 8];
    bf16x8 b0 = *(const bf16x8*)&B_s[(32 * wn + nl) * 32 + quad * 8];
    bf16x8 b1 = *(const bf16x8*)&B_s[(32 * wn + 16 + nl) * 32 + quad * 8];
    acc0 = __builtin_amdgcn_mfma_f32_16x16x32_bf16(a, b0, acc0, 0, 0, 0);
    acc1 = __builtin_amdgcn_mfma_f32_16x16x32_bf16(a, b1, acc1, 0, 0, 0);
    __syncthreads();
  }

#pragma unroll
  for (int nt = 0; nt < 2; nt++) {
    int col = n0 + 32 * wn + nt * 16 + nl;
    if (col >= DIMV) continue;
    float bv = bias[col];
#pragma unroll
    for (int r = 0; r < 4; r++) {
      int m = m0 + 16 * wm + quad * 4 + r;
      float rr = (nt ? acc1[r] : acc0[r]) + bv;
      if (col < 2) {
        float v = ws[WS_POS + m * 2 + col] + rr;
        ws[WS_POS + m * 2 + col] = v;
        out[m * 4 + col] = v;
      } else if (col == 2) {
        float v = ws[WS_OCC + m] + rr;
        ws[WS_OCC + m] = v;
        out[m * 4 + 2] = v;
      } else if (col == 3) {
        float v = ws[WS_EXPD + m] + rr;
        ws[WS_EXPD + m] = v;
        out[m * 4 + 3] = v;
      } else {
        ws[WS_FEATS + m * 384 + (col - 4)] += rr;
      }
    }
  }
}

// ---------------------------------------------------------------------------
extern "C" void kernel_launch(void* const* d_in, const int* in_sizes, int n_in,
                              void* d_out, int out_size, void* d_ws, size_t ws_size,
                              hipStream_t stream) {
  const float* fg = (const float*)d_in[0];
  const float* hg = (const float*)d_in[1];
  const float* qf = (const float*)d_in[2];
  const float* hq = (const float*)d_in[3];
  const float* w1 = (const float*)d_in[4];
  const float* b1 = (const float*)d_in[5];
  const float* w2 = (const float*)d_in[6];
  const float* b2 = (const float*)d_in[7];
  const float* w3 = (const float*)d_in[8];
  const float* b3 = (const float*)d_in[9];
  const float* w4 = (const float*)d_in[10];
  const float* b4 = (const float*)d_in[11];
  const float* w5 = (const float*)d_in[12];
  const float* b5 = (const float*)d_in[13];
  const float* wi = (const float*)d_in[14];
  const float* bi = (const float*)d_in[15];
  const float* wo = (const float*)d_in[16];
  const float* bo = (const float*)d_in[17];
  float* ws = (float*)d_ws;
  float* out = (float*)d_out;

  k_prep<<<4628, 256, 0, stream>>>(fg, qf, hq, w3, ws);
  k_cv<<<dim3(64, 16), 256, 0, stream>>>(qf, fg, ws);
  k_head_stripe<<<16384, 256, 0, stream>>>(w1, b1, w2, b2, b3, ws);
  k_head_merge<<<256, 256, 0, stream>>>(w4, b4, w5, b5, ws);
  k_cvt<<<1984, 256, 0, stream>>>(wi, wo, ws);
  for (int it = 0; it < 4; it++) {
    k_corr<<<1024, 256, 0, stream>>>(fg, hg, ws);
    k_mix1<<<dim3(8, 32), 256, 0, stream>>>(bi, ws);
    k_mix2<<<dim3(7, 32), 256, 0, stream>>>(bo, ws, out);
  }
}

// Round 8
// 340.750 us; speedup vs baseline: 6.2401x; 1.0601x over previous
//
#include <hip/hip_runtime.h>
#include <hip/hip_bf16.h>
#include <math.h>

// ---------------------------------------------------------------------------
// TAPIR forward. State f32; cv + mixer GEMMs + hid3 conv via bf16 MFMA.
// fg[64,64,256] hg[128,128,128] qf[1024,256] hq[1024,128] -> out[1024,4]
// ---------------------------------------------------------------------------

#define NQ 1024
#define TEMPF 20.0f
#define DIMV 388
#define INDIM 535
#define KPAD 544
#define HID 512

// workspace layout (float offsets)
#define WS_CV      0                          // 1024*4096 (dead after stripe)
#define WS_FGAVG   (WS_CV + NQ*4096)          // 32*32*256
#define WS_POS     (WS_FGAVG + 262144)        // 1024*2
#define WS_OCC     (WS_POS + NQ*2)            // 1024
#define WS_EXPD    (WS_OCC + NQ)              // 1024
#define WS_FEATS   (WS_EXPD + NQ)             // 1024*384
#define WS_MLPIN   (WS_FEATS + NQ*384)        // bf16 mlp_in [1024][544] (278528 fl)
#define WS_HIDDEN  (WS_MLPIN + NQ*KPAD)       // bf16 hidden [1024][512] / SUM3 f32
#define WS_W3B     (WS_HIDDEN + NQ*HID)       // bf16 hid3 B-fragments (5120 bf16)
// overlays:
#define WS_PART    (WS_MLPIN + 278528)        // 1024*32*4 softmax partials
#define WS_SUM3    WS_HIDDEN                  // 1024*16*32 hid3 relu-sums (dead after merge)
#define WS_WIT     WS_CV                      // bf16 [512][544] mix_in_w^T
#define WS_WOT     (WS_CV + 139264)           // bf16 [448][512] mix_out_w^T

#define OP 72                                 // occ LDS x-pitch
#define CVP 68                                // cvs LDS pitch (16B-aligned rows)

typedef __attribute__((ext_vector_type(8))) short bf16x8;
typedef __attribute__((ext_vector_type(4))) float f32x4;

// ---------------------------------------------------------------------------
// prep: fg 2x2 avg pyramid, feats=concat(hq,qf), W3B fragment pack, zero SUM3
// ---------------------------------------------------------------------------
__global__ __launch_bounds__(256) void k_prep(
    const float* __restrict__ fg, const float* __restrict__ qf,
    const float* __restrict__ hq, const float* __restrict__ w3,
    float* __restrict__ ws) {
  int i = blockIdx.x * 256 + threadIdx.x;
  if (i < 262144) {
    int c = i & 255, ox = (i >> 8) & 31, oy = i >> 13;
    const float* b = fg + (((oy * 2) * 64 + ox * 2) << 8) + c;
    ws[WS_FGAVG + i] = 0.25f * (b[0] + b[256] + b[16384] + b[16384 + 256]);
  } else if (i < 262144 + 393216) {
    int j = i - 262144;
    int n = j / 384, c = j - n * 384;
    ws[WS_FEATS + j] = (c < 128) ? hq[n * 128 + c] : qf[n * 256 + c - 128];
  } else if (i < 262144 + 393216 + 5120) {
    int j = i - (262144 + 393216);
    int e = j & 7, qd = (j >> 3) & 3, nl = (j >> 5) & 15;
    int nt = (j >> 9) & 1, kt = j >> 10;
    int k = kt * 32 + qd * 8 + e;
    int ic = k & 15, tap = k >> 4;
    int oc = nt * 16 + nl;
    float v = (tap < 9) ? w3[(oc * 16 + ic) * 9 + tap] : 0.f;
    ((__hip_bfloat16*)(ws + WS_W3B))[j] = __float2bfloat16(v);
  } else if (i < 262144 + 393216 + 5120 + 524288) {
    int j = i - (262144 + 393216 + 5120);
    ws[WS_SUM3 + j] = 0.f;
  }
}

// ---------------------------------------------------------------------------
// cost volume (bf16 MFMA): cv[m=query][n=pixel] = qf . fg, K=256.
// 32m x 64n tile, inline f32->bf16 staging. grid (64, 32).
// ---------------------------------------------------------------------------
__global__ __launch_bounds__(256) void k_cv(
    const float* __restrict__ qf, const float* __restrict__ fg,
    float* __restrict__ ws) {
  __shared__ __hip_bfloat16 A_s[32 * 32];
  __shared__ __hip_bfloat16 B_s[64 * 32];
  const int t = threadIdx.x;
  const int wv = t >> 6, lane = t & 63;
  const int wm = wv & 1, wn = wv >> 1;
  const int quad = lane >> 4, nl = lane & 15;
  const int p0 = blockIdx.x * 64, m0 = blockIdx.y * 32;
  f32x4 acc0 = {0.f, 0.f, 0.f, 0.f};
  f32x4 acc1 = {0.f, 0.f, 0.f, 0.f};

  for (int k0 = 0; k0 < 256; k0 += 32) {
    {
      int r = t >> 3, c = t & 7;
      float4 v = *(const float4*)&qf[(m0 + r) * 256 + k0 + c * 4];
      union { __hip_bfloat16 h[4]; uint2 u; } pk;
      pk.h[0] = __float2bfloat16(v.x); pk.h[1] = __float2bfloat16(v.y);
      pk.h[2] = __float2bfloat16(v.z); pk.h[3] = __float2bfloat16(v.w);
      *(uint2*)&A_s[r * 32 + c * 4] = pk.u;
    }
    {
      int r = t >> 2, c = t & 3;
      const float* src = &fg[(p0 + r) * 256 + k0 + c * 8];
      float4 v0 = *(const float4*)src;
      float4 v1 = *(const float4*)(src + 4);
      union { __hip_bfloat16 h[8]; uint4 u; } pk;
      pk.h[0] = __float2bfloat16(v0.x); pk.h[1] = __float2bfloat16(v0.y);
      pk.h[2] = __float2bfloat16(v0.z); pk.h[3] = __float2bfloat16(v0.w);
      pk.h[4] = __float2bfloat16(v1.x); pk.h[5] = __float2bfloat16(v1.y);
      pk.h[6] = __float2bfloat16(v1.z); pk.h[7] = __float2bfloat16(v1.w);
      *(uint4*)&B_s[r * 32 + c * 8] = pk.u;
    }
    __syncthreads();
    bf16x8 a = *(const bf16x8*)&A_s[(16 * wm + nl) * 32 + quad * 8];
    bf16x8 b0 = *(const bf16x8*)&B_s[(32 * wn + nl) * 32 + quad * 8];
    bf16x8 b1 = *(const bf16x8*)&B_s[(32 * wn + 16 + nl) * 32 + quad * 8];
    acc0 = __builtin_amdgcn_mfma_f32_16x16x32_bf16(a, b0, acc0, 0, 0, 0);
    acc1 = __builtin_amdgcn_mfma_f32_16x16x32_bf16(a, b1, acc1, 0, 0, 0);
    __syncthreads();
  }
#pragma unroll
  for (int nt = 0; nt < 2; nt++) {
    int n = p0 + 32 * wn + nt * 16 + nl;
#pragma unroll
    for (int r = 0; r < 4; r++) {
      int m = m0 + 16 * wm + quad * 4 + r;
      ws[WS_CV + m * 4096 + n] = (nt ? acc1[r] : acc0[r]);
    }
  }
}

// ---------------------------------------------------------------------------
// head stripe kernel: 1 block = (query, 4-row stripe). 16384 blocks.
// P1 (all waves): hid1 -> occ stripe, 4px/lane vectorized LDS.
// roles: 0/3 -> hid2+softmax (2 rows each); 1/2 -> hid3 MFMA (1 out-row each)
// ---------------------------------------------------------------------------
__global__ __launch_bounds__(256, 4) void k_head_stripe(
    const float* __restrict__ h1w, const float* __restrict__ h1b,
    const float* __restrict__ h2w, const float* __restrict__ h2b,
    const float* __restrict__ h3b, float* __restrict__ ws) {
  __shared__ float cvs[8 * CVP];         // cv rows y0-2..y0+5, x -1..64
  __shared__ float occ[6 * 16 * OP];     // [r][ch][x+4]

  const int bx = blockIdx.x;
  const int q = bx >> 4, st = bx & 15;
  const int y0 = st * 4;
  const int t = threadIdx.x;
  const int wv = t >> 6, lane = t & 63;
  const int role = (wv + bx) & 3;
  const float* cv = ws + WS_CV + q * 4096;

  // halo cols 0-3 / 68-71 of all 96 (r,ch) rows
  if (t < 192) {
    int rc = t >> 1, side = t & 1;
    *(float4*)&occ[rc * OP + side * 68] = make_float4(0.f, 0.f, 0.f, 0.f);
  }
  // out-of-range occ row (st==0: r=0 ; st==15: r=5)
  if (st == 0 || st == 15) {
    int r = (st == 0) ? 0 : 5;
    for (int i = t; i < 16 * 18; i += 256)
      *(float4*)&occ[(r * 16 + (i / 18)) * OP + (i % 18) * 4] =
          make_float4(0.f, 0.f, 0.f, 0.f);
  }
  // cv stripe load
#pragma unroll
  for (int j = 0; j < 2; j++) {
    int i = t + 256 * j;
    int lr = i >> 6, x = i & 63;
    int g = y0 - 2 + lr;
    cvs[lr * CVP + x + 1] = (g >= 0 && g < 64) ? cv[g * 64 + x] : 0.f;
  }
  if (t < 32) {
    int rr = t >> 2, c = t & 3;
    cvs[rr * CVP + ((c == 0) ? 0 : (64 + c))] = 0.f;  // idx 0,65,66,67
  }
  __syncthreads();

  // ---- P1: hid1 conv, 4 px/lane, wave = 4 channels ----
  {
    const int chg = wv * 4;
    const int xg = lane & 15, rsel = lane >> 4;
    const int x0 = xg * 4;
    float w1r[4][9], b1r[4];
#pragma unroll
    for (int k = 0; k < 4; k++) {
      b1r[k] = h1b[chg + k];
#pragma unroll
      for (int j = 0; j < 9; j++) w1r[k][j] = h1w[(chg + k) * 9 + j];
    }
#pragma unroll
    for (int p = 0; p < 2; p++) {
      int r = p * 4 + rsel;
      int yo = y0 - 1 + r;
      if (r < 6 && yo >= 0 && yo <= 63) {
        float rb[3][6];
#pragma unroll
        for (int ky = 0; ky < 3; ky++) {
          const float* cp = &cvs[(r + ky) * CVP + x0];
          float4 a4 = *(const float4*)cp;
          float2 b2 = *(const float2*)(cp + 4);
          rb[ky][0] = a4.x; rb[ky][1] = a4.y; rb[ky][2] = a4.z;
          rb[ky][3] = a4.w; rb[ky][4] = b2.x; rb[ky][5] = b2.y;
        }
#pragma unroll
        for (int k = 0; k < 4; k++) {
          float o[4];
#pragma unroll
          for (int px = 0; px < 4; px++) {
            float a = b1r[k];
#pragma unroll
            for (int ky = 0; ky < 3; ky++)
              a += w1r[k][3 * ky] * rb[ky][px] +
                   w1r[k][3 * ky + 1] * rb[ky][px + 1] +
                   w1r[k][3 * ky + 2] * rb[ky][px + 2];
            o[px] = fmaxf(a, 0.f);
          }
          *(float4*)&occ[(r * 16 + chg + k) * OP + x0 + 4] =
              make_float4(o[0], o[1], o[2], o[3]);
        }
      }
    }
  }
  __syncthreads();

  if (role == 1 || role == 2) {
    // ---- hid3 MFMA: one output row (oyl = role-1). M=32 ox, N=32 oc, K=160.
    const __hip_bfloat16* W3B = (const __hip_bfloat16*)(ws + WS_W3B);
    const int oyl = role - 1;
    const int nl = lane & 15;
    const int qd = lane >> 4, qh = qd >> 1, ql = qd & 1;
    f32x4 acc00 = {0.f,0.f,0.f,0.f}, acc01 = {0.f,0.f,0.f,0.f};
    f32x4 acc10 = {0.f,0.f,0.f,0.f}, acc11 = {0.f,0.f,0.f,0.f};
#pragma unroll
    for (int kt = 0; kt < 5; kt++) {
      int tap = kt * 2 + qh;               // 0..9 (9 => zero pad)
      int tv = (tap < 9) ? tap : 0;
      int ky = (tv >= 6) ? 2 : ((tv >= 3) ? 1 : 0);
      int kx = tv - 3 * ky;
      const float* ap =
          &occ[((2 * oyl + 1 + ky) * 16 + ql * 8) * OP + 4 + kx + 2 * nl];
      union { bf16x8 v; __hip_bfloat16 h[8]; } a0u, a1u;
      if (tap < 9) {
#pragma unroll
        for (int j = 0; j < 8; j++) {
          a0u.h[j] = __float2bfloat16(ap[j * OP]);
          a1u.h[j] = __float2bfloat16(ap[j * OP + 32]);
        }
      } else {
#pragma unroll
        for (int j = 0; j < 8; j++) {
          a0u.h[j] = __float2bfloat16(0.f);
          a1u.h[j] = __float2bfloat16(0.f);
        }
      }
      bf16x8 b0 = *(const bf16x8*)&W3B[((kt * 2 + 0) * 16 + nl) * 32 + qd * 8];
      bf16x8 b1 = *(const bf16x8*)&W3B[((kt * 2 + 1) * 16 + nl) * 32 + qd * 8];
      acc00 = __builtin_amdgcn_mfma_f32_16x16x32_bf16(a0u.v, b0, acc00, 0, 0, 0);
      acc01 = __builtin_amdgcn_mfma_f32_16x16x32_bf16(a0u.v, b1, acc01, 0, 0, 0);
      acc10 = __builtin_amdgcn_mfma_f32_16x16x32_bf16(a1u.v, b0, acc10, 0, 0, 0);
      acc11 = __builtin_amdgcn_mfma_f32_16x16x32_bf16(a1u.v, b1, acc11, 0, 0, 0);
    }
    float bb0 = h3b[nl], bb1 = h3b[16 + nl];
    float s0 = 0.f, s1 = 0.f;
#pragma unroll
    for (int r = 0; r < 4; r++) {
      s0 += fmaxf(acc00[r] + bb0, 0.f) + fmaxf(acc10[r] + bb0, 0.f);
      s1 += fmaxf(acc01[r] + bb1, 0.f) + fmaxf(acc11[r] + bb1, 0.f);
    }
    s0 += __shfl_xor(s0, 16); s0 += __shfl_xor(s0, 32);
    s1 += __shfl_xor(s1, 16); s1 += __shfl_xor(s1, 32);
    if (lane < 16) {
      atomicAdd(&ws[WS_SUM3 + (q * 16 + st) * 32 + nl], s0);
      atomicAdd(&ws[WS_SUM3 + (q * 16 + st) * 32 + 16 + nl], s1);
    }
  } else {
    // ---- hid2 + softmax partial on 2 rows ----
    const int rl = ((role == 3) ? 2 : 0) + (lane >> 5);
    const int yg = y0 + rl;
    const int x0 = (lane & 31) * 2;
    float pa = 0.f, pb = 0.f;
    for (int ch = 0; ch < 16; ch++) {
#pragma unroll
      for (int ky = 0; ky < 3; ky++) {
        const float* bp = &occ[((rl + ky) * 16 + ch) * OP + x0];
        float f0 = bp[3];
        float2 fm = *(const float2*)(bp + 4);
        float f3 = bp[6];
        float wa = h2w[ch * 9 + 3 * ky], wb = h2w[ch * 9 + 3 * ky + 1],
              wc = h2w[ch * 9 + 3 * ky + 2];
        pa += wa * f0 + wb * fm.x + wc * fm.y;
        pb += wa * fm.x + wb * fm.y + wc * f3;
      }
    }
    float bb = h2b[0];
    float v0 = (pa + bb) * TEMPF, v1 = (pb + bb) * TEMPF;
    float mg = fmaxf(v0, v1);
#pragma unroll
    for (int off = 1; off < 64; off <<= 1) mg = fmaxf(mg, __shfl_xor(mg, off));
    float e0 = __expf(v0 - mg), e1 = __expf(v1 - mg);
    float s = e0 + e1;
    float sx = e0 * (float)x0 + e1 * (float)(x0 + 1);
    float sy = s * (float)yg;
#pragma unroll
    for (int off = 1; off < 64; off <<= 1) {
      s += __shfl_xor(s, off);
      sx += __shfl_xor(sx, off);
      sy += __shfl_xor(sy, off);
    }
    if (lane == 0) {
      int slot = q * 32 + st * 2 + ((role == 3) ? 1 : 0);
      *(float4*)&ws[WS_PART + slot * 4] = make_float4(mg, s, sx, sy);
    }
  }
}

// ---------------------------------------------------------------------------
// head merge (blocks 0-255) + mixer weight convert (all 1984 blocks)
// ---------------------------------------------------------------------------
__global__ __launch_bounds__(256) void k_merge_cvt(
    const float* __restrict__ w4, const float* __restrict__ b4,
    const float* __restrict__ w5, const float* __restrict__ b5,
    const float* __restrict__ wi, const float* __restrict__ wo,
    float* __restrict__ ws) {
  // ---- cvt part ----
  {
    int i = blockIdx.x * 256 + threadIdx.x;
    __hip_bfloat16* WIT = (__hip_bfloat16*)(ws + WS_WIT);
    __hip_bfloat16* WOT = (__hip_bfloat16*)(ws + WS_WOT);
    if (i < 278528) {
      int n = i / KPAD, k = i - n * KPAD;
      float v = (k < INDIM) ? wi[k * HID + n] : 0.f;
      WIT[i] = __float2bfloat16(v);
    } else if (i < 278528 + 229376) {
      int j = i - 278528;
      int n = j >> 9, k = j & 511;
      float v = (n < DIMV) ? wo[k * DIMV + n] : 0.f;
      WOT[j] = __float2bfloat16(v);
    }
  }
  if (blockIdx.x >= 256) return;

  // ---- merge part ----
  __shared__ float sums_s[4][32];
  __shared__ float o4s[4][16];
  int t = threadIdx.x, wv = t >> 6, lane = t & 63;
  int q = blockIdx.x * 4 + wv;

  float M = -1e30f, S = 0.f, SX = 0.f, SY = 0.f;
  if (lane < 32) {
    float4 pv = *(const float4*)&ws[WS_PART + (q * 32 + lane) * 4];
    M = pv.x; S = pv.y; SX = pv.z; SY = pv.w;
  }
#pragma unroll
  for (int off = 1; off < 64; off <<= 1) {
    float Mo = __shfl_xor(M, off), So = __shfl_xor(S, off);
    float SXo = __shfl_xor(SX, off), SYo = __shfl_xor(SY, off);
    float Mn = fmaxf(M, Mo);
    float c1 = __expf(M - Mn), c2 = __expf(Mo - Mn);
    S = S * c1 + So * c2; SX = SX * c1 + SXo * c2; SY = SY * c1 + SYo * c2;
    M = Mn;
  }
  if (lane == 0) {
    ws[WS_POS + q * 2 + 0] = (SX / S) * 8.0f;
    ws[WS_POS + q * 2 + 1] = (SY / S) * 8.0f;
  }

  int ch = lane & 31, half = lane >> 5;
  float sm = 0.f;
#pragma unroll
  for (int s8 = 0; s8 < 8; s8++)
    sm += ws[WS_SUM3 + (q * 16 + half * 8 + s8) * 32 + ch];
  sm += __shfl_xor(sm, 32);
  if (lane < 32) sums_s[wv][lane] = sm * (1.f / 1024.f);
  __syncthreads();
  if (lane < 16) {
    float a = b4[lane];
#pragma unroll
    for (int i = 0; i < 32; i++) a += sums_s[wv][i] * w4[i * 16 + lane];
    o4s[wv][lane] = fmaxf(a, 0.f);
  }
  __syncthreads();
  if (lane < 2) {
    float r = b5[lane];
#pragma unroll
    for (int j = 0; j < 16; j++) r += o4s[wv][j] * w5[j * 2 + lane];
    if (lane == 0) ws[WS_OCC + q] = r;
    else           ws[WS_EXPD + q] = r;
  }
}

// ---------------------------------------------------------------------------
// correlation + bf16 mlp_in assembly. 1 block = 1 query.
// ---------------------------------------------------------------------------
__global__ __launch_bounds__(256) void k_corr(
    const float* __restrict__ fg, const float* __restrict__ hg,
    float* __restrict__ ws) {
  __shared__ float qs[384];
  __shared__ float dbuf[3][64];
  int t = threadIdx.x;
  int wv = t >> 6, lane = t & 63;
  int cl = lane & 15, sub = lane >> 4;
  int n = blockIdx.x;
  const float* feats = ws + WS_FEATS + n * 384;
  float posx = ws[WS_POS + n * 2 + 0];
  float posy = ws[WS_POS + n * 2 + 1];
  __hip_bfloat16* mi = (__hip_bfloat16*)(ws + WS_MLPIN) + n * KPAD;

  for (int col = t; col < 384; col += 256) {
    float v = feats[col];
    qs[col] = v;
    mi[4 + col] = __float2bfloat16(v);
  }
  if (t < 4) {
    float v = (t == 2) ? ws[WS_OCC + n] : ((t == 3) ? ws[WS_EXPD + n] : 0.f);
    mi[t] = __float2bfloat16(v);
  }
  __syncthreads();

  float4 qh0 = *(const float4*)&qs[cl * 4];
  float4 qh1 = *(const float4*)&qs[64 + cl * 4];
  float4 qq0 = *(const float4*)&qs[128 + cl * 4];
  float4 qq1 = *(const float4*)&qs[192 + cl * 4];
  float4 qq2 = *(const float4*)&qs[256 + cl * 4];
  float4 qq3 = *(const float4*)&qs[320 + cl * 4];

#pragma unroll
  for (int L = 0; L < 3; L++) {
    const float* grid;
    int Hg, Wg;
    float scl;
    if (L == 0)      { grid = hg;             Hg = 128; Wg = 128; scl = 0.25f; }
    else if (L == 1) { grid = fg;             Hg = 64;  Wg = 64;  scl = 0.125f; }
    else             { grid = ws + WS_FGAVG;  Hg = 32;  Wg = 32;  scl = 0.0625f; }
    float cy = posy * scl, cx = posx * scl;
    int iy = (int)floorf(cy), ix = (int)floorf(cx);
#pragma unroll
    for (int g = 0; g < 4; g++) {
      int p = wv * 16 + g * 4 + sub;
      int a = p >> 3, b = p & 7;
      int row = iy + a - 3; row = row < 0 ? 0 : (row > Hg - 1 ? Hg - 1 : row);
      int col = ix + b - 3; col = col < 0 ? 0 : (col > Wg - 1 ? Wg - 1 : col);
      float acc;
      if (L == 0) {
        const float* gp = grid + (row * Wg + col) * 128 + cl * 4;
        float4 g0 = *(const float4*)gp;
        float4 g1 = *(const float4*)(gp + 64);
        acc = g0.x * qh0.x + g0.y * qh0.y + g0.z * qh0.z + g0.w * qh0.w +
              g1.x * qh1.x + g1.y * qh1.y + g1.z * qh1.z + g1.w * qh1.w;
      } else {
        const float* gp = grid + (row * Wg + col) * 256 + cl * 4;
        float4 g0 = *(const float4*)gp;
        float4 g1 = *(const float4*)(gp + 64);
        float4 g2 = *(const float4*)(gp + 128);
        float4 g3 = *(const float4*)(gp + 192);
        acc = g0.x * qq0.x + g0.y * qq0.y + g0.z * qq0.z + g0.w * qq0.w +
              g1.x * qq1.x + g1.y * qq1.y + g1.z * qq1.z + g1.w * qq1.w +
              g2.x * qq2.x + g2.y * qq2.y + g2.z * qq2.z + g2.w * qq2.w +
              g3.x * qq3.x + g3.y * qq3.y + g3.z * qq3.z + g3.w * qq3.w;
      }
      acc += __shfl_xor(acc, 1);
      acc += __shfl_xor(acc, 2);
      acc += __shfl_xor(acc, 4);
      acc += __shfl_xor(acc, 8);
      if (cl == 0) dbuf[L][p] = acc;
    }
  }
  __syncthreads();

  if (t < 147) {
    int L = t / 49, s = t - L * 49;
    int sa = s / 7, sb = s - sa * 7;
    float scl = (L == 0) ? 0.25f : ((L == 1) ? 0.125f : 0.0625f);
    float cy = posy * scl, cx = posx * scl;
    float wy = cy - floorf(cy), wx = cx - floorf(cx);
    int i00 = sa * 8 + sb;
    float d00 = dbuf[L][i00], d01 = dbuf[L][i00 + 1];
    float d10 = dbuf[L][i00 + 8], d11 = dbuf[L][i00 + 9];
    float corr = (1.f - wy) * (1.f - wx) * d00 + (1.f - wy) * wx * d01 +
                 wy * (1.f - wx) * d10 + wy * wx * d11;
    mi[388 + t] = __float2bfloat16(corr);
  }
}

// ---------------------------------------------------------------------------
__device__ __forceinline__ float gelu_tanh(float x) {
  float z = 0.7978845608028654f * (x + 0.044715f * x * x * x);
  z = fminf(fmaxf(z, -15.f), 15.f);
  float e = __expf(2.f * z);
  float th = (e - 1.f) / (e + 1.f);
  return 0.5f * x * (1.f + th);
}

// ---------------------------------------------------------------------------
// mixer GEMM 1 (MFMA bf16): hidden = gelu(mlp_in @ mix_in_w + b)
// ---------------------------------------------------------------------------
__global__ __launch_bounds__(256) void k_mix1(
    const float* __restrict__ bias, float* __restrict__ ws) {
  __shared__ __hip_bfloat16 A_s[32 * 32];
  __shared__ __hip_bfloat16 B_s[64 * 32];
  const int t = threadIdx.x;
  const int wv = t >> 6, lane = t & 63;
  const int wm = wv & 1, wn = wv >> 1;
  const int quad = lane >> 4, nl = lane & 15;
  const int n0 = blockIdx.x * 64, m0 = blockIdx.y * 32;
  const unsigned short* Abf = (const unsigned short*)(ws + WS_MLPIN);
  const unsigned short* WIT = (const unsigned short*)(ws + WS_WIT);
  f32x4 acc0 = {0.f, 0.f, 0.f, 0.f};
  f32x4 acc1 = {0.f, 0.f, 0.f, 0.f};

  for (int k0 = 0; k0 < KPAD; k0 += 32) {
    if (t < 128) {
      int r = t >> 2, c = t & 3;
      *(uint4*)&A_s[r * 32 + c * 8] =
          *(const uint4*)&Abf[(m0 + r) * KPAD + k0 + c * 8];
    }
    {
      int r = t >> 2, c = t & 3;
      *(uint4*)&B_s[r * 32 + c * 8] =
          *(const uint4*)&WIT[(n0 + r) * KPAD + k0 + c * 8];
    }
    __syncthreads();
    bf16x8 a = *(const bf16x8*)&A_s[(16 * wm + nl) * 32 + quad * 8];
    bf16x8 b0 = *(const bf16x8*)&B_s[(32 * wn + nl) * 32 + quad * 8];
    bf16x8 b1 = *(const bf16x8*)&B_s[(32 * wn + 16 + nl) * 32 + quad * 8];
    acc0 = __builtin_amdgcn_mfma_f32_16x16x32_bf16(a, b0, acc0, 0, 0, 0);
    acc1 = __builtin_amdgcn_mfma_f32_16x16x32_bf16(a, b1, acc1, 0, 0, 0);
    __syncthreads();
  }

  __hip_bfloat16* Hd = (__hip_bfloat16*)(ws + WS_HIDDEN);
#pragma unroll
  for (int nt = 0; nt < 2; nt++) {
    int nn = n0 + 32 * wn + nt * 16 + nl;
    float bv = bias[nn];
#pragma unroll
    for (int r = 0; r < 4; r++) {
      int m = m0 + 16 * wm + quad * 4 + r;
      float v = gelu_tanh((nt ? acc1[r] : acc0[r]) + bv);
      Hd[m * HID + nn] = __float2bfloat16(v);
    }
  }
}

// ---------------------------------------------------------------------------
// mixer GEMM 2 (MFMA bf16) + state update + out write
// ---------------------------------------------------------------------------
__global__ __launch_bounds__(256) void k_mix2(
    const float* __restrict__ bias, float* __restrict__ ws,
    float* __restrict__ out) {
  __shared__ __hip_bfloat16 A_s[32 * 32];
  __shared__ __hip_bfloat16 B_s[64 * 32];
  const int t = threadIdx.x;
  const int wv = t >> 6, lane = t & 63;
  const int wm = wv & 1, wn = wv >> 1;
  const int quad = lane >> 4, nl = lane & 15;
  const int n0 = blockIdx.x * 64, m0 = blockIdx.y * 32;
  const unsigned short* Abf = (const unsigned short*)(ws + WS_HIDDEN);
  const unsigned short* WOT = (const unsigned short*)(ws + WS_WOT);
  f32x4 acc0 = {0.f, 0.f, 0.f, 0.f};
  f32x4 acc1 = {0.f, 0.f, 0.f, 0.f};

  for (int k0 = 0; k0 < HID; k0 += 32) {
    if (t < 128) {
      int r = t >> 2, c = t & 3;
      *(uint4*)&A_s[r * 32 + c * 8] =
          *(const uint4*)&Abf[(m0 + r) * HID + k0 + c * 8];
    }
    {
      int r = t >> 2, c = t & 3;
      *(uint4*)&B_s[r * 32 + c * 8] =
          *(const uint4*)&WOT[(n0 + r) * HID + k0 + c * 8];
    }
    __syncthreads();
    bf16x8 a = *(const bf16x8*)&A_s[(16 * wm + nl) * 32 + quad * 8];
    bf16x8 b0 = *(const bf16x8*)&B_s[(32 * wn + nl) * 32 + quad * 8];
    bf16x8 b1 = *(const bf16x8*)&B_s[(32 * wn + 16 + nl) * 32 + quad * 8];
    acc0 = __builtin_amdgcn_mfma_f32_16x16x32_bf16(a, b0, acc0, 0, 0, 0);
    acc1 = __builtin_amdgcn_mfma_f32_16x16x32_bf16(a, b1, acc1, 0, 0, 0);
    __syncthreads();
  }

#pragma unroll
  for (int nt = 0; nt < 2; nt++) {
    int col = n0 + 32 * wn + nt * 16 + nl;
    if (col >= DIMV) continue;
    float bv = bias[col];
#pragma unroll
    for (int r = 0; r < 4; r++) {
      int m = m0 + 16 * wm + quad * 4 + r;
      float rr = (nt ? acc1[r] : acc0[r]) + bv;
      if (col < 2) {
        float v = ws[WS_POS + m * 2 + col] + rr;
        ws[WS_POS + m * 2 + col] = v;
        out[m * 4 + col] = v;
      } else if (col == 2) {
        float v = ws[WS_OCC + m] + rr;
        ws[WS_OCC + m] = v;
        out[m * 4 + 2] = v;
      } else if (col == 3) {
        float v = ws[WS_EXPD + m] + rr;
        ws[WS_EXPD + m] = v;
        out[m * 4 + 3] = v;
      } else {
        ws[WS_FEATS + m * 384 + (col - 4)] += rr;
      }
    }
  }
}

// ---------------------------------------------------------------------------
extern "C" void kernel_launch(void* const* d_in, const int* in_sizes, int n_in,
                              void* d_out, int out_size, void* d_ws, size_t ws_size,
                              hipStream_t stream) {
  const float* fg = (const float*)d_in[0];
  const float* hg = (const float*)d_in[1];
  const float* qf = (const float*)d_in[2];
  const float* hq = (const float*)d_in[3];
  const float* w1 = (const float*)d_in[4];
  const float* b1 = (const float*)d_in[5];
  const float* w2 = (const float*)d_in[6];
  const float* b2 = (const float*)d_in[7];
  const float* w3 = (const float*)d_in[8];
  const float* b3 = (const float*)d_in[9];
  const float* w4 = (const float*)d_in[10];
  const float* b4 = (const float*)d_in[11];
  const float* w5 = (const float*)d_in[12];
  const float* b5 = (const float*)d_in[13];
  const float* wi = (const float*)d_in[14];
  const float* bi = (const float*)d_in[15];
  const float* wo = (const float*)d_in[16];
  const float* bo = (const float*)d_in[17];
  float* ws = (float*)d_ws;
  float* out = (float*)d_out;

  k_prep<<<4628, 256, 0, stream>>>(fg, qf, hq, w3, ws);
  k_cv<<<dim3(64, 32), 256, 0, stream>>>(qf, fg, ws);
  k_head_stripe<<<16384, 256, 0, stream>>>(w1, b1, w2, b2, b3, ws);
  k_merge_cvt<<<1984, 256, 0, stream>>>(w4, b4, w5, b5, wi, wo, ws);
  for (int it = 0; it < 4; it++) {
    k_corr<<<1024, 256, 0, stream>>>(fg, hg, ws);
    k_mix1<<<dim3(8, 32), 256, 0, stream>>>(bi, ws);
    k_mix2<<<dim3(7, 32), 256, 0, stream>>>(bo, ws, out);
  }
}